// Round 5
// baseline (821.201 us; speedup 1.0000x reference)
//
#include <hip/hip_runtime.h>
#include <cstdint>
#include <cstddef>

#define TT 4096
#define DM 1024
#define DN 2048
#define MROWS 16384  // B*T
#define NCH 64       // scan chunks per sequence
#define CHL 64       // chunk length (TT/NCH)
#define SW 16        // B/C staging window inside a chunk
#define XBCS 128     // xbc row stride (f32), padded from 96 for MFMA GEMM

typedef unsigned short u16;
typedef u16 ushort8_t __attribute__((ext_vector_type(8)));
typedef u16 ushort4_t __attribute__((ext_vector_type(4)));
typedef short bf16x8 __attribute__((ext_vector_type(8)));   // MFMA A/B frag (4 VGPR)
typedef float f32x4 __attribute__((ext_vector_type(4)));    // MFMA C/D frag

__device__ __forceinline__ float bf2f(u16 b) {
  return __uint_as_float(((unsigned int)b) << 16);
}
__device__ __forceinline__ u16 f2bf(float f) {
  unsigned int u = __float_as_uint(f);
  u = u + 0x7FFFu + ((u >> 16) & 1u);   // round-to-nearest-even
  return (u16)(u >> 16);
}
__device__ __forceinline__ u16 f2h(float f) {
  _Float16 h = (_Float16)f;
  return __builtin_bit_cast(u16, h);
}
__device__ __forceinline__ float h2f(u16 v) {
  return (float)__builtin_bit_cast(_Float16, v);
}

__device__ __forceinline__ void gload_lds16(const void* g, void* l) {
  __builtin_amdgcn_global_load_lds(
      (const __attribute__((address_space(1))) unsigned int*)g,
      (__attribute__((address_space(3))) unsigned int*)l, 16, 0, 0);
}

// ---------------- f32 -> bf16 converter (weights) ----------------
__global__ __launch_bounds__(256) void cvt_bf16_kernel(const float* __restrict__ in,
    u16* __restrict__ out, int n4) {
  int i = blockIdx.x * 256 + threadIdx.x;
  if (i >= n4) return;
  float4 v = ((const float4*)in)[i];
  ushort4_t o; o[0] = f2bf(v.x); o[1] = f2bf(v.y); o[2] = f2bf(v.z); o[3] = f2bf(v.w);
  ((ushort4_t*)out)[i] = o;
}

// ---------------- W_x f32(96x2048) -> bf16(128x2048), rows 96..127 zero ----------------
__global__ __launch_bounds__(256) void cvt_wx_kernel(const float* __restrict__ W_x,
    u16* __restrict__ out) {
  int i = blockIdx.x * 256 + threadIdx.x;   // over 128*2048/4 = 65536 float4 slots
  int row = i >> 9;                         // 512 float4 per row
  ushort4_t o;
  if (row < 96) {
    float4 v = ((const float4*)W_x)[i];
    o[0] = f2bf(v.x); o[1] = f2bf(v.y); o[2] = f2bf(v.z); o[3] = f2bf(v.w);
  } else {
    o[0] = 0; o[1] = 0; o[2] = 0; o[3] = 0;
  }
  ((ushort4_t*)out)[i] = o;
}

// ---------------- LayerNorm -> bf16 out ----------------
__global__ __launch_bounds__(256) void ln_kernel(const float* __restrict__ x,
    const float* __restrict__ ln_w, const float* __restrict__ ln_b,
    u16* __restrict__ xn) {
  int row = blockIdx.x;
  int tid = threadIdx.x;
  const float4* xr = (const float4*)(x + (size_t)row * DM);
  float4 v = xr[tid];
  float s  = v.x + v.y + v.z + v.w;
  float s2 = v.x*v.x + v.y*v.y + v.z*v.z + v.w*v.w;
#pragma unroll
  for (int o = 32; o > 0; o >>= 1) { s += __shfl_down(s, o, 64); s2 += __shfl_down(s2, o, 64); }
  __shared__ float red[2][4];
  __shared__ float mv[2];
  int wid = tid >> 6, lane = tid & 63;
  if (lane == 0) { red[0][wid] = s; red[1][wid] = s2; }
  __syncthreads();
  if (tid == 0) {
    float a  = red[0][0] + red[0][1] + red[0][2] + red[0][3];
    float b2 = red[1][0] + red[1][1] + red[1][2] + red[1][3];
    float mean = a * (1.f / DM);
    float var  = b2 * (1.f / DM) - mean * mean;
    mv[0] = mean; mv[1] = rsqrtf(var + 1e-5f);
  }
  __syncthreads();
  float mean = mv[0], inv = mv[1];
  float4 w = ((const float4*)ln_w)[tid];
  float4 b = ((const float4*)ln_b)[tid];
  ushort4_t o;
  o[0] = f2bf((v.x - mean) * inv * w.x + b.x);
  o[1] = f2bf((v.y - mean) * inv * w.y + b.y);
  o[2] = f2bf((v.z - mean) * inv * w.z + b.z);
  o[3] = f2bf((v.w - mean) * inv * w.w + b.w);
  *(ushort4_t*)(xn + (size_t)row * DM + tid * 4) = o;
}

// ---------------- bf16 MFMA GEMM, NT: C[i][j] = sum_k A[i][k]*B[j][k] -----------
// MODE 0: bf16 out. MODE 1: f32 out + bf16 dl copy of cols<64 (needs bj==0 grid).
// MODE 2: f32 out + residual add. MODE 3: f16 out = clamp(softplus(v+bias)+1e-3).
// XCD-aware block swizzle (nwg must be divisible by 8; all our grids are).
template<int MODE>
__global__ __launch_bounds__(256) void gemm_mfma_nt(
    const u16* __restrict__ A, int lda,
    const u16* __restrict__ B, int ldb,
    void* __restrict__ Cp, int ldc,
    const float* __restrict__ Res, int K,
    const float* __restrict__ bias, u16* __restrict__ dl_out) {
  __shared__ __align__(16) u16 a_s[128 * 64];
  __shared__ __align__(16) u16 b_s[128 * 64];
  const int tid = threadIdx.x;
  const int w = tid >> 6, l = tid & 63;
  const int wr = w >> 1, wc = w & 1;
  const int nbx = gridDim.x;
  int lin = blockIdx.y * nbx + blockIdx.x;
  int cpx = (nbx * gridDim.y) >> 3;
  int swz = (lin & 7) * cpx + (lin >> 3);
  const int bi = swz % nbx, bj = swz / nbx;
  const int lrow = l >> 3;                    // lane's row-in-8 within a 1KB chunk
  const int scol = ((l & 7) ^ lrow) * 16;     // inverse-swizzled source byte-in-row

  f32x4 acc[4][4] = {};

  const u16* Abase = A + (size_t)(bi * 128 + w * 8 + lrow) * lda;
  const u16* Bbase = B + (size_t)(bj * 128 + w * 8 + lrow) * ldb;

  for (int k0 = 0; k0 < K; k0 += 64) {
#pragma unroll
    for (int c = 0; c < 4; c++) {
      const char* ga = (const char*)(Abase + (size_t)(c * 32) * lda + k0) + scol;
      const char* gb = (const char*)(Bbase + (size_t)(c * 32) * ldb + k0) + scol;
      gload_lds16(ga, (char*)a_s + c * 4096 + w * 1024);
      gload_lds16(gb, (char*)b_s + c * 4096 + w * 1024);
    }
    __syncthreads();
#pragma unroll
    for (int kk = 0; kk < 2; kk++) {
      bf16x8 af[4], bfr[4];
#pragma unroll
      for (int m = 0; m < 4; m++) {
        int fr = wr * 64 + m * 16 + (l & 15);
        int cb = (kk * 64 + ((l >> 4) << 4)) ^ ((fr & 7) << 4);
        af[m] = *(const bf16x8*)((const char*)a_s + fr * 128 + cb);
      }
#pragma unroll
      for (int n = 0; n < 4; n++) {
        int fr = wc * 64 + n * 16 + (l & 15);
        int cb = (kk * 64 + ((l >> 4) << 4)) ^ ((fr & 7) << 4);
        bfr[n] = *(const bf16x8*)((const char*)b_s + fr * 128 + cb);
      }
#pragma unroll
      for (int m = 0; m < 4; m++)
#pragma unroll
        for (int n = 0; n < 4; n++)
          acc[m][n] = __builtin_amdgcn_mfma_f32_16x16x32_bf16(af[m], bfr[n], acc[m][n], 0, 0, 0);
    }
    __syncthreads();
  }
  const int col0 = bj * 128 + wc * 64 + (l & 15);
  const int row0 = bi * 128 + wr * 64 + (l >> 4) * 4;
#pragma unroll
  for (int m = 0; m < 4; m++)
#pragma unroll
    for (int n = 0; n < 4; n++) {
      int col = col0 + n * 16;
      float bv = 0.f;
      if constexpr (MODE == 3) bv = bias[col];
#pragma unroll
      for (int r = 0; r < 4; r++) {
        size_t row = (size_t)(row0 + m * 16 + r);
        float v = acc[m][n][r];
        if constexpr (MODE == 0) {
          ((u16*)Cp)[row * ldc + col] = f2bf(v);
        } else if constexpr (MODE == 1) {
          ((float*)Cp)[row * ldc + col] = v;
          if (col < 64) dl_out[row * 64 + col] = f2bf(v);
        } else if constexpr (MODE == 2) {
          v += Res[row * ldc + col];
          ((float*)Cp)[row * ldc + col] = v;
        } else {
          // fast softplus: log(1+exp(s)) via HW trans; s->-inf => 0 (dt=1e-3),
          // s large => exp->inf => log->inf => fmin caps at 0.1.
          float s = v + bv;
          float sp = __logf(1.f + __expf(s));
          float dtv = fminf(sp + 1e-3f, 0.1f);
          ((u16*)Cp)[row * ldc + col] = f2h(dtv);
        }
      }
    }
}

// ---------------- causal depthwise conv (width 4) + SiLU; bf16 in, bf16 out ----------------
__global__ __launch_bounds__(256) void conv_silu_kernel(const u16* __restrict__ xz,
    const float* __restrict__ conv_w, const float* __restrict__ conv_b,
    u16* __restrict__ u) {
  size_t gid = (size_t)blockIdx.x * 256 + threadIdx.x;
  int c = (int)(gid & 255);
  size_t i = gid >> 8;
  int t = (int)(i & (TT - 1));
  int d0 = c * 8;
  const u16* base = xz + i * 4096 + d0;
  ushort8_t r0 = *(const ushort8_t*)base;
  ushort8_t r1 = 0, r2 = 0, r3 = 0;
  if (t >= 1) r1 = *(const ushort8_t*)(base - 4096);
  if (t >= 2) r2 = *(const ushort8_t*)(base - 2 * 4096);
  if (t >= 3) r3 = *(const ushort8_t*)(base - 3 * 4096);
  float cbv[8];
  *(float4*)&cbv[0] = *(const float4*)(conv_b + d0);
  *(float4*)&cbv[4] = *(const float4*)(conv_b + d0 + 4);
  ushort8_t o;
#pragma unroll
  for (int j = 0; j < 8; j++) {
    float4 w = *(const float4*)(conv_w + (size_t)(d0 + j) * 4);
    float a = cbv[j] + w.w * bf2f(r0[j]) + w.z * bf2f(r1[j])
            + w.y * bf2f(r2[j]) + w.x * bf2f(r3[j]);
    a = a * __builtin_amdgcn_rcpf(1.f + __expf(-a));
    o[j] = f2bf(a);
  }
  *(ushort8_t*)(u + i * 2048 + d0) = o;
}

// ---------------- scan phase 1: local chunk scan from h=0; writes y_local over u ----------
// u/dt are thread-private streams -> direct global scalar loads (coalesced per wave).
// Only B/C rows (shared by all threads) are LDS-staged. hbuf layout [b][c][n][d].
__global__ __launch_bounds__(256) void scan_part1(u16* u,
    const u16* __restrict__ dt_g, const float* __restrict__ xbc,
    const float* __restrict__ log_A, const float* __restrict__ D_param,
    float* __restrict__ hbuf, float* __restrict__ Sbuf) {
  int d0 = blockIdx.x * 256;
  int c  = blockIdx.y;
  int b  = blockIdx.z;
  int tid = threadIdx.x;
  int d = d0 + tid;
  __shared__ __align__(16) float bc_s[SW][32];   // 2K (B | C)

  float A2[16];
#pragma unroll
  for (int n = 0; n < 4; n++) {
    float4 la = *(const float4*)(log_A + (size_t)d * 16 + n * 4);
    A2[n*4+0] = -__expf(la.x) * 1.44269504f;
    A2[n*4+1] = -__expf(la.y) * 1.44269504f;
    A2[n*4+2] = -__expf(la.z) * 1.44269504f;
    A2[n*4+3] = -__expf(la.w) * 1.44269504f;
  }
  float Dp = D_param[d];
  float h[16] = {};
  float sdt = 0.f;
  size_t t0 = (size_t)b * TT + (size_t)c * CHL;
  const u16* dtp = dt_g + t0 * 4096 + d;
  u16* up = u + t0 * 2048 + d;
  const int r2 = tid >> 4, q2 = (tid & 15) * 2;
  for (int wnd = 0; wnd < CHL / SW; wnd++) {
    size_t i0 = t0 + (size_t)wnd * SW;
    float2 bcv = *(const float2*)(xbc + (i0 + r2) * XBCS + 64 + q2);
    __syncthreads();                       // previous window's bc_s reads done
    *(float2*)&bc_s[r2][q2] = bcv;
    __syncthreads();
#pragma unroll 2
    for (int tt = 0; tt < SW; tt++) {
      float dtv = h2f(*dtp); dtp += 4096;
      float uv  = bf2f(*up);
      sdt += dtv;
      float xin = dtv * uv;
      float yv  = uv * Dp;
      const float4* R = (const float4*)bc_s[tt];
      float4 B0 = R[0], B1 = R[1], B2 = R[2], B3 = R[3];
      float4 C0 = R[4], C1 = R[5], C2 = R[6], C3 = R[7];
      h[0]  = exp2f(dtv*A2[0]) *h[0]  + xin*B0.x; yv += h[0] *C0.x;
      h[1]  = exp2f(dtv*A2[1]) *h[1]  + xin*B0.y; yv += h[1] *C0.y;
      h[2]  = exp2f(dtv*A2[2]) *h[2]  + xin*B0.z; yv += h[2] *C0.z;
      h[3]  = exp2f(dtv*A2[3]) *h[3]  + xin*B0.w; yv += h[3] *C0.w;
      h[4]  = exp2f(dtv*A2[4]) *h[4]  + xin*B1.x; yv += h[4] *C1.x;
      h[5]  = exp2f(dtv*A2[5]) *h[5]  + xin*B1.y; yv += h[5] *C1.y;
      h[6]  = exp2f(dtv*A2[6]) *h[6]  + xin*B1.z; yv += h[6] *C1.z;
      h[7]  = exp2f(dtv*A2[7]) *h[7]  + xin*B1.w; yv += h[7] *C1.w;
      h[8]  = exp2f(dtv*A2[8]) *h[8]  + xin*B2.x; yv += h[8] *C2.x;
      h[9]  = exp2f(dtv*A2[9]) *h[9]  + xin*B2.y; yv += h[9] *C2.y;
      h[10] = exp2f(dtv*A2[10])*h[10] + xin*B2.z; yv += h[10]*C2.z;
      h[11] = exp2f(dtv*A2[11])*h[11] + xin*B2.w; yv += h[11]*C2.w;
      h[12] = exp2f(dtv*A2[12])*h[12] + xin*B3.x; yv += h[12]*C3.x;
      h[13] = exp2f(dtv*A2[13])*h[13] + xin*B3.y; yv += h[13]*C3.y;
      h[14] = exp2f(dtv*A2[14])*h[14] + xin*B3.z; yv += h[14]*C3.z;
      h[15] = exp2f(dtv*A2[15])*h[15] + xin*B3.w; yv += h[15]*C3.w;
      *up = f2bf(yv); up += 2048;          // y_local over dead u (same thread)
    }
  }
  float* hp = hbuf + (((size_t)b * NCH + c) * 16) * DN + d;
#pragma unroll
  for (int n = 0; n < 16; n++) hp[(size_t)n * DN] = h[n];
  Sbuf[((size_t)b * NCH + c) * DN + d] = sdt;
}

// ---------------- scan phase 2: sequential chunk combine (in-place h_end -> h_start) -------
// hbuf layout [b][c][n][d]; thread per (b,n,d) with d fastest -> coalesced.
__global__ __launch_bounds__(256) void scan_combine(const float* __restrict__ log_A,
    const float* __restrict__ Sbuf, float* __restrict__ hbuf) {
  int idx = blockIdx.x * 256 + threadIdx.x;    // over B*16*DN
  int dd = idx & (DN - 1), n = (idx >> 11) & 15, b = idx >> 15;
  float A = -__expf(log_A[(size_t)dd * 16 + n]);
  float h = 0.f;
#pragma unroll
  for (int c = 0; c < NCH; c++) {
    size_t off = (((size_t)b * NCH + c) * 16 + n) * DN + dd;
    float hl = hbuf[off];
    float P = __expf(A * Sbuf[((size_t)b * NCH + c) * DN + dd]);
    hbuf[off] = h;                 // now holds h_start for chunk c
    h = hl + P * h;
  }
}

// ---------------- scan phase 3: y = (y_local + C.(exp(A*cum) o h_start)) * silu(z) --------
__global__ __launch_bounds__(256) void scan_part2(u16* yl,
    const u16* __restrict__ xz, const float* __restrict__ xbc,
    const u16* __restrict__ dt_g, const float* __restrict__ log_A,
    const float* __restrict__ hbuf) {
  int d0 = blockIdx.x * 256;
  int c  = blockIdx.y;
  int b  = blockIdx.z;
  int tid = threadIdx.x;
  int d = d0 + tid;
  __shared__ __align__(16) float c_s[SW][16];    // 1K

  float A2[16];
#pragma unroll
  for (int n = 0; n < 4; n++) {
    float4 la = *(const float4*)(log_A + (size_t)d * 16 + n * 4);
    A2[n*4+0] = -__expf(la.x) * 1.44269504f;
    A2[n*4+1] = -__expf(la.y) * 1.44269504f;
    A2[n*4+2] = -__expf(la.z) * 1.44269504f;
    A2[n*4+3] = -__expf(la.w) * 1.44269504f;
  }
  float hs[16];
  const float* hp = hbuf + (((size_t)b * NCH + c) * 16) * DN + d;
#pragma unroll
  for (int n = 0; n < 16; n++) hs[n] = hp[(size_t)n * DN];
  float cum = 0.f;
  size_t t0 = (size_t)b * TT + (size_t)c * CHL;
  const u16* dtp = dt_g + t0 * 4096 + d;
  const u16* zp  = xz + t0 * 4096 + 2048 + d;
  u16* ylp = yl + t0 * 2048 + d;
  const int r2 = tid >> 4, q2 = tid & 15;
  for (int wnd = 0; wnd < CHL / SW; wnd++) {
    size_t i0 = t0 + (size_t)wnd * SW;
    float cv = xbc[(i0 + r2) * XBCS + 80 + q2];
    __syncthreads();
    c_s[r2][q2] = cv;
    __syncthreads();
#pragma unroll 4
    for (int tt = 0; tt < SW; tt++) {
      float dtv = h2f(*dtp); dtp += 4096;
      cum += dtv;
      float yv = bf2f(*ylp);
      float zv = bf2f(*zp); zp += 4096;
      const float4* R = (const float4*)c_s[tt];
      float4 C0 = R[0], C1 = R[1], C2 = R[2], C3 = R[3];
      yv += C0.x*(exp2f(cum*A2[0]) *hs[0])  + C0.y*(exp2f(cum*A2[1]) *hs[1])
          + C0.z*(exp2f(cum*A2[2]) *hs[2])  + C0.w*(exp2f(cum*A2[3]) *hs[3]);
      yv += C1.x*(exp2f(cum*A2[4]) *hs[4])  + C1.y*(exp2f(cum*A2[5]) *hs[5])
          + C1.z*(exp2f(cum*A2[6]) *hs[6])  + C1.w*(exp2f(cum*A2[7]) *hs[7]);
      yv += C2.x*(exp2f(cum*A2[8]) *hs[8])  + C2.y*(exp2f(cum*A2[9]) *hs[9])
          + C2.z*(exp2f(cum*A2[10])*hs[10]) + C2.w*(exp2f(cum*A2[11])*hs[11]);
      yv += C3.x*(exp2f(cum*A2[12])*hs[12]) + C3.y*(exp2f(cum*A2[13])*hs[13])
          + C3.z*(exp2f(cum*A2[14])*hs[14]) + C3.w*(exp2f(cum*A2[15])*hs[15]);
      float sig = __builtin_amdgcn_rcpf(1.f + __expf(-zv));
      yv *= zv * sig;
      *ylp = f2bf(yv); ylp += 2048;        // final y over y_local (same thread)
    }
  }
}

extern "C" void kernel_launch(void* const* d_in, const int* in_sizes, int n_in,
                              void* d_out, int out_size, void* d_ws, size_t ws_size,
                              hipStream_t stream) {
  const float* x       = (const float*)d_in[0];
  const float* W_in    = (const float*)d_in[1];
  const float* conv_w  = (const float*)d_in[2];
  const float* conv_b  = (const float*)d_in[3];
  const float* W_x     = (const float*)d_in[4];
  const float* W_dt    = (const float*)d_in[5];
  const float* b_dt    = (const float*)d_in[6];
  const float* log_A   = (const float*)d_in[7];
  const float* D_param = (const float*)d_in[8];
  const float* W_out   = (const float*)d_in[9];
  const float* ln_w    = (const float*)d_in[10];
  const float* ln_b    = (const float*)d_in[11];
  float* out = (float*)d_out;

  // ws (proven >=198MiB): xz 128MiB + u 64MiB + 6MiB tail (W_out bf16 staging)
  size_t need = (size_t)MROWS * 4096 * 2 + (size_t)MROWS * DN * 2 + (size_t)MROWS * 96 * 4;
  if (ws_size < need) return;
  u16*   xz  = (u16*)d_ws;                        // 16384 x 4096 bf16 (x_inner | z); x_inner
                                                  // cols become f16 dt after dt_gemm
  u16*   u   = xz + (size_t)MROWS * 4096;         // 16384 x 2048 bf16 (u -> y_local -> y)
  u16*   W_out_b = (u16*)(u + (size_t)MROWS * DN);// 4MiB, used only for gemm2 staging

  // d_out (64MiB) staging: all dead before gemm2 fully overwrites d_out
  u16*   xn_b    = (u16*)d_out;                                  // [0,32)MiB, dead after gemm1
  float* xbc     = (float*)d_out;                                // [0,8)MiB, written AFTER gemm1
  float* hbuf    = (float*)((char*)d_out + (8u << 20));          // [8,40)MiB (4*64*16*2048 f32)
  u16*   W_in_b  = (u16*)((char*)d_out + (40u << 20));           // [40,48)MiB
  float* Sbuf    = (float*)((char*)d_out + (48u << 20));         // [48,50)MiB
  u16*   W_x_b   = (u16*)((char*)d_out + (50u << 20));           // [50,50.5)MiB
  u16*   W_dt_b  = (u16*)((char*)d_out + (50u << 20) + (512u << 10)); // [50.5,50.75) 2048x64 bf16
  u16*   dl_b    = (u16*)((char*)d_out + (51u << 20));           // [51,53)MiB 16384x64 bf16

  cvt_wx_kernel<<<(128 * 2048 / 4) / 256, 256, 0, stream>>>(W_x, W_x_b);
  cvt_bf16_kernel<<<(2048 * 64 / 4) / 256, 256, 0, stream>>>(W_dt, W_dt_b, 2048 * 64 / 4);
  ln_kernel<<<MROWS, 256, 0, stream>>>(x, ln_w, ln_b, xn_b);
  cvt_bf16_kernel<<<(4096 * 1024 / 4) / 256, 256, 0, stream>>>(W_in, W_in_b, 4096 * 1024 / 4);
  gemm_mfma_nt<0><<<dim3(MROWS / 128, 4096 / 128), 256, 0, stream>>>(
      xn_b, DM, W_in_b, DM, xz, 4096, nullptr, DM, nullptr, nullptr);
  conv_silu_kernel<<<MROWS, 256, 0, stream>>>(xz, conv_w, conv_b, u);
  // xbc = u @ W_x.T via MFMA (N padded 96->128); also emits dl bf16; overwrites dead xn_b
  gemm_mfma_nt<1><<<dim3(MROWS / 128, XBCS / 128), 256, 0, stream>>>(
      u, DN, W_x_b, DN, xbc, XBCS, nullptr, DN, nullptr, dl_b);
  // dt = clamp(softplus(dl @ W_dt.T + b_dt)+1e-3) -> f16 into dead x_inner cols of xz
  gemm_mfma_nt<3><<<dim3(MROWS / 128, DN / 128), 256, 0, stream>>>(
      dl_b, 64, W_dt_b, 64, xz, 4096, nullptr, 64, b_dt, nullptr);
  scan_part1<<<dim3(DN / 256, NCH, 4), 256, 0, stream>>>(
      u, xz, xbc, log_A, D_param, hbuf, Sbuf);
  scan_combine<<<4 * DN * 16 / 256, 256, 0, stream>>>(log_A, Sbuf, hbuf);
  scan_part2<<<dim3(DN / 256, NCH, 4), 256, 0, stream>>>(
      u, xz, xbc, xz, log_A, hbuf);
  cvt_bf16_kernel<<<(1024 * 2048 / 4) / 256, 256, 0, stream>>>(W_out, W_out_b, 1024 * 2048 / 4);
  gemm_mfma_nt<2><<<dim3(MROWS / 128, 1024 / 128), 256, 0, stream>>>(
      u, DN, W_out_b, DN, out, DM, x, DN, nullptr, nullptr);
}

// Round 6
// 680.235 us; speedup vs baseline: 1.2072x; 1.2072x over previous
//
#include <hip/hip_runtime.h>
#include <cstdint>
#include <cstddef>

#define TT 4096
#define DM 1024
#define DN 2048
#define MROWS 16384  // B*T
#define NCH 64       // scan chunks per sequence
#define CHL 64       // chunk length (TT/NCH)
#define SW 16        // staging window inside a chunk
#define XBCS 128     // xbc row stride (f32), padded from 96 for MFMA GEMM

typedef unsigned short u16;
typedef u16 ushort8_t __attribute__((ext_vector_type(8)));
typedef u16 ushort4_t __attribute__((ext_vector_type(4)));
typedef short bf16x8 __attribute__((ext_vector_type(8)));   // MFMA A/B frag (4 VGPR)
typedef float f32x4 __attribute__((ext_vector_type(4)));    // MFMA C/D frag

#define EXP2(x) __builtin_amdgcn_exp2f(x)
#define L2E 1.44269504f

__device__ __forceinline__ float bf2f(u16 b) {
  return __uint_as_float(((unsigned int)b) << 16);
}
__device__ __forceinline__ u16 f2bf(float f) {
  unsigned int u = __float_as_uint(f);
  u = u + 0x7FFFu + ((u >> 16) & 1u);   // round-to-nearest-even
  return (u16)(u >> 16);
}
__device__ __forceinline__ u16 f2h(float f) {
  _Float16 h = (_Float16)f;
  return __builtin_bit_cast(u16, h);
}
__device__ __forceinline__ float h2f(u16 v) {
  return (float)__builtin_bit_cast(_Float16, v);
}

__device__ __forceinline__ void gload_lds16(const void* g, void* l) {
  __builtin_amdgcn_global_load_lds(
      (const __attribute__((address_space(1))) unsigned int*)g,
      (__attribute__((address_space(3))) unsigned int*)l, 16, 0, 0);
}

// ---------------- f32 -> bf16 converter (weights) ----------------
__global__ __launch_bounds__(256) void cvt_bf16_kernel(const float* __restrict__ in,
    u16* __restrict__ out, int n4) {
  int i = blockIdx.x * 256 + threadIdx.x;
  if (i >= n4) return;
  float4 v = ((const float4*)in)[i];
  ushort4_t o; o[0] = f2bf(v.x); o[1] = f2bf(v.y); o[2] = f2bf(v.z); o[3] = f2bf(v.w);
  ((ushort4_t*)out)[i] = o;
}

// ---------------- W_x f32(96x2048) -> bf16(128x2048), rows 96..127 zero ----------------
__global__ __launch_bounds__(256) void cvt_wx_kernel(const float* __restrict__ W_x,
    u16* __restrict__ out) {
  int i = blockIdx.x * 256 + threadIdx.x;   // over 128*2048/4 = 65536 float4 slots
  int row = i >> 9;                         // 512 float4 per row
  ushort4_t o;
  if (row < 96) {
    float4 v = ((const float4*)W_x)[i];
    o[0] = f2bf(v.x); o[1] = f2bf(v.y); o[2] = f2bf(v.z); o[3] = f2bf(v.w);
  } else {
    o[0] = 0; o[1] = 0; o[2] = 0; o[3] = 0;
  }
  ((ushort4_t*)out)[i] = o;
}

// ---------------- LayerNorm -> bf16 out ----------------
__global__ __launch_bounds__(256) void ln_kernel(const float* __restrict__ x,
    const float* __restrict__ ln_w, const float* __restrict__ ln_b,
    u16* __restrict__ xn) {
  int row = blockIdx.x;
  int tid = threadIdx.x;
  const float4* xr = (const float4*)(x + (size_t)row * DM);
  float4 v = xr[tid];
  float s  = v.x + v.y + v.z + v.w;
  float s2 = v.x*v.x + v.y*v.y + v.z*v.z + v.w*v.w;
#pragma unroll
  for (int o = 32; o > 0; o >>= 1) { s += __shfl_down(s, o, 64); s2 += __shfl_down(s2, o, 64); }
  __shared__ float red[2][4];
  __shared__ float mv[2];
  int wid = tid >> 6, lane = tid & 63;
  if (lane == 0) { red[0][wid] = s; red[1][wid] = s2; }
  __syncthreads();
  if (tid == 0) {
    float a  = red[0][0] + red[0][1] + red[0][2] + red[0][3];
    float b2 = red[1][0] + red[1][1] + red[1][2] + red[1][3];
    float mean = a * (1.f / DM);
    float var  = b2 * (1.f / DM) - mean * mean;
    mv[0] = mean; mv[1] = rsqrtf(var + 1e-5f);
  }
  __syncthreads();
  float mean = mv[0], inv = mv[1];
  float4 w = ((const float4*)ln_w)[tid];
  float4 b = ((const float4*)ln_b)[tid];
  ushort4_t o;
  o[0] = f2bf((v.x - mean) * inv * w.x + b.x);
  o[1] = f2bf((v.y - mean) * inv * w.y + b.y);
  o[2] = f2bf((v.z - mean) * inv * w.z + b.z);
  o[3] = f2bf((v.w - mean) * inv * w.w + b.w);
  *(ushort4_t*)(xn + (size_t)row * DM + tid * 4) = o;
}

// ---------------- bf16 MFMA GEMM, NT: C[i][j] = sum_k A[i][k]*B[j][k] -----------
// MODE 0: bf16 out. MODE 1: f32 out + bf16 dl copy of cols<64 (needs bj==0 grid).
// MODE 2: f32 out + residual add. MODE 3: f16 out = clamp(softplus(v+bias)+1e-3).
// XCD-aware block swizzle (nwg divisible by 8 for all our grids).
template<int MODE>
__global__ __launch_bounds__(256) void gemm_mfma_nt(
    const u16* __restrict__ A, int lda,
    const u16* __restrict__ B, int ldb,
    void* __restrict__ Cp, int ldc,
    const float* __restrict__ Res, int K,
    const float* __restrict__ bias, u16* __restrict__ dl_out) {
  __shared__ __align__(16) u16 a_s[128 * 64];
  __shared__ __align__(16) u16 b_s[128 * 64];
  const int tid = threadIdx.x;
  const int w = tid >> 6, l = tid & 63;
  const int wr = w >> 1, wc = w & 1;
  const int nbx = gridDim.x;
  int lin = blockIdx.y * nbx + blockIdx.x;
  int cpx = (nbx * gridDim.y) >> 3;
  int swz = (lin & 7) * cpx + (lin >> 3);
  const int bi = swz % nbx, bj = swz / nbx;
  const int lrow = l >> 3;                    // lane's row-in-8 within a 1KB chunk
  const int scol = ((l & 7) ^ lrow) * 16;     // inverse-swizzled source byte-in-row

  f32x4 acc[4][4] = {};

  const u16* Abase = A + (size_t)(bi * 128 + w * 8 + lrow) * lda;
  const u16* Bbase = B + (size_t)(bj * 128 + w * 8 + lrow) * ldb;

  for (int k0 = 0; k0 < K; k0 += 64) {
#pragma unroll
    for (int c = 0; c < 4; c++) {
      const char* ga = (const char*)(Abase + (size_t)(c * 32) * lda + k0) + scol;
      const char* gb = (const char*)(Bbase + (size_t)(c * 32) * ldb + k0) + scol;
      gload_lds16(ga, (char*)a_s + c * 4096 + w * 1024);
      gload_lds16(gb, (char*)b_s + c * 4096 + w * 1024);
    }
    __syncthreads();
#pragma unroll
    for (int kk = 0; kk < 2; kk++) {
      bf16x8 af[4], bfr[4];
#pragma unroll
      for (int m = 0; m < 4; m++) {
        int fr = wr * 64 + m * 16 + (l & 15);
        int cb = (kk * 64 + ((l >> 4) << 4)) ^ ((fr & 7) << 4);
        af[m] = *(const bf16x8*)((const char*)a_s + fr * 128 + cb);
      }
#pragma unroll
      for (int n = 0; n < 4; n++) {
        int fr = wc * 64 + n * 16 + (l & 15);
        int cb = (kk * 64 + ((l >> 4) << 4)) ^ ((fr & 7) << 4);
        bfr[n] = *(const bf16x8*)((const char*)b_s + fr * 128 + cb);
      }
#pragma unroll
      for (int m = 0; m < 4; m++)
#pragma unroll
        for (int n = 0; n < 4; n++)
          acc[m][n] = __builtin_amdgcn_mfma_f32_16x16x32_bf16(af[m], bfr[n], acc[m][n], 0, 0, 0);
    }
    __syncthreads();
  }
  const int col0 = bj * 128 + wc * 64 + (l & 15);
  const int row0 = bi * 128 + wr * 64 + (l >> 4) * 4;
#pragma unroll
  for (int m = 0; m < 4; m++)
#pragma unroll
    for (int n = 0; n < 4; n++) {
      int col = col0 + n * 16;
      float bv = 0.f;
      if constexpr (MODE == 3) bv = bias[col];
#pragma unroll
      for (int r = 0; r < 4; r++) {
        size_t row = (size_t)(row0 + m * 16 + r);
        float v = acc[m][n][r];
        if constexpr (MODE == 0) {
          ((u16*)Cp)[row * ldc + col] = f2bf(v);
        } else if constexpr (MODE == 1) {
          ((float*)Cp)[row * ldc + col] = v;
          if (col < 64) dl_out[row * 64 + col] = f2bf(v);
        } else if constexpr (MODE == 2) {
          v += Res[row * ldc + col];
          ((float*)Cp)[row * ldc + col] = v;
        } else {
          // fast softplus: log(1+exp(s)) via HW trans; s->-inf => 0 (dt=1e-3),
          // s large => exp->inf => log->inf => fmin caps at 0.1.
          float s = v + bv;
          float sp = __logf(1.f + __expf(s));
          float dtv = fminf(sp + 1e-3f, 0.1f);
          ((u16*)Cp)[row * ldc + col] = f2h(dtv);
        }
      }
    }
}

// ---------------- causal depthwise conv (width 4) + SiLU; bf16 in, bf16 out ----------------
__global__ __launch_bounds__(256) void conv_silu_kernel(const u16* __restrict__ xz,
    const float* __restrict__ conv_w, const float* __restrict__ conv_b,
    u16* __restrict__ u) {
  size_t gid = (size_t)blockIdx.x * 256 + threadIdx.x;
  int c = (int)(gid & 255);
  size_t i = gid >> 8;
  int t = (int)(i & (TT - 1));
  int d0 = c * 8;
  const u16* base = xz + i * 4096 + d0;
  ushort8_t r0 = *(const ushort8_t*)base;
  ushort8_t r1 = 0, r2 = 0, r3 = 0;
  if (t >= 1) r1 = *(const ushort8_t*)(base - 4096);
  if (t >= 2) r2 = *(const ushort8_t*)(base - 2 * 4096);
  if (t >= 3) r3 = *(const ushort8_t*)(base - 3 * 4096);
  float cbv[8];
  *(float4*)&cbv[0] = *(const float4*)(conv_b + d0);
  *(float4*)&cbv[4] = *(const float4*)(conv_b + d0 + 4);
  ushort8_t o;
#pragma unroll
  for (int j = 0; j < 8; j++) {
    float4 w = *(const float4*)(conv_w + (size_t)(d0 + j) * 4);
    float a = cbv[j] + w.w * bf2f(r0[j]) + w.z * bf2f(r1[j])
            + w.y * bf2f(r2[j]) + w.x * bf2f(r3[j]);
    a = a * __builtin_amdgcn_rcpf(1.f + EXP2(-a * L2E));
    o[j] = f2bf(a);
  }
  *(ushort8_t*)(u + i * 2048 + d0) = o;
}

// ---------------- scan phase 1: local chunk scan from h=0; writes y_local (f16) over u ----
// n-split: lanes 2k/2k+1 share d, each owns 8 of 16 states; partial y combined by shfl_xor.
// Double-buffered async LDS staging (stage w+1 issued after the barrier -> overlaps compute).
__global__ __launch_bounds__(256) void scan_part1(u16* u_g,
    const u16* __restrict__ dt_g, const float* __restrict__ xbc,
    const float* __restrict__ log_A, const float* __restrict__ D_param,
    float* __restrict__ hbuf, float* __restrict__ Sbuf) {
  int d0 = blockIdx.x * 128;
  int c  = blockIdx.y;
  int b  = blockIdx.z;
  int tid = threadIdx.x;
  int w = tid >> 6, l = tid & 63;
  int dl = tid >> 1, q = tid & 1, q8 = q << 3;
  int d = d0 + dl;
  __shared__ __align__(16) u16 u_s[2][SW][128];     // 8K
  __shared__ __align__(16) u16 dts[2][SW][128];     // 8K
  __shared__ __align__(16) float bc_s[2][SW][32];   // 4K (B | C)

  float A2[8];
  {
    float4 la0 = *(const float4*)(log_A + (size_t)d * 16 + q8);
    float4 la1 = *(const float4*)(log_A + (size_t)d * 16 + q8 + 4);
    A2[0] = -EXP2(la0.x * L2E) * L2E; A2[1] = -EXP2(la0.y * L2E) * L2E;
    A2[2] = -EXP2(la0.z * L2E) * L2E; A2[3] = -EXP2(la0.w * L2E) * L2E;
    A2[4] = -EXP2(la1.x * L2E) * L2E; A2[5] = -EXP2(la1.y * L2E) * L2E;
    A2[6] = -EXP2(la1.z * L2E) * L2E; A2[7] = -EXP2(la1.w * L2E) * L2E;
  }
  float Dp = D_param[d];
  float h[8] = {};
  float sdt = 0.f;
  size_t t0 = (size_t)b * TT + (size_t)c * CHL;
  const int sr = w * 4 + (l >> 4);        // staging row in window
  const int sc = (l & 15) * 8;            // staging col (u16 units)
  u16* up = u_g + t0 * 2048 + d;          // y_local out (f16, same thread pair)

#define P1STAGE(wnd, pb) { size_t i0_ = t0 + (size_t)(wnd) * SW;                          \
    gload_lds16(u_g  + (i0_ + sr) * 2048 + d0 + sc, (char*)u_s[pb] + w * 1024);           \
    gload_lds16(dt_g + (i0_ + sr) * 4096 + d0 + sc, (char*)dts[pb] + w * 1024);           \
    if (w < 2) gload_lds16(xbc + (i0_ + w * 8 + (l >> 3)) * XBCS + 64 + (l & 7) * 4,      \
                           (char*)bc_s[pb] + w * 1024); }

  P1STAGE(0, 0);
  for (int wnd = 0; wnd < CHL / SW; wnd++) {
    int pb = wnd & 1;
    __syncthreads();                       // buf[pb] landed; buf[pb^1] readers done
    if (wnd + 1 < CHL / SW) P1STAGE(wnd + 1, pb ^ 1);
#pragma unroll 4
    for (int tt = 0; tt < SW; tt++) {
      float dtv = h2f(dts[pb][tt][dl]);
      float uv  = bf2f(u_s[pb][tt][dl]);
      sdt += dtv;
      float xin = dtv * uv;
      float yv = q ? 0.f : uv * Dp;
      float4 B0 = *(const float4*)&bc_s[pb][tt][q8];
      float4 B1 = *(const float4*)&bc_s[pb][tt][q8 + 4];
      float4 C0 = *(const float4*)&bc_s[pb][tt][16 + q8];
      float4 C1 = *(const float4*)&bc_s[pb][tt][16 + q8 + 4];
      h[0] = __builtin_fmaf(EXP2(dtv * A2[0]), h[0], xin * B0.x); yv = __builtin_fmaf(h[0], C0.x, yv);
      h[1] = __builtin_fmaf(EXP2(dtv * A2[1]), h[1], xin * B0.y); yv = __builtin_fmaf(h[1], C0.y, yv);
      h[2] = __builtin_fmaf(EXP2(dtv * A2[2]), h[2], xin * B0.z); yv = __builtin_fmaf(h[2], C0.z, yv);
      h[3] = __builtin_fmaf(EXP2(dtv * A2[3]), h[3], xin * B0.w); yv = __builtin_fmaf(h[3], C0.w, yv);
      h[4] = __builtin_fmaf(EXP2(dtv * A2[4]), h[4], xin * B1.x); yv = __builtin_fmaf(h[4], C1.x, yv);
      h[5] = __builtin_fmaf(EXP2(dtv * A2[5]), h[5], xin * B1.y); yv = __builtin_fmaf(h[5], C1.y, yv);
      h[6] = __builtin_fmaf(EXP2(dtv * A2[6]), h[6], xin * B1.z); yv = __builtin_fmaf(h[6], C1.z, yv);
      h[7] = __builtin_fmaf(EXP2(dtv * A2[7]), h[7], xin * B1.w); yv = __builtin_fmaf(h[7], C1.w, yv);
      yv += __shfl_xor(yv, 1, 64);
      if (q == 0) *up = f2h(yv);           // y_local (f16) over dead u
      up += 2048;
    }
  }
  float* hp = hbuf + (((size_t)b * NCH + c) * 16 + q8) * DN + d;
#pragma unroll
  for (int k = 0; k < 8; k++) hp[(size_t)k * DN] = h[k];
  if (q == 0) Sbuf[((size_t)b * NCH + c) * DN + d] = sdt;
#undef P1STAGE
}

// ---------------- scan phase 2: sequential chunk combine (in-place h_end -> h_start) -------
// hbuf layout [b][c][n][d]; thread per (b,n,d) with d fastest -> coalesced.
__global__ __launch_bounds__(256) void scan_combine(const float* __restrict__ log_A,
    const float* __restrict__ Sbuf, float* __restrict__ hbuf) {
  int idx = blockIdx.x * 256 + threadIdx.x;    // over B*16*DN
  int dd = idx & (DN - 1), n = (idx >> 11) & 15, b = idx >> 15;
  float A2 = -EXP2(log_A[(size_t)dd * 16 + n] * L2E) * L2E;
  float h = 0.f;
#pragma unroll
  for (int c = 0; c < NCH; c++) {
    size_t off = (((size_t)b * NCH + c) * 16 + n) * DN + dd;
    float hl = hbuf[off];
    float P = EXP2(A2 * Sbuf[((size_t)b * NCH + c) * DN + dd]);
    hbuf[off] = h;                 // now holds h_start for chunk c
    h = hl + P * h;
  }
}

// ---------------- scan phase 3: y = (y_local + C.(exp(A*cum) o h_start)) * silu(z) --------
__global__ __launch_bounds__(256) void scan_part2(u16* yl,
    const u16* __restrict__ xz, const float* __restrict__ xbc,
    const u16* __restrict__ dt_g, const float* __restrict__ log_A,
    const float* __restrict__ hbuf) {
  int d0 = blockIdx.x * 128;
  int c  = blockIdx.y;
  int b  = blockIdx.z;
  int tid = threadIdx.x;
  int w = tid >> 6, l = tid & 63;
  int dl = tid >> 1, q = tid & 1, q8 = q << 3;
  int d = d0 + dl;
  __shared__ __align__(16) u16 yls[2][SW][128];     // 8K
  __shared__ __align__(16) u16 z_s[2][SW][128];     // 8K
  __shared__ __align__(16) u16 dts[2][SW][128];     // 8K
  __shared__ __align__(16) float c_s[2][SW][16];    // 2K

  float A2[8];
  {
    float4 la0 = *(const float4*)(log_A + (size_t)d * 16 + q8);
    float4 la1 = *(const float4*)(log_A + (size_t)d * 16 + q8 + 4);
    A2[0] = -EXP2(la0.x * L2E) * L2E; A2[1] = -EXP2(la0.y * L2E) * L2E;
    A2[2] = -EXP2(la0.z * L2E) * L2E; A2[3] = -EXP2(la0.w * L2E) * L2E;
    A2[4] = -EXP2(la1.x * L2E) * L2E; A2[5] = -EXP2(la1.y * L2E) * L2E;
    A2[6] = -EXP2(la1.z * L2E) * L2E; A2[7] = -EXP2(la1.w * L2E) * L2E;
  }
  float hs[8];
  {
    const float* hp = hbuf + (((size_t)b * NCH + c) * 16 + q8) * DN + d;
#pragma unroll
    for (int k = 0; k < 8; k++) hs[k] = hp[(size_t)k * DN];
  }
  float cum = 0.f;
  size_t t0 = (size_t)b * TT + (size_t)c * CHL;
  const int sr = w * 4 + (l >> 4);
  const int sc = (l & 15) * 8;
  u16* ylp = yl + t0 * 2048 + d;

#define P2STAGE(wnd, pb) { size_t i0_ = t0 + (size_t)(wnd) * SW;                          \
    gload_lds16(yl   + (i0_ + sr) * 2048 + d0 + sc, (char*)yls[pb] + w * 1024);           \
    gload_lds16(xz   + (i0_ + sr) * 4096 + 2048 + d0 + sc, (char*)z_s[pb] + w * 1024);    \
    gload_lds16(dt_g + (i0_ + sr) * 4096 + d0 + sc, (char*)dts[pb] + w * 1024);           \
    if (w == 0) gload_lds16(xbc + (i0_ + (l >> 2)) * XBCS + 80 + (l & 3) * 4,             \
                            (char*)c_s[pb]); }

  P2STAGE(0, 0);
  for (int wnd = 0; wnd < CHL / SW; wnd++) {
    int pb = wnd & 1;
    __syncthreads();
    if (wnd + 1 < CHL / SW) P2STAGE(wnd + 1, pb ^ 1);
#pragma unroll 4
    for (int tt = 0; tt < SW; tt++) {
      float dtv = h2f(dts[pb][tt][dl]);
      cum += dtv;
      float4 C0 = *(const float4*)&c_s[pb][tt][q8];
      float4 C1 = *(const float4*)&c_s[pb][tt][q8 + 4];
      float yv = C0.x * (EXP2(cum * A2[0]) * hs[0]) + C0.y * (EXP2(cum * A2[1]) * hs[1])
               + C0.z * (EXP2(cum * A2[2]) * hs[2]) + C0.w * (EXP2(cum * A2[3]) * hs[3])
               + C1.x * (EXP2(cum * A2[4]) * hs[4]) + C1.y * (EXP2(cum * A2[5]) * hs[5])
               + C1.z * (EXP2(cum * A2[6]) * hs[6]) + C1.w * (EXP2(cum * A2[7]) * hs[7]);
      if (q == 0) yv += h2f(yls[pb][tt][dl]);
      yv += __shfl_xor(yv, 1, 64);
      float zv = bf2f(z_s[pb][tt][dl]);
      float sig = __builtin_amdgcn_rcpf(1.f + EXP2(-zv * L2E));
      if (q == 0) *ylp = f2bf(yv * zv * sig);   // final y (bf16) over y_local
      ylp += 2048;
    }
  }
#undef P2STAGE
}

extern "C" void kernel_launch(void* const* d_in, const int* in_sizes, int n_in,
                              void* d_out, int out_size, void* d_ws, size_t ws_size,
                              hipStream_t stream) {
  const float* x       = (const float*)d_in[0];
  const float* W_in    = (const float*)d_in[1];
  const float* conv_w  = (const float*)d_in[2];
  const float* conv_b  = (const float*)d_in[3];
  const float* W_x     = (const float*)d_in[4];
  const float* W_dt    = (const float*)d_in[5];
  const float* b_dt    = (const float*)d_in[6];
  const float* log_A   = (const float*)d_in[7];
  const float* D_param = (const float*)d_in[8];
  const float* W_out   = (const float*)d_in[9];
  const float* ln_w    = (const float*)d_in[10];
  const float* ln_b    = (const float*)d_in[11];
  float* out = (float*)d_out;

  // ws (proven >=198MiB): xz 128MiB + u 64MiB + 6MiB tail (W_out bf16 staging)
  size_t need = (size_t)MROWS * 4096 * 2 + (size_t)MROWS * DN * 2 + (size_t)MROWS * 96 * 4;
  if (ws_size < need) return;
  u16*   xz  = (u16*)d_ws;                        // 16384 x 4096 bf16 (x_inner | z); x_inner
                                                  // cols become f16 dt after dt_gemm
  u16*   u   = xz + (size_t)MROWS * 4096;         // 16384 x 2048 bf16 (u -> y_local -> y)
  u16*   W_out_b = (u16*)(u + (size_t)MROWS * DN);// 4MiB, used only for gemm2 staging

  // d_out (64MiB) staging: all dead before gemm2 fully overwrites d_out
  u16*   xn_b    = (u16*)d_out;                                  // [0,32)MiB, dead after gemm1
  float* xbc     = (float*)d_out;                                // [0,8)MiB, written AFTER gemm1
  float* hbuf    = (float*)((char*)d_out + (8u << 20));          // [8,40)MiB (4*64*16*2048 f32)
  u16*   W_in_b  = (u16*)((char*)d_out + (40u << 20));           // [40,48)MiB
  float* Sbuf    = (float*)((char*)d_out + (48u << 20));         // [48,50)MiB
  u16*   W_x_b   = (u16*)((char*)d_out + (50u << 20));           // [50,50.5)MiB
  u16*   W_dt_b  = (u16*)((char*)d_out + (50u << 20) + (512u << 10)); // [50.5,50.75) 2048x64 bf16
  u16*   dl_b    = (u16*)((char*)d_out + (51u << 20));           // [51,53)MiB 16384x64 bf16

  cvt_wx_kernel<<<(128 * 2048 / 4) / 256, 256, 0, stream>>>(W_x, W_x_b);
  cvt_bf16_kernel<<<(2048 * 64 / 4) / 256, 256, 0, stream>>>(W_dt, W_dt_b, 2048 * 64 / 4);
  ln_kernel<<<MROWS, 256, 0, stream>>>(x, ln_w, ln_b, xn_b);
  cvt_bf16_kernel<<<(4096 * 1024 / 4) / 256, 256, 0, stream>>>(W_in, W_in_b, 4096 * 1024 / 4);
  gemm_mfma_nt<0><<<dim3(MROWS / 128, 4096 / 128), 256, 0, stream>>>(
      xn_b, DM, W_in_b, DM, xz, 4096, nullptr, DM, nullptr, nullptr);
  conv_silu_kernel<<<MROWS, 256, 0, stream>>>(xz, conv_w, conv_b, u);
  // xbc = u @ W_x.T via MFMA (N padded 96->128); also emits dl bf16; overwrites dead xn_b
  gemm_mfma_nt<1><<<dim3(MROWS / 128, XBCS / 128), 256, 0, stream>>>(
      u, DN, W_x_b, DN, xbc, XBCS, nullptr, DN, nullptr, dl_b);
  // dt = clamp(softplus(dl @ W_dt.T + b_dt)+1e-3) -> f16 into dead x_inner cols of xz
  gemm_mfma_nt<3><<<dim3(MROWS / 128, DN / 128), 256, 0, stream>>>(
      dl_b, 64, W_dt_b, 64, xz, 4096, nullptr, 64, b_dt, nullptr);
  scan_part1<<<dim3(DN / 128, NCH, 4), 256, 0, stream>>>(
      u, xz, xbc, log_A, D_param, hbuf, Sbuf);
  scan_combine<<<4 * DN * 16 / 256, 256, 0, stream>>>(log_A, Sbuf, hbuf);
  scan_part2<<<dim3(DN / 128, NCH, 4), 256, 0, stream>>>(
      u, xz, xbc, xz, log_A, hbuf);
  cvt_bf16_kernel<<<(1024 * 2048 / 4) / 256, 256, 0, stream>>>(W_out, W_out_b, 1024 * 2048 / 4);
  gemm_mfma_nt<2><<<dim3(MROWS / 128, 1024 / 128), 256, 0, stream>>>(
      u, DN, W_out_b, DN, out, DM, x, DN, nullptr, nullptr);
}

// Round 7
// 665.447 us; speedup vs baseline: 1.2341x; 1.0222x over previous
//
#include <hip/hip_runtime.h>
#include <cstdint>
#include <cstddef>

#define TT 4096
#define DM 1024
#define DN 2048
#define MROWS 16384  // B*T
#define NCH 64       // scan chunks per sequence
#define CHL 64       // chunk length (TT/NCH)
#define SW 16        // staging window inside a chunk
#define XBCS 128     // xbc row stride (f32), padded from 96 for MFMA GEMM

typedef unsigned short u16;
typedef u16 ushort8_t __attribute__((ext_vector_type(8)));
typedef u16 ushort4_t __attribute__((ext_vector_type(4)));
typedef short bf16x8 __attribute__((ext_vector_type(8)));   // MFMA A/B frag (4 VGPR)
typedef float f32x4 __attribute__((ext_vector_type(4)));    // MFMA C/D frag

#define EXP2(x) __builtin_amdgcn_exp2f(x)
#define L2E 1.44269504f

__device__ __forceinline__ float bf2f(u16 b) {
  return __uint_as_float(((unsigned int)b) << 16);
}
__device__ __forceinline__ u16 f2bf(float f) {
  unsigned int u = __float_as_uint(f);
  u = u + 0x7FFFu + ((u >> 16) & 1u);   // round-to-nearest-even
  return (u16)(u >> 16);
}
__device__ __forceinline__ u16 f2h(float f) {
  _Float16 h = (_Float16)f;
  return __builtin_bit_cast(u16, h);
}
__device__ __forceinline__ float h2f(u16 v) {
  return (float)__builtin_bit_cast(_Float16, v);
}

__device__ __forceinline__ void gload_lds16(const void* g, void* l) {
  __builtin_amdgcn_global_load_lds(
      (const __attribute__((address_space(1))) unsigned int*)g,
      (__attribute__((address_space(3))) unsigned int*)l, 16, 0, 0);
}

// ---------------- f32 -> bf16 converter (weights) ----------------
__global__ __launch_bounds__(256) void cvt_bf16_kernel(const float* __restrict__ in,
    u16* __restrict__ out, int n4) {
  int i = blockIdx.x * 256 + threadIdx.x;
  if (i >= n4) return;
  float4 v = ((const float4*)in)[i];
  ushort4_t o; o[0] = f2bf(v.x); o[1] = f2bf(v.y); o[2] = f2bf(v.z); o[3] = f2bf(v.w);
  ((ushort4_t*)out)[i] = o;
}

// ---------------- W_x f32(96x2048) -> bf16(128x2048), rows 96..127 zero ----------------
__global__ __launch_bounds__(256) void cvt_wx_kernel(const float* __restrict__ W_x,
    u16* __restrict__ out) {
  int i = blockIdx.x * 256 + threadIdx.x;   // over 128*2048/4 = 65536 float4 slots
  int row = i >> 9;                         // 512 float4 per row
  ushort4_t o;
  if (row < 96) {
    float4 v = ((const float4*)W_x)[i];
    o[0] = f2bf(v.x); o[1] = f2bf(v.y); o[2] = f2bf(v.z); o[3] = f2bf(v.w);
  } else {
    o[0] = 0; o[1] = 0; o[2] = 0; o[3] = 0;
  }
  ((ushort4_t*)out)[i] = o;
}

// ---------------- LayerNorm -> bf16 out ----------------
__global__ __launch_bounds__(256) void ln_kernel(const float* __restrict__ x,
    const float* __restrict__ ln_w, const float* __restrict__ ln_b,
    u16* __restrict__ xn) {
  int row = blockIdx.x;
  int tid = threadIdx.x;
  const float4* xr = (const float4*)(x + (size_t)row * DM);
  float4 v = xr[tid];
  float s  = v.x + v.y + v.z + v.w;
  float s2 = v.x*v.x + v.y*v.y + v.z*v.z + v.w*v.w;
#pragma unroll
  for (int o = 32; o > 0; o >>= 1) { s += __shfl_down(s, o, 64); s2 += __shfl_down(s2, o, 64); }
  __shared__ float red[2][4];
  __shared__ float mv[2];
  int wid = tid >> 6, lane = tid & 63;
  if (lane == 0) { red[0][wid] = s; red[1][wid] = s2; }
  __syncthreads();
  if (tid == 0) {
    float a  = red[0][0] + red[0][1] + red[0][2] + red[0][3];
    float b2 = red[1][0] + red[1][1] + red[1][2] + red[1][3];
    float mean = a * (1.f / DM);
    float var  = b2 * (1.f / DM) - mean * mean;
    mv[0] = mean; mv[1] = rsqrtf(var + 1e-5f);
  }
  __syncthreads();
  float mean = mv[0], inv = mv[1];
  float4 w = ((const float4*)ln_w)[tid];
  float4 b = ((const float4*)ln_b)[tid];
  ushort4_t o;
  o[0] = f2bf((v.x - mean) * inv * w.x + b.x);
  o[1] = f2bf((v.y - mean) * inv * w.y + b.y);
  o[2] = f2bf((v.z - mean) * inv * w.z + b.z);
  o[3] = f2bf((v.w - mean) * inv * w.w + b.w);
  *(ushort4_t*)(xn + (size_t)row * DM + tid * 4) = o;
}

// ---------------- bf16 MFMA GEMM, NT: C[i][j] = sum_k A[i][k]*B[j][k] -----------
// MODE 0: bf16 out. MODE 1: f32 out + bf16 dl copy of cols<64 (needs bj==0 grid).
// MODE 2: f32 out + residual add. MODE 3: f16 out = clamp(softplus(v+bias)+1e-3).
// XCD-aware supertile swizzle: linear HW block id round-robins XCDs (id%8);
// within an XCD's chunk iterate bj FASTEST so its njx B-panels stay L2-resident
// and each A-panel is fetched once per XCD (L3 serves repeats across XCDs).
template<int MODE>
__global__ __launch_bounds__(256) void gemm_mfma_nt(
    const u16* __restrict__ A, int lda,
    const u16* __restrict__ B, int ldb,
    void* __restrict__ Cp, int ldc,
    const float* __restrict__ Res, int K,
    const float* __restrict__ bias, u16* __restrict__ dl_out) {
  __shared__ __align__(16) u16 a_s[128 * 64];
  __shared__ __align__(16) u16 b_s[128 * 64];
  const int tid = threadIdx.x;
  const int w = tid >> 6, l = tid & 63;
  const int wr = w >> 1, wc = w & 1;
  const int nbx = gridDim.x, gy = gridDim.y;
  int lin = blockIdx.y * nbx + blockIdx.x;
  int xcd = lin & 7;                 // HW round-robin XCD assignment of linear id
  int m   = lin >> 3;                // index within this XCD's chunk
  int bi, bj;
  if (gy >= 8) {                     // gy % 8 == 0 for all such grids here
    int njx = gy >> 3;               // bj's owned by this XCD
    bi = m / njx;
    bj = xcd * njx + m % njx;        // bj fastest within chunk
  } else {
    int cpx = (nbx * gy) >> 3;
    int swz = xcd * cpx + m;
    bi = swz % nbx; bj = swz / nbx;
  }
  const int lrow = l >> 3;                    // lane's row-in-8 within a 1KB chunk
  const int scol = ((l & 7) ^ lrow) * 16;     // inverse-swizzled source byte-in-row

  f32x4 acc[4][4] = {};

  const u16* Abase = A + (size_t)(bi * 128 + w * 8 + lrow) * lda;
  const u16* Bbase = B + (size_t)(bj * 128 + w * 8 + lrow) * ldb;

  for (int k0 = 0; k0 < K; k0 += 64) {
#pragma unroll
    for (int c = 0; c < 4; c++) {
      const char* ga = (const char*)(Abase + (size_t)(c * 32) * lda + k0) + scol;
      const char* gb = (const char*)(Bbase + (size_t)(c * 32) * ldb + k0) + scol;
      gload_lds16(ga, (char*)a_s + c * 4096 + w * 1024);
      gload_lds16(gb, (char*)b_s + c * 4096 + w * 1024);
    }
    __syncthreads();
#pragma unroll
    for (int kk = 0; kk < 2; kk++) {
      bf16x8 af[4], bfr[4];
#pragma unroll
      for (int m2 = 0; m2 < 4; m2++) {
        int fr = wr * 64 + m2 * 16 + (l & 15);
        int cb = (kk * 64 + ((l >> 4) << 4)) ^ ((fr & 7) << 4);
        af[m2] = *(const bf16x8*)((const char*)a_s + fr * 128 + cb);
      }
#pragma unroll
      for (int n = 0; n < 4; n++) {
        int fr = wc * 64 + n * 16 + (l & 15);
        int cb = (kk * 64 + ((l >> 4) << 4)) ^ ((fr & 7) << 4);
        bfr[n] = *(const bf16x8*)((const char*)b_s + fr * 128 + cb);
      }
#pragma unroll
      for (int m2 = 0; m2 < 4; m2++)
#pragma unroll
        for (int n = 0; n < 4; n++)
          acc[m2][n] = __builtin_amdgcn_mfma_f32_16x16x32_bf16(af[m2], bfr[n], acc[m2][n], 0, 0, 0);
    }
    __syncthreads();
  }
  const int col0 = bj * 128 + wc * 64 + (l & 15);
  const int row0 = bi * 128 + wr * 64 + (l >> 4) * 4;
#pragma unroll
  for (int m2 = 0; m2 < 4; m2++)
#pragma unroll
    for (int n = 0; n < 4; n++) {
      int col = col0 + n * 16;
      float bv = 0.f;
      if constexpr (MODE == 3) bv = bias[col];
#pragma unroll
      for (int r = 0; r < 4; r++) {
        size_t row = (size_t)(row0 + m2 * 16 + r);
        float v = acc[m2][n][r];
        if constexpr (MODE == 0) {
          ((u16*)Cp)[row * ldc + col] = f2bf(v);
        } else if constexpr (MODE == 1) {
          ((float*)Cp)[row * ldc + col] = v;
          if (col < 64) dl_out[row * 64 + col] = f2bf(v);
        } else if constexpr (MODE == 2) {
          v += Res[row * ldc + col];
          ((float*)Cp)[row * ldc + col] = v;
        } else {
          // fast softplus: log(1+exp(s)) via HW trans; s->-inf => 0 (dt=1e-3),
          // s large => exp->inf => log->inf => fmin caps at 0.1.
          float s = v + bv;
          float sp = __logf(1.f + __expf(s));
          float dtv = fminf(sp + 1e-3f, 0.1f);
          ((u16*)Cp)[row * ldc + col] = f2h(dtv);
        }
      }
    }
}

// ---------------- causal depthwise conv (width 4) + SiLU; bf16 in, bf16 out ----------------
__global__ __launch_bounds__(256) void conv_silu_kernel(const u16* __restrict__ xz,
    const float* __restrict__ conv_w, const float* __restrict__ conv_b,
    u16* __restrict__ u) {
  size_t gid = (size_t)blockIdx.x * 256 + threadIdx.x;
  int c = (int)(gid & 255);
  size_t i = gid >> 8;
  int t = (int)(i & (TT - 1));
  int d0 = c * 8;
  const u16* base = xz + i * 4096 + d0;
  ushort8_t r0 = *(const ushort8_t*)base;
  ushort8_t r1 = 0, r2 = 0, r3 = 0;
  if (t >= 1) r1 = *(const ushort8_t*)(base - 4096);
  if (t >= 2) r2 = *(const ushort8_t*)(base - 2 * 4096);
  if (t >= 3) r3 = *(const ushort8_t*)(base - 3 * 4096);
  float cbv[8];
  *(float4*)&cbv[0] = *(const float4*)(conv_b + d0);
  *(float4*)&cbv[4] = *(const float4*)(conv_b + d0 + 4);
  ushort8_t o;
#pragma unroll
  for (int j = 0; j < 8; j++) {
    float4 w = *(const float4*)(conv_w + (size_t)(d0 + j) * 4);
    float a = cbv[j] + w.w * bf2f(r0[j]) + w.z * bf2f(r1[j])
            + w.y * bf2f(r2[j]) + w.x * bf2f(r3[j]);
    a = a * __builtin_amdgcn_rcpf(1.f + EXP2(-a * L2E));
    o[j] = f2bf(a);
  }
  *(ushort8_t*)(u + i * 2048 + d0) = o;
}

// ---------------- scan phase 1: local chunk scan from h=0; writes y_local (f16) over u ----
// n-split: lanes 2k/2k+1 share d, each owns 8 of 16 states; partial y combined by shfl_xor.
// Double-buffered async LDS staging (stage w+1 issued after the barrier -> overlaps compute).
__global__ __launch_bounds__(256) void scan_part1(u16* u_g,
    const u16* __restrict__ dt_g, const float* __restrict__ xbc,
    const float* __restrict__ log_A, const float* __restrict__ D_param,
    float* __restrict__ hbuf, float* __restrict__ Sbuf) {
  int d0 = blockIdx.x * 128;
  int c  = blockIdx.y;
  int b  = blockIdx.z;
  int tid = threadIdx.x;
  int w = tid >> 6, l = tid & 63;
  int dl = tid >> 1, q = tid & 1, q8 = q << 3;
  int d = d0 + dl;
  __shared__ __align__(16) u16 u_s[2][SW][128];     // 8K
  __shared__ __align__(16) u16 dts[2][SW][128];     // 8K
  __shared__ __align__(16) float bc_s[2][SW][32];   // 4K (B | C)

  float A2[8];
  {
    float4 la0 = *(const float4*)(log_A + (size_t)d * 16 + q8);
    float4 la1 = *(const float4*)(log_A + (size_t)d * 16 + q8 + 4);
    A2[0] = -EXP2(la0.x * L2E) * L2E; A2[1] = -EXP2(la0.y * L2E) * L2E;
    A2[2] = -EXP2(la0.z * L2E) * L2E; A2[3] = -EXP2(la0.w * L2E) * L2E;
    A2[4] = -EXP2(la1.x * L2E) * L2E; A2[5] = -EXP2(la1.y * L2E) * L2E;
    A2[6] = -EXP2(la1.z * L2E) * L2E; A2[7] = -EXP2(la1.w * L2E) * L2E;
  }
  float Dp = D_param[d];
  float h[8] = {};
  float sdt = 0.f;
  size_t t0 = (size_t)b * TT + (size_t)c * CHL;
  const int sr = w * 4 + (l >> 4);        // staging row in window
  const int sc = (l & 15) * 8;            // staging col (u16 units)
  u16* up = u_g + t0 * 2048 + d;          // y_local out (f16, same thread pair)

#define P1STAGE(wnd, pb) { size_t i0_ = t0 + (size_t)(wnd) * SW;                          \
    gload_lds16(u_g  + (i0_ + sr) * 2048 + d0 + sc, (char*)u_s[pb] + w * 1024);           \
    gload_lds16(dt_g + (i0_ + sr) * 4096 + d0 + sc, (char*)dts[pb] + w * 1024);           \
    if (w < 2) gload_lds16(xbc + (i0_ + w * 8 + (l >> 3)) * XBCS + 64 + (l & 7) * 4,      \
                           (char*)bc_s[pb] + w * 1024); }

  P1STAGE(0, 0);
  for (int wnd = 0; wnd < CHL / SW; wnd++) {
    int pb = wnd & 1;
    __syncthreads();                       // buf[pb] landed; buf[pb^1] readers done
    if (wnd + 1 < CHL / SW) P1STAGE(wnd + 1, pb ^ 1);
#pragma unroll 4
    for (int tt = 0; tt < SW; tt++) {
      float dtv = h2f(dts[pb][tt][dl]);
      float uv  = bf2f(u_s[pb][tt][dl]);
      sdt += dtv;
      float xin = dtv * uv;
      float yv = q ? 0.f : uv * Dp;
      float4 B0 = *(const float4*)&bc_s[pb][tt][q8];
      float4 B1 = *(const float4*)&bc_s[pb][tt][q8 + 4];
      float4 C0 = *(const float4*)&bc_s[pb][tt][16 + q8];
      float4 C1 = *(const float4*)&bc_s[pb][tt][16 + q8 + 4];
      h[0] = __builtin_fmaf(EXP2(dtv * A2[0]), h[0], xin * B0.x); yv = __builtin_fmaf(h[0], C0.x, yv);
      h[1] = __builtin_fmaf(EXP2(dtv * A2[1]), h[1], xin * B0.y); yv = __builtin_fmaf(h[1], C0.y, yv);
      h[2] = __builtin_fmaf(EXP2(dtv * A2[2]), h[2], xin * B0.z); yv = __builtin_fmaf(h[2], C0.z, yv);
      h[3] = __builtin_fmaf(EXP2(dtv * A2[3]), h[3], xin * B0.w); yv = __builtin_fmaf(h[3], C0.w, yv);
      h[4] = __builtin_fmaf(EXP2(dtv * A2[4]), h[4], xin * B1.x); yv = __builtin_fmaf(h[4], C1.x, yv);
      h[5] = __builtin_fmaf(EXP2(dtv * A2[5]), h[5], xin * B1.y); yv = __builtin_fmaf(h[5], C1.y, yv);
      h[6] = __builtin_fmaf(EXP2(dtv * A2[6]), h[6], xin * B1.z); yv = __builtin_fmaf(h[6], C1.z, yv);
      h[7] = __builtin_fmaf(EXP2(dtv * A2[7]), h[7], xin * B1.w); yv = __builtin_fmaf(h[7], C1.w, yv);
      yv += __shfl_xor(yv, 1, 64);
      if (q == 0) *up = f2h(yv);           // y_local (f16) over dead u
      up += 2048;
    }
  }
  float* hp = hbuf + (((size_t)b * NCH + c) * 16 + q8) * DN + d;
#pragma unroll
  for (int k = 0; k < 8; k++) hp[(size_t)k * DN] = h[k];
  if (q == 0) Sbuf[((size_t)b * NCH + c) * DN + d] = sdt;
#undef P1STAGE
}

// ---------------- scan phase 2: sequential chunk combine (in-place h_end -> h_start) -------
// hbuf layout [b][c][n][d]; thread per (b,n,d) with d fastest -> coalesced.
__global__ __launch_bounds__(256) void scan_combine(const float* __restrict__ log_A,
    const float* __restrict__ Sbuf, float* __restrict__ hbuf) {
  int idx = blockIdx.x * 256 + threadIdx.x;    // over B*16*DN
  int dd = idx & (DN - 1), n = (idx >> 11) & 15, b = idx >> 15;
  float A2 = -EXP2(log_A[(size_t)dd * 16 + n] * L2E) * L2E;
  float h = 0.f;
#pragma unroll
  for (int c = 0; c < NCH; c++) {
    size_t off = (((size_t)b * NCH + c) * 16 + n) * DN + dd;
    float hl = hbuf[off];
    float P = EXP2(A2 * Sbuf[((size_t)b * NCH + c) * DN + dd]);
    hbuf[off] = h;                 // now holds h_start for chunk c
    h = hl + P * h;
  }
}

// ---------------- scan phase 3: y = (y_local + C.(exp(A*cum) o h_start)) * silu(z) --------
__global__ __launch_bounds__(256) void scan_part2(u16* yl,
    const u16* __restrict__ xz, const float* __restrict__ xbc,
    const u16* __restrict__ dt_g, const float* __restrict__ log_A,
    const float* __restrict__ hbuf) {
  int d0 = blockIdx.x * 128;
  int c  = blockIdx.y;
  int b  = blockIdx.z;
  int tid = threadIdx.x;
  int w = tid >> 6, l = tid & 63;
  int dl = tid >> 1, q = tid & 1, q8 = q << 3;
  int d = d0 + dl;
  __shared__ __align__(16) u16 yls[2][SW][128];     // 8K
  __shared__ __align__(16) u16 z_s[2][SW][128];     // 8K
  __shared__ __align__(16) u16 dts[2][SW][128];     // 8K
  __shared__ __align__(16) float c_s[2][SW][16];    // 2K

  float A2[8];
  {
    float4 la0 = *(const float4*)(log_A + (size_t)d * 16 + q8);
    float4 la1 = *(const float4*)(log_A + (size_t)d * 16 + q8 + 4);
    A2[0] = -EXP2(la0.x * L2E) * L2E; A2[1] = -EXP2(la0.y * L2E) * L2E;
    A2[2] = -EXP2(la0.z * L2E) * L2E; A2[3] = -EXP2(la0.w * L2E) * L2E;
    A2[4] = -EXP2(la1.x * L2E) * L2E; A2[5] = -EXP2(la1.y * L2E) * L2E;
    A2[6] = -EXP2(la1.z * L2E) * L2E; A2[7] = -EXP2(la1.w * L2E) * L2E;
  }
  float hs[8];
  {
    const float* hp = hbuf + (((size_t)b * NCH + c) * 16 + q8) * DN + d;
#pragma unroll
    for (int k = 0; k < 8; k++) hs[k] = hp[(size_t)k * DN];
  }
  float cum = 0.f;
  size_t t0 = (size_t)b * TT + (size_t)c * CHL;
  const int sr = w * 4 + (l >> 4);
  const int sc = (l & 15) * 8;
  u16* ylp = yl + t0 * 2048 + d;

#define P2STAGE(wnd, pb) { size_t i0_ = t0 + (size_t)(wnd) * SW;                          \
    gload_lds16(yl   + (i0_ + sr) * 2048 + d0 + sc, (char*)yls[pb] + w * 1024);           \
    gload_lds16(xz   + (i0_ + sr) * 4096 + 2048 + d0 + sc, (char*)z_s[pb] + w * 1024);    \
    gload_lds16(dt_g + (i0_ + sr) * 4096 + d0 + sc, (char*)dts[pb] + w * 1024);           \
    if (w == 0) gload_lds16(xbc + (i0_ + (l >> 2)) * XBCS + 80 + (l & 3) * 4,             \
                            (char*)c_s[pb]); }

  P2STAGE(0, 0);
  for (int wnd = 0; wnd < CHL / SW; wnd++) {
    int pb = wnd & 1;
    __syncthreads();
    if (wnd + 1 < CHL / SW) P2STAGE(wnd + 1, pb ^ 1);
#pragma unroll 4
    for (int tt = 0; tt < SW; tt++) {
      float dtv = h2f(dts[pb][tt][dl]);
      cum += dtv;
      float4 C0 = *(const float4*)&c_s[pb][tt][q8];
      float4 C1 = *(const float4*)&c_s[pb][tt][q8 + 4];
      float yv = C0.x * (EXP2(cum * A2[0]) * hs[0]) + C0.y * (EXP2(cum * A2[1]) * hs[1])
               + C0.z * (EXP2(cum * A2[2]) * hs[2]) + C0.w * (EXP2(cum * A2[3]) * hs[3])
               + C1.x * (EXP2(cum * A2[4]) * hs[4]) + C1.y * (EXP2(cum * A2[5]) * hs[5])
               + C1.z * (EXP2(cum * A2[6]) * hs[6]) + C1.w * (EXP2(cum * A2[7]) * hs[7]);
      if (q == 0) yv += h2f(yls[pb][tt][dl]);
      yv += __shfl_xor(yv, 1, 64);
      float zv = bf2f(z_s[pb][tt][dl]);
      float sig = __builtin_amdgcn_rcpf(1.f + EXP2(-zv * L2E));
      if (q == 0) *ylp = f2bf(yv * zv * sig);   // final y (bf16) over y_local
      ylp += 2048;
    }
  }
#undef P2STAGE
}

extern "C" void kernel_launch(void* const* d_in, const int* in_sizes, int n_in,
                              void* d_out, int out_size, void* d_ws, size_t ws_size,
                              hipStream_t stream) {
  const float* x       = (const float*)d_in[0];
  const float* W_in    = (const float*)d_in[1];
  const float* conv_w  = (const float*)d_in[2];
  const float* conv_b  = (const float*)d_in[3];
  const float* W_x     = (const float*)d_in[4];
  const float* W_dt    = (const float*)d_in[5];
  const float* b_dt    = (const float*)d_in[6];
  const float* log_A   = (const float*)d_in[7];
  const float* D_param = (const float*)d_in[8];
  const float* W_out   = (const float*)d_in[9];
  const float* ln_w    = (const float*)d_in[10];
  const float* ln_b    = (const float*)d_in[11];
  float* out = (float*)d_out;

  // ws (proven >=198MiB): xz 128MiB + u 64MiB + 6MiB tail (W_out bf16 staging)
  size_t need = (size_t)MROWS * 4096 * 2 + (size_t)MROWS * DN * 2 + (size_t)MROWS * 96 * 4;
  if (ws_size < need) return;
  u16*   xz  = (u16*)d_ws;                        // 16384 x 4096 bf16 (x_inner | z); x_inner
                                                  // cols become f16 dt after dt_gemm
  u16*   u   = xz + (size_t)MROWS * 4096;         // 16384 x 2048 bf16 (u -> y_local -> y)
  u16*   W_out_b = (u16*)(u + (size_t)MROWS * DN);// 4MiB, used only for gemm2 staging

  // d_out (64MiB) staging: all dead before gemm2 fully overwrites d_out
  u16*   xn_b    = (u16*)d_out;                                  // [0,32)MiB, dead after gemm1
  float* xbc     = (float*)d_out;                                // [0,8)MiB, written AFTER gemm1
  float* hbuf    = (float*)((char*)d_out + (8u << 20));          // [8,40)MiB (4*64*16*2048 f32)
  u16*   W_in_b  = (u16*)((char*)d_out + (40u << 20));           // [40,48)MiB
  float* Sbuf    = (float*)((char*)d_out + (48u << 20));         // [48,50)MiB
  u16*   W_x_b   = (u16*)((char*)d_out + (50u << 20));           // [50,50.5)MiB
  u16*   W_dt_b  = (u16*)((char*)d_out + (50u << 20) + (512u << 10)); // [50.5,50.75) 2048x64 bf16
  u16*   dl_b    = (u16*)((char*)d_out + (51u << 20));           // [51,53)MiB 16384x64 bf16

  cvt_wx_kernel<<<(128 * 2048 / 4) / 256, 256, 0, stream>>>(W_x, W_x_b);
  cvt_bf16_kernel<<<(2048 * 64 / 4) / 256, 256, 0, stream>>>(W_dt, W_dt_b, 2048 * 64 / 4);
  ln_kernel<<<MROWS, 256, 0, stream>>>(x, ln_w, ln_b, xn_b);
  cvt_bf16_kernel<<<(4096 * 1024 / 4) / 256, 256, 0, stream>>>(W_in, W_in_b, 4096 * 1024 / 4);
  gemm_mfma_nt<0><<<dim3(MROWS / 128, 4096 / 128), 256, 0, stream>>>(
      xn_b, DM, W_in_b, DM, xz, 4096, nullptr, DM, nullptr, nullptr);
  conv_silu_kernel<<<MROWS, 256, 0, stream>>>(xz, conv_w, conv_b, u);
  // xbc = u @ W_x.T via MFMA (N padded 96->128); also emits dl bf16; overwrites dead xn_b
  gemm_mfma_nt<1><<<dim3(MROWS / 128, XBCS / 128), 256, 0, stream>>>(
      u, DN, W_x_b, DN, xbc, XBCS, nullptr, DN, nullptr, dl_b);
  // dt = clamp(softplus(dl @ W_dt.T + b_dt)+1e-3) -> f16 into dead x_inner cols of xz
  gemm_mfma_nt<3><<<dim3(MROWS / 128, DN / 128), 256, 0, stream>>>(
      dl_b, 64, W_dt_b, 64, xz, 4096, nullptr, 64, b_dt, nullptr);
  scan_part1<<<dim3(DN / 128, NCH, 4), 256, 0, stream>>>(
      u, xz, xbc, log_A, D_param, hbuf, Sbuf);
  scan_combine<<<4 * DN * 16 / 256, 256, 0, stream>>>(log_A, Sbuf, hbuf);
  scan_part2<<<dim3(DN / 128, NCH, 4), 256, 0, stream>>>(
      u, xz, xbc, xz, log_A, hbuf);
  cvt_bf16_kernel<<<(1024 * 2048 / 4) / 256, 256, 0, stream>>>(W_out, W_out_b, 1024 * 2048 / 4);
  gemm_mfma_nt<2><<<dim3(MROWS / 128, 1024 / 128), 256, 0, stream>>>(
      u, DN, W_out_b, DN, out, DM, x, DN, nullptr, nullptr);
}

// Round 8
// 623.516 us; speedup vs baseline: 1.3170x; 1.0672x over previous
//
#include <hip/hip_runtime.h>
#include <cstdint>
#include <cstddef>

#define TT 4096
#define DM 1024
#define DN 2048
#define MROWS 16384  // B*T
#define NCH 64       // scan chunks per sequence
#define CHL 64       // chunk length (TT/NCH)
#define SW 16        // staging window inside a chunk
#define XBCS 128     // xbc row stride (f32), padded from 96 for MFMA GEMM

typedef unsigned short u16;
typedef u16 ushort8_t __attribute__((ext_vector_type(8)));
typedef u16 ushort4_t __attribute__((ext_vector_type(4)));
typedef short bf16x8 __attribute__((ext_vector_type(8)));   // MFMA A/B frag (4 VGPR)
typedef float f32x4 __attribute__((ext_vector_type(4)));    // MFMA C/D frag

#define EXP2(x) __builtin_amdgcn_exp2f(x)
#define L2E 1.44269504f

__device__ __forceinline__ float bf2f(u16 b) {
  return __uint_as_float(((unsigned int)b) << 16);
}
__device__ __forceinline__ u16 f2bf(float f) {
  unsigned int u = __float_as_uint(f);
  u = u + 0x7FFFu + ((u >> 16) & 1u);   // round-to-nearest-even
  return (u16)(u >> 16);
}
__device__ __forceinline__ u16 f2h(float f) {
  _Float16 h = (_Float16)f;
  return __builtin_bit_cast(u16, h);
}
__device__ __forceinline__ float h2f(u16 v) {
  return (float)__builtin_bit_cast(_Float16, v);
}

__device__ __forceinline__ void gload_lds16(const void* g, void* l) {
  __builtin_amdgcn_global_load_lds(
      (const __attribute__((address_space(1))) unsigned int*)g,
      (__attribute__((address_space(3))) unsigned int*)l, 16, 0, 0);
}

#define FENCE() asm volatile("" ::: "memory")

// ---------------- f32 -> bf16 converter (weights) ----------------
__global__ __launch_bounds__(256) void cvt_bf16_kernel(const float* __restrict__ in,
    u16* __restrict__ out, int n4) {
  int i = blockIdx.x * 256 + threadIdx.x;
  if (i >= n4) return;
  float4 v = ((const float4*)in)[i];
  ushort4_t o; o[0] = f2bf(v.x); o[1] = f2bf(v.y); o[2] = f2bf(v.z); o[3] = f2bf(v.w);
  ((ushort4_t*)out)[i] = o;
}

// ---------------- W_x f32(96x2048) -> bf16(128x2048), rows 96..127 zero ----------------
__global__ __launch_bounds__(256) void cvt_wx_kernel(const float* __restrict__ W_x,
    u16* __restrict__ out) {
  int i = blockIdx.x * 256 + threadIdx.x;   // over 128*2048/4 = 65536 float4 slots
  int row = i >> 9;                         // 512 float4 per row
  ushort4_t o;
  if (row < 96) {
    float4 v = ((const float4*)W_x)[i];
    o[0] = f2bf(v.x); o[1] = f2bf(v.y); o[2] = f2bf(v.z); o[3] = f2bf(v.w);
  } else {
    o[0] = 0; o[1] = 0; o[2] = 0; o[3] = 0;
  }
  ((ushort4_t*)out)[i] = o;
}

// ---------------- LayerNorm -> bf16 out ----------------
__global__ __launch_bounds__(256) void ln_kernel(const float* __restrict__ x,
    const float* __restrict__ ln_w, const float* __restrict__ ln_b,
    u16* __restrict__ xn) {
  int row = blockIdx.x;
  int tid = threadIdx.x;
  const float4* xr = (const float4*)(x + (size_t)row * DM);
  float4 v = xr[tid];
  float s  = v.x + v.y + v.z + v.w;
  float s2 = v.x*v.x + v.y*v.y + v.z*v.z + v.w*v.w;
#pragma unroll
  for (int o = 32; o > 0; o >>= 1) { s += __shfl_down(s, o, 64); s2 += __shfl_down(s2, o, 64); }
  __shared__ float red[2][4];
  __shared__ float mv[2];
  int wid = tid >> 6, lane = tid & 63;
  if (lane == 0) { red[0][wid] = s; red[1][wid] = s2; }
  __syncthreads();
  if (tid == 0) {
    float a  = red[0][0] + red[0][1] + red[0][2] + red[0][3];
    float b2 = red[1][0] + red[1][1] + red[1][2] + red[1][3];
    float mean = a * (1.f / DM);
    float var  = b2 * (1.f / DM) - mean * mean;
    mv[0] = mean; mv[1] = rsqrtf(var + 1e-5f);
  }
  __syncthreads();
  float mean = mv[0], inv = mv[1];
  float4 w = ((const float4*)ln_w)[tid];
  float4 b = ((const float4*)ln_b)[tid];
  ushort4_t o;
  o[0] = f2bf((v.x - mean) * inv * w.x + b.x);
  o[1] = f2bf((v.y - mean) * inv * w.y + b.y);
  o[2] = f2bf((v.z - mean) * inv * w.z + b.z);
  o[3] = f2bf((v.w - mean) * inv * w.w + b.w);
  *(ushort4_t*)(xn + (size_t)row * DM + tid * 4) = o;
}

// ---------------- 128-tile bf16 MFMA GEMM (kept for xbc MODE1, dt MODE3, fallback) -------
template<int MODE>
__global__ __launch_bounds__(256) void gemm_mfma_nt(
    const u16* __restrict__ A, int lda,
    const u16* __restrict__ B, int ldb,
    void* __restrict__ Cp, int ldc,
    const float* __restrict__ Res, int K,
    const float* __restrict__ bias, u16* __restrict__ dl_out) {
  __shared__ __align__(16) u16 a_s[128 * 64];
  __shared__ __align__(16) u16 b_s[128 * 64];
  const int tid = threadIdx.x;
  const int w = tid >> 6, l = tid & 63;
  const int wr = w >> 1, wc = w & 1;
  const int nbx = gridDim.x, gy = gridDim.y;
  int lin = blockIdx.y * nbx + blockIdx.x;
  int xcd = lin & 7;
  int m = lin >> 3;
  int bi, bj;
  if (gy >= 8) {
    int njx = gy >> 3;
    bi = m / njx;
    bj = xcd * njx + m % njx;
  } else {
    int cpx = (nbx * gy) >> 3;
    int swz = xcd * cpx + m;
    bi = swz % nbx; bj = swz / nbx;
  }
  const int lrow = l >> 3;
  const int scol = ((l & 7) ^ lrow) * 16;

  f32x4 acc[4][4] = {};

  const u16* Abase = A + (size_t)(bi * 128 + w * 8 + lrow) * lda;
  const u16* Bbase = B + (size_t)(bj * 128 + w * 8 + lrow) * ldb;

  for (int k0 = 0; k0 < K; k0 += 64) {
#pragma unroll
    for (int c = 0; c < 4; c++) {
      const char* ga = (const char*)(Abase + (size_t)(c * 32) * lda + k0) + scol;
      const char* gb = (const char*)(Bbase + (size_t)(c * 32) * ldb + k0) + scol;
      gload_lds16(ga, (char*)a_s + c * 4096 + w * 1024);
      gload_lds16(gb, (char*)b_s + c * 4096 + w * 1024);
    }
    __syncthreads();
#pragma unroll
    for (int kk = 0; kk < 2; kk++) {
      bf16x8 af[4], bfr[4];
#pragma unroll
      for (int m2 = 0; m2 < 4; m2++) {
        int fr = wr * 64 + m2 * 16 + (l & 15);
        int cb = (kk * 64 + ((l >> 4) << 4)) ^ ((fr & 7) << 4);
        af[m2] = *(const bf16x8*)((const char*)a_s + fr * 128 + cb);
      }
#pragma unroll
      for (int n = 0; n < 4; n++) {
        int fr = wc * 64 + n * 16 + (l & 15);
        int cb = (kk * 64 + ((l >> 4) << 4)) ^ ((fr & 7) << 4);
        bfr[n] = *(const bf16x8*)((const char*)b_s + fr * 128 + cb);
      }
#pragma unroll
      for (int m2 = 0; m2 < 4; m2++)
#pragma unroll
        for (int n = 0; n < 4; n++)
          acc[m2][n] = __builtin_amdgcn_mfma_f32_16x16x32_bf16(af[m2], bfr[n], acc[m2][n], 0, 0, 0);
    }
    __syncthreads();
  }
  const int col0 = bj * 128 + wc * 64 + (l & 15);
  const int row0 = bi * 128 + wr * 64 + (l >> 4) * 4;
#pragma unroll
  for (int m2 = 0; m2 < 4; m2++)
#pragma unroll
    for (int n = 0; n < 4; n++) {
      int col = col0 + n * 16;
      float bv = 0.f;
      if constexpr (MODE == 3) bv = bias[col];
#pragma unroll
      for (int r = 0; r < 4; r++) {
        size_t row = (size_t)(row0 + m2 * 16 + r);
        float v = acc[m2][n][r];
        if constexpr (MODE == 0) {
          ((u16*)Cp)[row * ldc + col] = f2bf(v);
        } else if constexpr (MODE == 1) {
          ((float*)Cp)[row * ldc + col] = v;
          if (col < 64) dl_out[row * 64 + col] = f2bf(v);
        } else if constexpr (MODE == 2) {
          v += Res[row * ldc + col];
          ((float*)Cp)[row * ldc + col] = v;
        } else {
          float s = v + bv;
          float sp = __logf(1.f + __expf(s));
          float dtv = fminf(sp + 1e-3f, 0.1f);
          ((u16*)Cp)[row * ldc + col] = f2h(dtv);
        }
      }
    }
}

// ---------------- 256x256 8-phase pipelined bf16 GEMM (MODE 0: bf16 out, 2: f32+Res) -----
// 512 thr / 8 waves (2m x 4n); per-wave out 128x64; BK=64; LDS 128KB dynamic:
// A[2][256x64] | B[2][256x64], row-XOR swizzle ((row&7)<<4) both sides.
// Schedule (provable under in-order vmcnt retire): per tile t, phases issue exactly one
// part each: [A2,A1,A3 of t+1; B0,B1,B2,B3,A0 of t+2] into regions proven dead;
// waits: vmcnt(8)@ph0 (forces this tile's B*+A0+A2), vmcnt(10)@ph4 (forces A1,A3).
// B fragments live in regs after ph0/ph2 -> B LDS dead after ph2's barrier.
template<int MODE>
__global__ __launch_bounds__(512) void gemm256(
    const u16* __restrict__ A, int lda,
    const u16* __restrict__ B, int ldb,
    void* __restrict__ Cp, int ldc,
    const float* __restrict__ Res, int K) {
  extern __shared__ char smem[];          // 131072 B
  const int tid = threadIdx.x;
  const int w = tid >> 6, l = tid & 63;
  const int wm = w >> 2, wn = w & 3;
  const int nbx = gridDim.x, gy = gridDim.y;
  int lin = blockIdx.y * nbx + blockIdx.x;
  int xcd = lin & 7, mm = lin >> 3;
  int bi, bj;
  if (gy >= 8) { int njx = gy >> 3; bi = mm / njx; bj = xcd * njx + mm % njx; }
  else { int cpx = (nbx * gy) >> 3; int swz = xcd * cpx + mm; bi = swz % nbx; bj = swz / nbx; }
  const int lrow = l >> 3;
  const int scol = ((l & 7) ^ lrow) * 16;
  const int l15 = l & 15, lhi = (l >> 4) << 4;
  const u16* aRow = A + (size_t)(bi * 256 + w * 8 + lrow) * lda;
  const u16* bRow = B + (size_t)(bj * 256 + w * 8 + lrow) * ldb;
  char* As = smem;
  char* Bs = smem + 65536;

#define IS_A(s, k) gload_lds16((const char*)(aRow + (size_t)((k) * 64) * lda + (size_t)(s) * 64) + scol, \
                               As + ((((s) & 1)) << 15) + (k) * 8192 + w * 1024)
#define IS_B(s, k) gload_lds16((const char*)(bRow + (size_t)((k) * 64) * ldb + (size_t)(s) * 64) + scol, \
                               Bs + ((((s) & 1)) << 15) + (k) * 8192 + w * 1024)

  f32x4 acc[8][4] = {};
  bf16x8 bf[2][4];
  const int NT = K >> 6;

  // prologue: tile0 fully [B0..B3,A0,A2,A1,A3], tile1 first 5 [B0..B3,A0] (13 issues)
  IS_B(0, 0); IS_B(0, 1); IS_B(0, 2); IS_B(0, 3);
  IS_A(0, 0); IS_A(0, 2); IS_A(0, 1); IS_A(0, 3);
  IS_B(1, 0); IS_B(1, 1); IS_B(1, 2); IS_B(1, 3); IS_A(1, 0);

#define MFMA8(MLO, KK) do { \
    bf16x8 a0_ = ardA(MLO, KK), a1_ = ardA((MLO) + 1, KK); \
    __builtin_amdgcn_s_setprio(1); \
    _Pragma("unroll") \
    for (int n_ = 0; n_ < 4; n_++) { \
      acc[MLO][n_]       = __builtin_amdgcn_mfma_f32_16x16x32_bf16(a0_, bf[KK][n_], acc[MLO][n_], 0, 0, 0); \
      acc[(MLO) + 1][n_] = __builtin_amdgcn_mfma_f32_16x16x32_bf16(a1_, bf[KK][n_], acc[(MLO) + 1][n_], 0, 0, 0); \
    } \
    __builtin_amdgcn_s_setprio(0); \
  } while (0)

  for (int t = 0; t < NT; ++t) {
    const char* Ab = As + ((t & 1) << 15);
    const char* Bb = Bs + ((t & 1) << 15);
    auto ardA = [&](int m, int kk) {
      int fr = wm * 128 + m * 16 + l15;
      int cb = (kk * 64 + lhi) ^ ((fr & 7) << 4);
      return *(const bf16x8*)(Ab + fr * 128 + cb);
    };
    auto ardB = [&](int n, int kk) {
      int fr = wn * 64 + n * 16 + l15;
      int cb = (kk * 64 + lhi) ^ ((fr & 7) << 4);
      return *(const bf16x8*)(Bb + fr * 128 + cb);
    };
    // ---- ph0 ----
    if (t + 1 < NT) IS_A(t + 1, 2);
    FENCE();
    asm volatile("s_waitcnt vmcnt(8)" ::: "memory");
    __builtin_amdgcn_s_barrier();
    FENCE();
    bf[0][0] = ardB(0, 0); bf[0][1] = ardB(1, 0); bf[0][2] = ardB(2, 0); bf[0][3] = ardB(3, 0);
    MFMA8(0, 0);
    // ---- ph1 ----
    if (t + 1 < NT) IS_A(t + 1, 1);
    MFMA8(2, 0);
    // ---- ph2 ----
    if (t + 1 < NT) IS_A(t + 1, 3);
    bf[1][0] = ardB(0, 1); bf[1][1] = ardB(1, 1); bf[1][2] = ardB(2, 1); bf[1][3] = ardB(3, 1);
    MFMA8(0, 1);
    FENCE();
    __builtin_amdgcn_s_barrier();     // B LDS (cur buf) dead past here
    FENCE();
    // ---- ph3 ----
    if (t + 2 < NT) IS_B(t + 2, 0);
    MFMA8(2, 1);
    // ---- ph4 ----
    if (t + 2 < NT) IS_B(t + 2, 1);
    FENCE();
    asm volatile("s_waitcnt vmcnt(10)" ::: "memory");
    __builtin_amdgcn_s_barrier();
    FENCE();
    MFMA8(4, 0);
    // ---- ph5 ----
    if (t + 2 < NT) IS_B(t + 2, 2);
    MFMA8(6, 0);
    // ---- ph6 ----
    if (t + 2 < NT) IS_B(t + 2, 3);
    MFMA8(4, 1);
    // ---- ph7 ----
    if (t + 2 < NT) IS_A(t + 2, 0);
    MFMA8(6, 1);
  }
#undef MFMA8
#undef IS_A
#undef IS_B

  const int col0 = bj * 256 + wn * 64 + l15;
  const int row0 = bi * 256 + wm * 128 + (l >> 4) * 4;
#pragma unroll
  for (int m = 0; m < 8; m++)
#pragma unroll
    for (int n = 0; n < 4; n++) {
      int col = col0 + n * 16;
#pragma unroll
      for (int r = 0; r < 4; r++) {
        size_t row = (size_t)(row0 + m * 16 + r);
        float v = acc[m][n][r];
        if constexpr (MODE == 0) {
          ((u16*)Cp)[row * ldc + col] = f2bf(v);
        } else {
          v += Res[row * ldc + col];
          ((float*)Cp)[row * ldc + col] = v;
        }
      }
    }
}

// ---------------- causal depthwise conv (width 4) + SiLU; bf16 in, bf16 out ----------------
__global__ __launch_bounds__(256) void conv_silu_kernel(const u16* __restrict__ xz,
    const float* __restrict__ conv_w, const float* __restrict__ conv_b,
    u16* __restrict__ u) {
  size_t gid = (size_t)blockIdx.x * 256 + threadIdx.x;
  int c = (int)(gid & 255);
  size_t i = gid >> 8;
  int t = (int)(i & (TT - 1));
  int d0 = c * 8;
  const u16* base = xz + i * 4096 + d0;
  ushort8_t r0 = *(const ushort8_t*)base;
  ushort8_t r1 = 0, r2 = 0, r3 = 0;
  if (t >= 1) r1 = *(const ushort8_t*)(base - 4096);
  if (t >= 2) r2 = *(const ushort8_t*)(base - 2 * 4096);
  if (t >= 3) r3 = *(const ushort8_t*)(base - 3 * 4096);
  float cbv[8];
  *(float4*)&cbv[0] = *(const float4*)(conv_b + d0);
  *(float4*)&cbv[4] = *(const float4*)(conv_b + d0 + 4);
  ushort8_t o;
#pragma unroll
  for (int j = 0; j < 8; j++) {
    float4 w = *(const float4*)(conv_w + (size_t)(d0 + j) * 4);
    float a = cbv[j] + w.w * bf2f(r0[j]) + w.z * bf2f(r1[j])
            + w.y * bf2f(r2[j]) + w.x * bf2f(r3[j]);
    a = a * __builtin_amdgcn_rcpf(1.f + EXP2(-a * L2E));
    o[j] = f2bf(a);
  }
  *(ushort8_t*)(u + i * 2048 + d0) = o;
}

// ---------------- scan phase 1: local chunk scan from h=0; writes y_local (f16) over u ----
__global__ __launch_bounds__(256) void scan_part1(u16* u_g,
    const u16* __restrict__ dt_g, const float* __restrict__ xbc,
    const float* __restrict__ log_A, const float* __restrict__ D_param,
    float* __restrict__ hbuf, float* __restrict__ Sbuf) {
  int d0 = blockIdx.x * 128;
  int c  = blockIdx.y;
  int b  = blockIdx.z;
  int tid = threadIdx.x;
  int w = tid >> 6, l = tid & 63;
  int dl = tid >> 1, q = tid & 1, q8 = q << 3;
  int d = d0 + dl;
  __shared__ __align__(16) u16 u_s[2][SW][128];     // 8K
  __shared__ __align__(16) u16 dts[2][SW][128];     // 8K
  __shared__ __align__(16) float bc_s[2][SW][32];   // 4K (B | C)

  float A2[8];
  {
    float4 la0 = *(const float4*)(log_A + (size_t)d * 16 + q8);
    float4 la1 = *(const float4*)(log_A + (size_t)d * 16 + q8 + 4);
    A2[0] = -EXP2(la0.x * L2E) * L2E; A2[1] = -EXP2(la0.y * L2E) * L2E;
    A2[2] = -EXP2(la0.z * L2E) * L2E; A2[3] = -EXP2(la0.w * L2E) * L2E;
    A2[4] = -EXP2(la1.x * L2E) * L2E; A2[5] = -EXP2(la1.y * L2E) * L2E;
    A2[6] = -EXP2(la1.z * L2E) * L2E; A2[7] = -EXP2(la1.w * L2E) * L2E;
  }
  float Dp = D_param[d];
  float h[8] = {};
  float sdt = 0.f;
  size_t t0 = (size_t)b * TT + (size_t)c * CHL;
  const int sr = w * 4 + (l >> 4);        // staging row in window
  const int sc = (l & 15) * 8;            // staging col (u16 units)
  u16* up = u_g + t0 * 2048 + d;

#define P1STAGE(wnd, pb) { size_t i0_ = t0 + (size_t)(wnd) * SW;                          \
    gload_lds16(u_g  + (i0_ + sr) * 2048 + d0 + sc, (char*)u_s[pb] + w * 1024);           \
    gload_lds16(dt_g + (i0_ + sr) * 4096 + d0 + sc, (char*)dts[pb] + w * 1024);           \
    if (w < 2) gload_lds16(xbc + (i0_ + w * 8 + (l >> 3)) * XBCS + 64 + (l & 7) * 4,      \
                           (char*)bc_s[pb] + w * 1024); }

  P1STAGE(0, 0);
  for (int wnd = 0; wnd < CHL / SW; wnd++) {
    int pb = wnd & 1;
    __syncthreads();
    if (wnd + 1 < CHL / SW) P1STAGE(wnd + 1, pb ^ 1);
#pragma unroll 4
    for (int tt = 0; tt < SW; tt++) {
      float dtv = h2f(dts[pb][tt][dl]);
      float uv  = bf2f(u_s[pb][tt][dl]);
      sdt += dtv;
      float xin = dtv * uv;
      float yv = q ? 0.f : uv * Dp;
      float4 B0 = *(const float4*)&bc_s[pb][tt][q8];
      float4 B1 = *(const float4*)&bc_s[pb][tt][q8 + 4];
      float4 C0 = *(const float4*)&bc_s[pb][tt][16 + q8];
      float4 C1 = *(const float4*)&bc_s[pb][tt][16 + q8 + 4];
      h[0] = __builtin_fmaf(EXP2(dtv * A2[0]), h[0], xin * B0.x); yv = __builtin_fmaf(h[0], C0.x, yv);
      h[1] = __builtin_fmaf(EXP2(dtv * A2[1]), h[1], xin * B0.y); yv = __builtin_fmaf(h[1], C0.y, yv);
      h[2] = __builtin_fmaf(EXP2(dtv * A2[2]), h[2], xin * B0.z); yv = __builtin_fmaf(h[2], C0.z, yv);
      h[3] = __builtin_fmaf(EXP2(dtv * A2[3]), h[3], xin * B0.w); yv = __builtin_fmaf(h[3], C0.w, yv);
      h[4] = __builtin_fmaf(EXP2(dtv * A2[4]), h[4], xin * B1.x); yv = __builtin_fmaf(h[4], C1.x, yv);
      h[5] = __builtin_fmaf(EXP2(dtv * A2[5]), h[5], xin * B1.y); yv = __builtin_fmaf(h[5], C1.y, yv);
      h[6] = __builtin_fmaf(EXP2(dtv * A2[6]), h[6], xin * B1.z); yv = __builtin_fmaf(h[6], C1.z, yv);
      h[7] = __builtin_fmaf(EXP2(dtv * A2[7]), h[7], xin * B1.w); yv = __builtin_fmaf(h[7], C1.w, yv);
      yv += __shfl_xor(yv, 1, 64);
      if (q == 0) *up = f2h(yv);
      up += 2048;
    }
  }
  float* hp = hbuf + (((size_t)b * NCH + c) * 16 + q8) * DN + d;
#pragma unroll
  for (int k = 0; k < 8; k++) hp[(size_t)k * DN] = h[k];
  if (q == 0) Sbuf[((size_t)b * NCH + c) * DN + d] = sdt;
#undef P1STAGE
}

// ---------------- scan phase 2: sequential chunk combine (in-place h_end -> h_start) -------
__global__ __launch_bounds__(256) void scan_combine(const float* __restrict__ log_A,
    const float* __restrict__ Sbuf, float* __restrict__ hbuf) {
  int idx = blockIdx.x * 256 + threadIdx.x;    // over B*16*DN
  int dd = idx & (DN - 1), n = (idx >> 11) & 15, b = idx >> 15;
  float A2 = -EXP2(log_A[(size_t)dd * 16 + n] * L2E) * L2E;
  float h = 0.f;
#pragma unroll
  for (int c = 0; c < NCH; c++) {
    size_t off = (((size_t)b * NCH + c) * 16 + n) * DN + dd;
    float hl = hbuf[off];
    float P = EXP2(A2 * Sbuf[((size_t)b * NCH + c) * DN + dd]);
    hbuf[off] = h;
    h = hl + P * h;
  }
}

// ---------------- scan phase 3: y = (y_local + C.(exp(A*cum) o h_start)) * silu(z) --------
__global__ __launch_bounds__(256) void scan_part2(u16* yl,
    const u16* __restrict__ xz, const float* __restrict__ xbc,
    const u16* __restrict__ dt_g, const float* __restrict__ log_A,
    const float* __restrict__ hbuf) {
  int d0 = blockIdx.x * 128;
  int c  = blockIdx.y;
  int b  = blockIdx.z;
  int tid = threadIdx.x;
  int w = tid >> 6, l = tid & 63;
  int dl = tid >> 1, q = tid & 1, q8 = q << 3;
  int d = d0 + dl;
  __shared__ __align__(16) u16 yls[2][SW][128];     // 8K
  __shared__ __align__(16) u16 z_s[2][SW][128];     // 8K
  __shared__ __align__(16) u16 dts[2][SW][128];     // 8K
  __shared__ __align__(16) float c_s[2][SW][16];    // 2K

  float A2[8];
  {
    float4 la0 = *(const float4*)(log_A + (size_t)d * 16 + q8);
    float4 la1 = *(const float4*)(log_A + (size_t)d * 16 + q8 + 4);
    A2[0] = -EXP2(la0.x * L2E) * L2E; A2[1] = -EXP2(la0.y * L2E) * L2E;
    A2[2] = -EXP2(la0.z * L2E) * L2E; A2[3] = -EXP2(la0.w * L2E) * L2E;
    A2[4] = -EXP2(la1.x * L2E) * L2E; A2[5] = -EXP2(la1.y * L2E) * L2E;
    A2[6] = -EXP2(la1.z * L2E) * L2E; A2[7] = -EXP2(la1.w * L2E) * L2E;
  }
  float hs[8];
  {
    const float* hp = hbuf + (((size_t)b * NCH + c) * 16 + q8) * DN + d;
#pragma unroll
    for (int k = 0; k < 8; k++) hs[k] = hp[(size_t)k * DN];
  }
  float cum = 0.f;
  size_t t0 = (size_t)b * TT + (size_t)c * CHL;
  const int sr = w * 4 + (l >> 4);
  const int sc = (l & 15) * 8;
  u16* ylp = yl + t0 * 2048 + d;

#define P2STAGE(wnd, pb) { size_t i0_ = t0 + (size_t)(wnd) * SW;                          \
    gload_lds16(yl   + (i0_ + sr) * 2048 + d0 + sc, (char*)yls[pb] + w * 1024);           \
    gload_lds16(xz   + (i0_ + sr) * 4096 + 2048 + d0 + sc, (char*)z_s[pb] + w * 1024);    \
    gload_lds16(dt_g + (i0_ + sr) * 4096 + d0 + sc, (char*)dts[pb] + w * 1024);           \
    if (w == 0) gload_lds16(xbc + (i0_ + (l >> 2)) * XBCS + 80 + (l & 3) * 4,             \
                            (char*)c_s[pb]); }

  P2STAGE(0, 0);
  for (int wnd = 0; wnd < CHL / SW; wnd++) {
    int pb = wnd & 1;
    __syncthreads();
    if (wnd + 1 < CHL / SW) P2STAGE(wnd + 1, pb ^ 1);
#pragma unroll 4
    for (int tt = 0; tt < SW; tt++) {
      float dtv = h2f(dts[pb][tt][dl]);
      cum += dtv;
      float4 C0 = *(const float4*)&c_s[pb][tt][q8];
      float4 C1 = *(const float4*)&c_s[pb][tt][q8 + 4];
      float yv = C0.x * (EXP2(cum * A2[0]) * hs[0]) + C0.y * (EXP2(cum * A2[1]) * hs[1])
               + C0.z * (EXP2(cum * A2[2]) * hs[2]) + C0.w * (EXP2(cum * A2[3]) * hs[3])
               + C1.x * (EXP2(cum * A2[4]) * hs[4]) + C1.y * (EXP2(cum * A2[5]) * hs[5])
               + C1.z * (EXP2(cum * A2[6]) * hs[6]) + C1.w * (EXP2(cum * A2[7]) * hs[7]);
      if (q == 0) yv += h2f(yls[pb][tt][dl]);
      yv += __shfl_xor(yv, 1, 64);
      float zv = bf2f(z_s[pb][tt][dl]);
      float sig = __builtin_amdgcn_rcpf(1.f + EXP2(-zv * L2E));
      if (q == 0) *ylp = f2bf(yv * zv * sig);
      ylp += 2048;
    }
  }
#undef P2STAGE
}

extern "C" void kernel_launch(void* const* d_in, const int* in_sizes, int n_in,
                              void* d_out, int out_size, void* d_ws, size_t ws_size,
                              hipStream_t stream) {
  const float* x       = (const float*)d_in[0];
  const float* W_in    = (const float*)d_in[1];
  const float* conv_w  = (const float*)d_in[2];
  const float* conv_b  = (const float*)d_in[3];
  const float* W_x     = (const float*)d_in[4];
  const float* W_dt    = (const float*)d_in[5];
  const float* b_dt    = (const float*)d_in[6];
  const float* log_A   = (const float*)d_in[7];
  const float* D_param = (const float*)d_in[8];
  const float* W_out   = (const float*)d_in[9];
  const float* ln_w    = (const float*)d_in[10];
  const float* ln_b    = (const float*)d_in[11];
  float* out = (float*)d_out;

  size_t need = (size_t)MROWS * 4096 * 2 + (size_t)MROWS * DN * 2 + (size_t)MROWS * 96 * 4;
  if (ws_size < need) return;
  u16*   xz  = (u16*)d_ws;                        // 16384 x 4096 bf16 (x_inner | z)
  u16*   u   = xz + (size_t)MROWS * 4096;         // 16384 x 2048 bf16 (u -> y_local -> y)
  u16*   W_out_b = (u16*)(u + (size_t)MROWS * DN);// 4MiB, gemm2 staging

  u16*   xn_b    = (u16*)d_out;                                  // [0,32)MiB, dead after gemm1
  float* xbc     = (float*)d_out;                                // [0,8)MiB, written AFTER gemm1
  float* hbuf    = (float*)((char*)d_out + (8u << 20));          // [8,40)MiB
  u16*   W_in_b  = (u16*)((char*)d_out + (40u << 20));           // [40,48)MiB
  float* Sbuf    = (float*)((char*)d_out + (48u << 20));         // [48,50)MiB
  u16*   W_x_b   = (u16*)((char*)d_out + (50u << 20));           // [50,50.5)MiB
  u16*   W_dt_b  = (u16*)((char*)d_out + (50u << 20) + (512u << 10)); // [50.5,50.75)
  u16*   dl_b    = (u16*)((char*)d_out + (51u << 20));           // [51,53)MiB

  // one-time opt-in for 128KB dynamic LDS; fall back to 128-tile GEMM if unavailable
  static int use256 = -1;
  if (use256 < 0) {
    hipError_t e0 = hipFuncSetAttribute(reinterpret_cast<const void*>(&gemm256<0>),
        hipFuncAttributeMaxDynamicSharedMemorySize, 131072);
    hipError_t e2 = hipFuncSetAttribute(reinterpret_cast<const void*>(&gemm256<2>),
        hipFuncAttributeMaxDynamicSharedMemorySize, 131072);
    use256 = (e0 == hipSuccess && e2 == hipSuccess) ? 1 : 0;
  }

  cvt_wx_kernel<<<(128 * 2048 / 4) / 256, 256, 0, stream>>>(W_x, W_x_b);
  cvt_bf16_kernel<<<(2048 * 64 / 4) / 256, 256, 0, stream>>>(W_dt, W_dt_b, 2048 * 64 / 4);
  ln_kernel<<<MROWS, 256, 0, stream>>>(x, ln_w, ln_b, xn_b);
  cvt_bf16_kernel<<<(4096 * 1024 / 4) / 256, 256, 0, stream>>>(W_in, W_in_b, 4096 * 1024 / 4);
  if (use256) {
    gemm256<0><<<dim3(MROWS / 256, 4096 / 256), 512, 131072, stream>>>(
        xn_b, DM, W_in_b, DM, xz, 4096, nullptr, DM);
  } else {
    gemm_mfma_nt<0><<<dim3(MROWS / 128, 4096 / 128), 256, 0, stream>>>(
        xn_b, DM, W_in_b, DM, xz, 4096, nullptr, DM, nullptr, nullptr);
  }
  conv_silu_kernel<<<MROWS, 256, 0, stream>>>(xz, conv_w, conv_b, u);
  gemm_mfma_nt<1><<<dim3(MROWS / 128, XBCS / 128), 256, 0, stream>>>(
      u, DN, W_x_b, DN, xbc, XBCS, nullptr, DN, nullptr, dl_b);
  gemm_mfma_nt<3><<<dim3(MROWS / 128, DN / 128), 256, 0, stream>>>(
      dl_b, 64, W_dt_b, 64, xz, 4096, nullptr, 64, b_dt, nullptr);
  scan_part1<<<dim3(DN / 128, NCH, 4), 256, 0, stream>>>(
      u, xz, xbc, log_A, D_param, hbuf, Sbuf);
  scan_combine<<<4 * DN * 16 / 256, 256, 0, stream>>>(log_A, Sbuf, hbuf);
  scan_part2<<<dim3(DN / 128, NCH, 4), 256, 0, stream>>>(
      u, xz, xbc, xz, log_A, hbuf);
  cvt_bf16_kernel<<<(1024 * 2048 / 4) / 256, 256, 0, stream>>>(W_out, W_out_b, 1024 * 2048 / 4);
  if (use256) {
    gemm256<2><<<dim3(MROWS / 256, 1024 / 256), 512, 131072, stream>>>(
        u, DN, W_out_b, DN, out, DM, x, DN);
  } else {
    gemm_mfma_nt<2><<<dim3(MROWS / 128, 1024 / 128), 256, 0, stream>>>(
        u, DN, W_out_b, DN, out, DM, x, DN, nullptr, nullptr);
  }
}

// Round 9
// 619.894 us; speedup vs baseline: 1.3247x; 1.0058x over previous
//
#include <hip/hip_runtime.h>
#include <cstdint>
#include <cstddef>

#define TT 4096
#define DM 1024
#define DN 2048
#define MROWS 16384  // B*T
#define NCH 64       // scan chunks per sequence
#define CHL 64       // chunk length (TT/NCH)
#define SW 16        // staging window inside a chunk
#define XBCS 128     // xbc row stride (f32), padded from 96 for MFMA GEMM

typedef unsigned short u16;
typedef u16 ushort8_t __attribute__((ext_vector_type(8)));
typedef u16 ushort4_t __attribute__((ext_vector_type(4)));
typedef short bf16x8 __attribute__((ext_vector_type(8)));   // MFMA A/B frag (4 VGPR)
typedef float f32x4 __attribute__((ext_vector_type(4)));    // MFMA C/D frag

#define EXP2(x) __builtin_amdgcn_exp2f(x)
#define L2E 1.44269504f

__device__ __forceinline__ float bf2f(u16 b) {
  return __uint_as_float(((unsigned int)b) << 16);
}
__device__ __forceinline__ u16 f2bf(float f) {
  unsigned int u = __float_as_uint(f);
  u = u + 0x7FFFu + ((u >> 16) & 1u);   // round-to-nearest-even
  return (u16)(u >> 16);
}
__device__ __forceinline__ u16 f2h(float f) {
  _Float16 h = (_Float16)f;
  return __builtin_bit_cast(u16, h);
}
__device__ __forceinline__ float h2f(u16 v) {
  return (float)__builtin_bit_cast(_Float16, v);
}

__device__ __forceinline__ void gload_lds16(const void* g, void* l) {
  __builtin_amdgcn_global_load_lds(
      (const __attribute__((address_space(1))) unsigned int*)g,
      (__attribute__((address_space(3))) unsigned int*)l, 16, 0, 0);
}

#define FENCE() asm volatile("" ::: "memory")

// ---------------- f32 -> bf16 converter (weights) ----------------
__global__ __launch_bounds__(256) void cvt_bf16_kernel(const float* __restrict__ in,
    u16* __restrict__ out, int n4) {
  int i = blockIdx.x * 256 + threadIdx.x;
  if (i >= n4) return;
  float4 v = ((const float4*)in)[i];
  ushort4_t o; o[0] = f2bf(v.x); o[1] = f2bf(v.y); o[2] = f2bf(v.z); o[3] = f2bf(v.w);
  ((ushort4_t*)out)[i] = o;
}

// ---------------- W_x f32(96x2048) -> bf16(128x2048), rows 96..127 zero ----------------
__global__ __launch_bounds__(256) void cvt_wx_kernel(const float* __restrict__ W_x,
    u16* __restrict__ out) {
  int i = blockIdx.x * 256 + threadIdx.x;   // over 128*2048/4 = 65536 float4 slots
  int row = i >> 9;                         // 512 float4 per row
  ushort4_t o;
  if (row < 96) {
    float4 v = ((const float4*)W_x)[i];
    o[0] = f2bf(v.x); o[1] = f2bf(v.y); o[2] = f2bf(v.z); o[3] = f2bf(v.w);
  } else {
    o[0] = 0; o[1] = 0; o[2] = 0; o[3] = 0;
  }
  ((ushort4_t*)out)[i] = o;
}

// ---------------- LayerNorm -> bf16 out ----------------
__global__ __launch_bounds__(256) void ln_kernel(const float* __restrict__ x,
    const float* __restrict__ ln_w, const float* __restrict__ ln_b,
    u16* __restrict__ xn) {
  int row = blockIdx.x;
  int tid = threadIdx.x;
  const float4* xr = (const float4*)(x + (size_t)row * DM);
  float4 v = xr[tid];
  float s  = v.x + v.y + v.z + v.w;
  float s2 = v.x*v.x + v.y*v.y + v.z*v.z + v.w*v.w;
#pragma unroll
  for (int o = 32; o > 0; o >>= 1) { s += __shfl_down(s, o, 64); s2 += __shfl_down(s2, o, 64); }
  __shared__ float red[2][4];
  __shared__ float mv[2];
  int wid = tid >> 6, lane = tid & 63;
  if (lane == 0) { red[0][wid] = s; red[1][wid] = s2; }
  __syncthreads();
  if (tid == 0) {
    float a  = red[0][0] + red[0][1] + red[0][2] + red[0][3];
    float b2 = red[1][0] + red[1][1] + red[1][2] + red[1][3];
    float mean = a * (1.f / DM);
    float var  = b2 * (1.f / DM) - mean * mean;
    mv[0] = mean; mv[1] = rsqrtf(var + 1e-5f);
  }
  __syncthreads();
  float mean = mv[0], inv = mv[1];
  float4 w = ((const float4*)ln_w)[tid];
  float4 b = ((const float4*)ln_b)[tid];
  ushort4_t o;
  o[0] = f2bf((v.x - mean) * inv * w.x + b.x);
  o[1] = f2bf((v.y - mean) * inv * w.y + b.y);
  o[2] = f2bf((v.z - mean) * inv * w.z + b.z);
  o[3] = f2bf((v.w - mean) * inv * w.w + b.w);
  *(ushort4_t*)(xn + (size_t)row * DM + tid * 4) = o;
}

// ---------------- 128-tile bf16 MFMA GEMM (kept for xbc MODE1, dt MODE3, fallback) -------
template<int MODE>
__global__ __launch_bounds__(256) void gemm_mfma_nt(
    const u16* __restrict__ A, int lda,
    const u16* __restrict__ B, int ldb,
    void* __restrict__ Cp, int ldc,
    const float* __restrict__ Res, int K,
    const float* __restrict__ bias, u16* __restrict__ dl_out) {
  __shared__ __align__(16) u16 a_s[128 * 64];
  __shared__ __align__(16) u16 b_s[128 * 64];
  const int tid = threadIdx.x;
  const int w = tid >> 6, l = tid & 63;
  const int wr = w >> 1, wc = w & 1;
  const int nbx = gridDim.x, gy = gridDim.y;
  int lin = blockIdx.y * nbx + blockIdx.x;
  int xcd = lin & 7;
  int m = lin >> 3;
  int bi, bj;
  if (gy >= 8) {
    int njx = gy >> 3;
    bi = m / njx;
    bj = xcd * njx + m % njx;
  } else {
    int cpx = (nbx * gy) >> 3;
    int swz = xcd * cpx + m;
    bi = swz % nbx; bj = swz / nbx;
  }
  const int lrow = l >> 3;
  const int scol = ((l & 7) ^ lrow) * 16;

  f32x4 acc[4][4] = {};

  const u16* Abase = A + (size_t)(bi * 128 + w * 8 + lrow) * lda;
  const u16* Bbase = B + (size_t)(bj * 128 + w * 8 + lrow) * ldb;

  for (int k0 = 0; k0 < K; k0 += 64) {
#pragma unroll
    for (int c = 0; c < 4; c++) {
      const char* ga = (const char*)(Abase + (size_t)(c * 32) * lda + k0) + scol;
      const char* gb = (const char*)(Bbase + (size_t)(c * 32) * ldb + k0) + scol;
      gload_lds16(ga, (char*)a_s + c * 4096 + w * 1024);
      gload_lds16(gb, (char*)b_s + c * 4096 + w * 1024);
    }
    __syncthreads();
#pragma unroll
    for (int kk = 0; kk < 2; kk++) {
      bf16x8 af[4], bfr[4];
#pragma unroll
      for (int m2 = 0; m2 < 4; m2++) {
        int fr = wr * 64 + m2 * 16 + (l & 15);
        int cb = (kk * 64 + ((l >> 4) << 4)) ^ ((fr & 7) << 4);
        af[m2] = *(const bf16x8*)((const char*)a_s + fr * 128 + cb);
      }
#pragma unroll
      for (int n = 0; n < 4; n++) {
        int fr = wc * 64 + n * 16 + (l & 15);
        int cb = (kk * 64 + ((l >> 4) << 4)) ^ ((fr & 7) << 4);
        bfr[n] = *(const bf16x8*)((const char*)b_s + fr * 128 + cb);
      }
#pragma unroll
      for (int m2 = 0; m2 < 4; m2++)
#pragma unroll
        for (int n = 0; n < 4; n++)
          acc[m2][n] = __builtin_amdgcn_mfma_f32_16x16x32_bf16(af[m2], bfr[n], acc[m2][n], 0, 0, 0);
    }
    __syncthreads();
  }
  const int col0 = bj * 128 + wc * 64 + (l & 15);
  const int row0 = bi * 128 + wr * 64 + (l >> 4) * 4;
#pragma unroll
  for (int m2 = 0; m2 < 4; m2++)
#pragma unroll
    for (int n = 0; n < 4; n++) {
      int col = col0 + n * 16;
      float bv = 0.f;
      if constexpr (MODE == 3) bv = bias[col];
#pragma unroll
      for (int r = 0; r < 4; r++) {
        size_t row = (size_t)(row0 + m2 * 16 + r);
        float v = acc[m2][n][r];
        if constexpr (MODE == 0) {
          ((u16*)Cp)[row * ldc + col] = f2bf(v);
        } else if constexpr (MODE == 1) {
          ((float*)Cp)[row * ldc + col] = v;
          if (col < 64) dl_out[row * 64 + col] = f2bf(v);
        } else if constexpr (MODE == 2) {
          v += Res[row * ldc + col];
          ((float*)Cp)[row * ldc + col] = v;
        } else {
          float s = v + bv;
          float sp = __logf(1.f + __expf(s));
          float dtv = fminf(sp + 1e-3f, 0.1f);
          ((u16*)Cp)[row * ldc + col] = f2h(dtv);
        }
      }
    }
}

// ---------------- 256x256 pipelined bf16 GEMM, m201-faithful 4-phase schedule ------------
// 512 thr / 8 waves (2m x 4n); per-wave out 128x64; BK=64; LDS 128KB dynamic.
// Per K-tile: arrival gate {2 prefetch + vmcnt(2) + barrier}, then 4 phases, each:
// {ds_reads for THIS phase's MFMA -> regs; 2 prefetch gloads; barrier;
//  setprio(1) + 16 dependency-free MFMA + setprio(0); barrier}.
// Reads are issued one barrier ahead of their MFMAs -> ds latency hides under
// barrier convergence + other waves' MFMA (role-split; m196/m218b mechanism).
// Prefetch of tile t+1 spread: B0,B1@gate, B2,B3@ph0, A0,A2@ph1, A1,A3@ph2 (8/tile);
// all forced retired by tile t+1's gate vmcnt(2). Buffer safety: a wave reaches
// tile t's first gload only after t-1's final barrier, by which point all reads of
// buf[(t+1)&1] (done during t-1) completed.
template<int MODE>
__global__ __launch_bounds__(512) void gemm256(
    const u16* __restrict__ A, int lda,
    const u16* __restrict__ B, int ldb,
    void* __restrict__ Cp, int ldc,
    const float* __restrict__ Res, int K) {
  extern __shared__ char smem[];          // 131072 B
  const int tid = threadIdx.x;
  const int w = tid >> 6, l = tid & 63;
  const int wm = w >> 2, wn = w & 3;
  const int nbx = gridDim.x, gy = gridDim.y;
  int lin = blockIdx.y * nbx + blockIdx.x;
  int xcd = lin & 7, mm = lin >> 3;
  int bi, bj;
  if (gy >= 8) { int njx = gy >> 3; bi = mm / njx; bj = xcd * njx + mm % njx; }
  else { int cpx = (nbx * gy) >> 3; int swz = xcd * cpx + mm; bi = swz % nbx; bj = swz / nbx; }
  const int lrow = l >> 3;
  const int scol = ((l & 7) ^ lrow) * 16;
  const int l15 = l & 15, lhi = (l >> 4) << 4;
  const u16* aRow = A + (size_t)(bi * 256 + w * 8 + lrow) * lda;
  const u16* bRow = B + (size_t)(bj * 256 + w * 8 + lrow) * ldb;
  char* As = smem;
  char* Bs = smem + 65536;

#define IS_A(s, k) gload_lds16((const char*)(aRow + (size_t)((k) * 64) * lda + (size_t)(s) * 64) + scol, \
                               As + ((((s) & 1)) << 15) + (k) * 8192 + w * 1024)
#define IS_B(s, k) gload_lds16((const char*)(bRow + (size_t)((k) * 64) * ldb + (size_t)(s) * 64) + scol, \
                               Bs + ((((s) & 1)) << 15) + (k) * 8192 + w * 1024)

  f32x4 acc[8][4] = {};
  const int NT = K >> 6;

  // prologue: tile 0, all 8 parts
  IS_B(0, 0); IS_B(0, 1); IS_B(0, 2); IS_B(0, 3);
  IS_A(0, 0); IS_A(0, 2); IS_A(0, 1); IS_A(0, 3);

#define CLUSTER16(AARR, BARR, MBASE) do { \
    __builtin_amdgcn_s_setprio(1); \
    _Pragma("unroll") \
    for (int m_ = 0; m_ < 4; m_++) \
      _Pragma("unroll") \
      for (int n_ = 0; n_ < 4; n_++) \
        acc[(MBASE) + m_][n_] = __builtin_amdgcn_mfma_f32_16x16x32_bf16( \
            AARR[m_], BARR[n_], acc[(MBASE) + m_][n_], 0, 0, 0); \
    __builtin_amdgcn_s_setprio(0); \
  } while (0)

  for (int t = 0; t < NT; ++t) {
    const char* Ab = As + ((t & 1) << 15);
    const char* Bb = Bs + ((t & 1) << 15);
    auto ardA = [&](int m, int kk) {
      int fr = wm * 128 + m * 16 + l15;
      int cb = (kk * 64 + lhi) ^ ((fr & 7) << 4);
      return *(const bf16x8*)(Ab + fr * 128 + cb);
    };
    auto ardB = [&](int n, int kk) {
      int fr = wn * 64 + n * 16 + l15;
      int cb = (kk * 64 + lhi) ^ ((fr & 7) << 4);
      return *(const bf16x8*)(Bb + fr * 128 + cb);
    };
    bf16x8 a[4], b0[4], b1[4];
    // ---- arrival gate ----
    if (t + 1 < NT) {
      IS_B(t + 1, 0); IS_B(t + 1, 1);
      FENCE();
      asm volatile("s_waitcnt vmcnt(2)" ::: "memory");
    } else {
      asm volatile("s_waitcnt vmcnt(0)" ::: "memory");
    }
    __builtin_amdgcn_s_barrier();
    FENCE();
    // ---- ph0: m0-3 x kk0 ----
    b0[0] = ardB(0, 0); b0[1] = ardB(1, 0); b0[2] = ardB(2, 0); b0[3] = ardB(3, 0);
    a[0] = ardA(0, 0); a[1] = ardA(1, 0); a[2] = ardA(2, 0); a[3] = ardA(3, 0);
    FENCE();
    if (t + 1 < NT) { IS_B(t + 1, 2); IS_B(t + 1, 3); FENCE(); }
    __builtin_amdgcn_s_barrier();
    CLUSTER16(a, b0, 0);
    FENCE();
    __builtin_amdgcn_s_barrier();
    FENCE();
    // ---- ph1: m4-7 x kk0 ----
    a[0] = ardA(4, 0); a[1] = ardA(5, 0); a[2] = ardA(6, 0); a[3] = ardA(7, 0);
    FENCE();
    if (t + 1 < NT) { IS_A(t + 1, 0); IS_A(t + 1, 2); FENCE(); }
    __builtin_amdgcn_s_barrier();
    CLUSTER16(a, b0, 4);
    FENCE();
    __builtin_amdgcn_s_barrier();
    FENCE();
    // ---- ph2: m0-3 x kk1 ----
    b1[0] = ardB(0, 1); b1[1] = ardB(1, 1); b1[2] = ardB(2, 1); b1[3] = ardB(3, 1);
    a[0] = ardA(0, 1); a[1] = ardA(1, 1); a[2] = ardA(2, 1); a[3] = ardA(3, 1);
    FENCE();
    if (t + 1 < NT) { IS_A(t + 1, 1); IS_A(t + 1, 3); FENCE(); }
    __builtin_amdgcn_s_barrier();
    CLUSTER16(a, b1, 0);
    FENCE();
    __builtin_amdgcn_s_barrier();
    FENCE();
    // ---- ph3: m4-7 x kk1 ----
    a[0] = ardA(4, 1); a[1] = ardA(5, 1); a[2] = ardA(6, 1); a[3] = ardA(7, 1);
    FENCE();
    __builtin_amdgcn_s_barrier();
    CLUSTER16(a, b1, 4);
    FENCE();
    __builtin_amdgcn_s_barrier();
    FENCE();
  }
#undef CLUSTER16
#undef IS_A
#undef IS_B

  const int col0 = bj * 256 + wn * 64 + l15;
  const int row0 = bi * 256 + wm * 128 + (l >> 4) * 4;
#pragma unroll
  for (int m = 0; m < 8; m++)
#pragma unroll
    for (int n = 0; n < 4; n++) {
      int col = col0 + n * 16;
#pragma unroll
      for (int r = 0; r < 4; r++) {
        size_t row = (size_t)(row0 + m * 16 + r);
        float v = acc[m][n][r];
        if constexpr (MODE == 0) {
          ((u16*)Cp)[row * ldc + col] = f2bf(v);
        } else {
          v += Res[row * ldc + col];
          ((float*)Cp)[row * ldc + col] = v;
        }
      }
    }
}

// ---------------- causal depthwise conv (width 4) + SiLU; bf16 in, bf16 out ----------------
__global__ __launch_bounds__(256) void conv_silu_kernel(const u16* __restrict__ xz,
    const float* __restrict__ conv_w, const float* __restrict__ conv_b,
    u16* __restrict__ u) {
  size_t gid = (size_t)blockIdx.x * 256 + threadIdx.x;
  int c = (int)(gid & 255);
  size_t i = gid >> 8;
  int t = (int)(i & (TT - 1));
  int d0 = c * 8;
  const u16* base = xz + i * 4096 + d0;
  ushort8_t r0 = *(const ushort8_t*)base;
  ushort8_t r1 = 0, r2 = 0, r3 = 0;
  if (t >= 1) r1 = *(const ushort8_t*)(base - 4096);
  if (t >= 2) r2 = *(const ushort8_t*)(base - 2 * 4096);
  if (t >= 3) r3 = *(const ushort8_t*)(base - 3 * 4096);
  float cbv[8];
  *(float4*)&cbv[0] = *(const float4*)(conv_b + d0);
  *(float4*)&cbv[4] = *(const float4*)(conv_b + d0 + 4);
  ushort8_t o;
#pragma unroll
  for (int j = 0; j < 8; j++) {
    float4 w = *(const float4*)(conv_w + (size_t)(d0 + j) * 4);
    float a = cbv[j] + w.w * bf2f(r0[j]) + w.z * bf2f(r1[j])
            + w.y * bf2f(r2[j]) + w.x * bf2f(r3[j]);
    a = a * __builtin_amdgcn_rcpf(1.f + EXP2(-a * L2E));
    o[j] = f2bf(a);
  }
  *(ushort8_t*)(u + i * 2048 + d0) = o;
}

// ---------------- scan phase 1: local chunk scan from h=0; writes y_local (f16) over u ----
__global__ __launch_bounds__(256) void scan_part1(u16* u_g,
    const u16* __restrict__ dt_g, const float* __restrict__ xbc,
    const float* __restrict__ log_A, const float* __restrict__ D_param,
    float* __restrict__ hbuf, float* __restrict__ Sbuf) {
  int d0 = blockIdx.x * 128;
  int c  = blockIdx.y;
  int b  = blockIdx.z;
  int tid = threadIdx.x;
  int w = tid >> 6, l = tid & 63;
  int dl = tid >> 1, q = tid & 1, q8 = q << 3;
  int d = d0 + dl;
  __shared__ __align__(16) u16 u_s[2][SW][128];     // 8K
  __shared__ __align__(16) u16 dts[2][SW][128];     // 8K
  __shared__ __align__(16) float bc_s[2][SW][32];   // 4K (B | C)

  float A2[8];
  {
    float4 la0 = *(const float4*)(log_A + (size_t)d * 16 + q8);
    float4 la1 = *(const float4*)(log_A + (size_t)d * 16 + q8 + 4);
    A2[0] = -EXP2(la0.x * L2E) * L2E; A2[1] = -EXP2(la0.y * L2E) * L2E;
    A2[2] = -EXP2(la0.z * L2E) * L2E; A2[3] = -EXP2(la0.w * L2E) * L2E;
    A2[4] = -EXP2(la1.x * L2E) * L2E; A2[5] = -EXP2(la1.y * L2E) * L2E;
    A2[6] = -EXP2(la1.z * L2E) * L2E; A2[7] = -EXP2(la1.w * L2E) * L2E;
  }
  float Dp = D_param[d];
  float h[8] = {};
  float sdt = 0.f;
  size_t t0 = (size_t)b * TT + (size_t)c * CHL;
  const int sr = w * 4 + (l >> 4);        // staging row in window
  const int sc = (l & 15) * 8;            // staging col (u16 units)
  u16* up = u_g + t0 * 2048 + d;

#define P1STAGE(wnd, pb) { size_t i0_ = t0 + (size_t)(wnd) * SW;                          \
    gload_lds16(u_g  + (i0_ + sr) * 2048 + d0 + sc, (char*)u_s[pb] + w * 1024);           \
    gload_lds16(dt_g + (i0_ + sr) * 4096 + d0 + sc, (char*)dts[pb] + w * 1024);           \
    if (w < 2) gload_lds16(xbc + (i0_ + w * 8 + (l >> 3)) * XBCS + 64 + (l & 7) * 4,      \
                           (char*)bc_s[pb] + w * 1024); }

  P1STAGE(0, 0);
  for (int wnd = 0; wnd < CHL / SW; wnd++) {
    int pb = wnd & 1;
    __syncthreads();
    if (wnd + 1 < CHL / SW) P1STAGE(wnd + 1, pb ^ 1);
#pragma unroll 4
    for (int tt = 0; tt < SW; tt++) {
      float dtv = h2f(dts[pb][tt][dl]);
      float uv  = bf2f(u_s[pb][tt][dl]);
      sdt += dtv;
      float xin = dtv * uv;
      float yv = q ? 0.f : uv * Dp;
      float4 B0 = *(const float4*)&bc_s[pb][tt][q8];
      float4 B1 = *(const float4*)&bc_s[pb][tt][q8 + 4];
      float4 C0 = *(const float4*)&bc_s[pb][tt][16 + q8];
      float4 C1 = *(const float4*)&bc_s[pb][tt][16 + q8 + 4];
      h[0] = __builtin_fmaf(EXP2(dtv * A2[0]), h[0], xin * B0.x); yv = __builtin_fmaf(h[0], C0.x, yv);
      h[1] = __builtin_fmaf(EXP2(dtv * A2[1]), h[1], xin * B0.y); yv = __builtin_fmaf(h[1], C0.y, yv);
      h[2] = __builtin_fmaf(EXP2(dtv * A2[2]), h[2], xin * B0.z); yv = __builtin_fmaf(h[2], C0.z, yv);
      h[3] = __builtin_fmaf(EXP2(dtv * A2[3]), h[3], xin * B0.w); yv = __builtin_fmaf(h[3], C0.w, yv);
      h[4] = __builtin_fmaf(EXP2(dtv * A2[4]), h[4], xin * B1.x); yv = __builtin_fmaf(h[4], C1.x, yv);
      h[5] = __builtin_fmaf(EXP2(dtv * A2[5]), h[5], xin * B1.y); yv = __builtin_fmaf(h[5], C1.y, yv);
      h[6] = __builtin_fmaf(EXP2(dtv * A2[6]), h[6], xin * B1.z); yv = __builtin_fmaf(h[6], C1.z, yv);
      h[7] = __builtin_fmaf(EXP2(dtv * A2[7]), h[7], xin * B1.w); yv = __builtin_fmaf(h[7], C1.w, yv);
      yv += __shfl_xor(yv, 1, 64);
      if (q == 0) *up = f2h(yv);
      up += 2048;
    }
  }
  float* hp = hbuf + (((size_t)b * NCH + c) * 16 + q8) * DN + d;
#pragma unroll
  for (int k = 0; k < 8; k++) hp[(size_t)k * DN] = h[k];
  if (q == 0) Sbuf[((size_t)b * NCH + c) * DN + d] = sdt;
#undef P1STAGE
}

// ---------------- scan phase 2: sequential chunk combine (in-place h_end -> h_start) -------
__global__ __launch_bounds__(256) void scan_combine(const float* __restrict__ log_A,
    const float* __restrict__ Sbuf, float* __restrict__ hbuf) {
  int idx = blockIdx.x * 256 + threadIdx.x;    // over B*16*DN
  int dd = idx & (DN - 1), n = (idx >> 11) & 15, b = idx >> 15;
  float A2 = -EXP2(log_A[(size_t)dd * 16 + n] * L2E) * L2E;
  float h = 0.f;
#pragma unroll
  for (int c = 0; c < NCH; c++) {
    size_t off = (((size_t)b * NCH + c) * 16 + n) * DN + dd;
    float hl = hbuf[off];
    float P = EXP2(A2 * Sbuf[((size_t)b * NCH + c) * DN + dd]);
    hbuf[off] = h;
    h = hl + P * h;
  }
}

// ---------------- scan phase 3: y = (y_local + C.(exp(A*cum) o h_start)) * silu(z) --------
__global__ __launch_bounds__(256) void scan_part2(u16* yl,
    const u16* __restrict__ xz, const float* __restrict__ xbc,
    const u16* __restrict__ dt_g, const float* __restrict__ log_A,
    const float* __restrict__ hbuf) {
  int d0 = blockIdx.x * 128;
  int c  = blockIdx.y;
  int b  = blockIdx.z;
  int tid = threadIdx.x;
  int w = tid >> 6, l = tid & 63;
  int dl = tid >> 1, q = tid & 1, q8 = q << 3;
  int d = d0 + dl;
  __shared__ __align__(16) u16 yls[2][SW][128];     // 8K
  __shared__ __align__(16) u16 z_s[2][SW][128];     // 8K
  __shared__ __align__(16) u16 dts[2][SW][128];     // 8K
  __shared__ __align__(16) float c_s[2][SW][16];    // 2K

  float A2[8];
  {
    float4 la0 = *(const float4*)(log_A + (size_t)d * 16 + q8);
    float4 la1 = *(const float4*)(log_A + (size_t)d * 16 + q8 + 4);
    A2[0] = -EXP2(la0.x * L2E) * L2E; A2[1] = -EXP2(la0.y * L2E) * L2E;
    A2[2] = -EXP2(la0.z * L2E) * L2E; A2[3] = -EXP2(la0.w * L2E) * L2E;
    A2[4] = -EXP2(la1.x * L2E) * L2E; A2[5] = -EXP2(la1.y * L2E) * L2E;
    A2[6] = -EXP2(la1.z * L2E) * L2E; A2[7] = -EXP2(la1.w * L2E) * L2E;
  }
  float hs[8];
  {
    const float* hp = hbuf + (((size_t)b * NCH + c) * 16 + q8) * DN + d;
#pragma unroll
    for (int k = 0; k < 8; k++) hs[k] = hp[(size_t)k * DN];
  }
  float cum = 0.f;
  size_t t0 = (size_t)b * TT + (size_t)c * CHL;
  const int sr = w * 4 + (l >> 4);
  const int sc = (l & 15) * 8;
  u16* ylp = yl + t0 * 2048 + d;

#define P2STAGE(wnd, pb) { size_t i0_ = t0 + (size_t)(wnd) * SW;                          \
    gload_lds16(yl   + (i0_ + sr) * 2048 + d0 + sc, (char*)yls[pb] + w * 1024);           \
    gload_lds16(xz   + (i0_ + sr) * 4096 + 2048 + d0 + sc, (char*)z_s[pb] + w * 1024);    \
    gload_lds16(dt_g + (i0_ + sr) * 4096 + d0 + sc, (char*)dts[pb] + w * 1024);           \
    if (w == 0) gload_lds16(xbc + (i0_ + (l >> 2)) * XBCS + 80 + (l & 3) * 4,             \
                            (char*)c_s[pb]); }

  P2STAGE(0, 0);
  for (int wnd = 0; wnd < CHL / SW; wnd++) {
    int pb = wnd & 1;
    __syncthreads();
    if (wnd + 1 < CHL / SW) P2STAGE(wnd + 1, pb ^ 1);
#pragma unroll 4
    for (int tt = 0; tt < SW; tt++) {
      float dtv = h2f(dts[pb][tt][dl]);
      cum += dtv;
      float4 C0 = *(const float4*)&c_s[pb][tt][q8];
      float4 C1 = *(const float4*)&c_s[pb][tt][q8 + 4];
      float yv = C0.x * (EXP2(cum * A2[0]) * hs[0]) + C0.y * (EXP2(cum * A2[1]) * hs[1])
               + C0.z * (EXP2(cum * A2[2]) * hs[2]) + C0.w * (EXP2(cum * A2[3]) * hs[3])
               + C1.x * (EXP2(cum * A2[4]) * hs[4]) + C1.y * (EXP2(cum * A2[5]) * hs[5])
               + C1.z * (EXP2(cum * A2[6]) * hs[6]) + C1.w * (EXP2(cum * A2[7]) * hs[7]);
      if (q == 0) yv += h2f(yls[pb][tt][dl]);
      yv += __shfl_xor(yv, 1, 64);
      float zv = bf2f(z_s[pb][tt][dl]);
      float sig = __builtin_amdgcn_rcpf(1.f + EXP2(-zv * L2E));
      if (q == 0) *ylp = f2bf(yv * zv * sig);
      ylp += 2048;
    }
  }
#undef P2STAGE
}

extern "C" void kernel_launch(void* const* d_in, const int* in_sizes, int n_in,
                              void* d_out, int out_size, void* d_ws, size_t ws_size,
                              hipStream_t stream) {
  const float* x       = (const float*)d_in[0];
  const float* W_in    = (const float*)d_in[1];
  const float* conv_w  = (const float*)d_in[2];
  const float* conv_b  = (const float*)d_in[3];
  const float* W_x     = (const float*)d_in[4];
  const float* W_dt    = (const float*)d_in[5];
  const float* b_dt    = (const float*)d_in[6];
  const float* log_A   = (const float*)d_in[7];
  const float* D_param = (const float*)d_in[8];
  const float* W_out   = (const float*)d_in[9];
  const float* ln_w    = (const float*)d_in[10];
  const float* ln_b    = (const float*)d_in[11];
  float* out = (float*)d_out;

  size_t need = (size_t)MROWS * 4096 * 2 + (size_t)MROWS * DN * 2 + (size_t)MROWS * 96 * 4;
  if (ws_size < need) return;
  u16*   xz  = (u16*)d_ws;                        // 16384 x 4096 bf16 (x_inner | z)
  u16*   u   = xz + (size_t)MROWS * 4096;         // 16384 x 2048 bf16 (u -> y_local -> y)
  u16*   W_out_b = (u16*)(u + (size_t)MROWS * DN);// 4MiB, gemm2 staging

  u16*   xn_b    = (u16*)d_out;                                  // [0,32)MiB, dead after gemm1
  float* xbc     = (float*)d_out;                                // [0,8)MiB, written AFTER gemm1
  float* hbuf    = (float*)((char*)d_out + (8u << 20));          // [8,40)MiB
  u16*   W_in_b  = (u16*)((char*)d_out + (40u << 20));           // [40,48)MiB
  float* Sbuf    = (float*)((char*)d_out + (48u << 20));         // [48,50)MiB
  u16*   W_x_b   = (u16*)((char*)d_out + (50u << 20));           // [50,50.5)MiB
  u16*   W_dt_b  = (u16*)((char*)d_out + (50u << 20) + (512u << 10)); // [50.5,50.75)
  u16*   dl_b    = (u16*)((char*)d_out + (51u << 20));           // [51,53)MiB

  // one-time opt-in for 128KB dynamic LDS; fall back to 128-tile GEMM if unavailable
  static int use256 = -1;
  if (use256 < 0) {
    hipError_t e0 = hipFuncSetAttribute(reinterpret_cast<const void*>(&gemm256<0>),
        hipFuncAttributeMaxDynamicSharedMemorySize, 131072);
    hipError_t e2 = hipFuncSetAttribute(reinterpret_cast<const void*>(&gemm256<2>),
        hipFuncAttributeMaxDynamicSharedMemorySize, 131072);
    use256 = (e0 == hipSuccess && e2 == hipSuccess) ? 1 : 0;
  }

  cvt_wx_kernel<<<(128 * 2048 / 4) / 256, 256, 0, stream>>>(W_x, W_x_b);
  cvt_bf16_kernel<<<(2048 * 64 / 4) / 256, 256, 0, stream>>>(W_dt, W_dt_b, 2048 * 64 / 4);
  ln_kernel<<<MROWS, 256, 0, stream>>>(x, ln_w, ln_b, xn_b);
  cvt_bf16_kernel<<<(4096 * 1024 / 4) / 256, 256, 0, stream>>>(W_in, W_in_b, 4096 * 1024 / 4);
  if (use256) {
    gemm256<0><<<dim3(MROWS / 256, 4096 / 256), 512, 131072, stream>>>(
        xn_b, DM, W_in_b, DM, xz, 4096, nullptr, DM);
  } else {
    gemm_mfma_nt<0><<<dim3(MROWS / 128, 4096 / 128), 256, 0, stream>>>(
        xn_b, DM, W_in_b, DM, xz, 4096, nullptr, DM, nullptr, nullptr);
  }
  conv_silu_kernel<<<MROWS, 256, 0, stream>>>(xz, conv_w, conv_b, u);
  gemm_mfma_nt<1><<<dim3(MROWS / 128, XBCS / 128), 256, 0, stream>>>(
      u, DN, W_x_b, DN, xbc, XBCS, nullptr, DN, nullptr, dl_b);
  gemm_mfma_nt<3><<<dim3(MROWS / 128, DN / 128), 256, 0, stream>>>(
      dl_b, 64, W_dt_b, 64, xz, 4096, nullptr, 64, b_dt, nullptr);
  scan_part1<<<dim3(DN / 128, NCH, 4), 256, 0, stream>>>(
      u, xz, xbc, log_A, D_param, hbuf, Sbuf);
  scan_combine<<<4 * DN * 16 / 256, 256, 0, stream>>>(log_A, Sbuf, hbuf);
  scan_part2<<<dim3(DN / 128, NCH, 4), 256, 0, stream>>>(
      u, xz, xbc, xz, log_A, hbuf);
  cvt_bf16_kernel<<<(1024 * 2048 / 4) / 256, 256, 0, stream>>>(W_out, W_out_b, 1024 * 2048 / 4);
  if (use256) {
    gemm256<2><<<dim3(MROWS / 256, 1024 / 256), 512, 131072, stream>>>(
        u, DN, W_out_b, DN, out, DM, x, DN);
  } else {
    gemm_mfma_nt<2><<<dim3(MROWS / 128, 1024 / 128), 256, 0, stream>>>(
        u, DN, W_out_b, DN, out, DM, x, DN, nullptr, nullptr);
  }
}

// Round 10
// 603.460 us; speedup vs baseline: 1.3608x; 1.0272x over previous
//
#include <hip/hip_runtime.h>
#include <cstdint>
#include <cstddef>

#define TT 4096
#define DM 1024
#define DN 2048
#define MROWS 16384  // B*T
#define NCH 64       // scan chunks per sequence
#define CHL 64       // chunk length (TT/NCH)
#define SW 16        // staging window inside a chunk
#define XBCS 128     // xbc row stride (f32), padded from 96 for MFMA GEMM

typedef unsigned short u16;
typedef u16 ushort8_t __attribute__((ext_vector_type(8)));
typedef u16 ushort4_t __attribute__((ext_vector_type(4)));
typedef short bf16x8 __attribute__((ext_vector_type(8)));   // MFMA A/B frag (4 VGPR)
typedef float f32x4 __attribute__((ext_vector_type(4)));    // MFMA C/D frag

#define EXP2(x) __builtin_amdgcn_exp2f(x)
#define L2E 1.44269504f

__device__ __forceinline__ float bf2f(u16 b) {
  return __uint_as_float(((unsigned int)b) << 16);
}
__device__ __forceinline__ u16 f2bf(float f) {
  unsigned int u = __float_as_uint(f);
  u = u + 0x7FFFu + ((u >> 16) & 1u);   // round-to-nearest-even
  return (u16)(u >> 16);
}
__device__ __forceinline__ u16 f2h(float f) {
  _Float16 h = (_Float16)f;
  return __builtin_bit_cast(u16, h);
}
__device__ __forceinline__ float h2f(u16 v) {
  return (float)__builtin_bit_cast(_Float16, v);
}

__device__ __forceinline__ void gload_lds16(const void* g, void* l) {
  __builtin_amdgcn_global_load_lds(
      (const __attribute__((address_space(1))) unsigned int*)g,
      (__attribute__((address_space(3))) unsigned int*)l, 16, 0, 0);
}

#define FENCE() asm volatile("" ::: "memory")

// ---------------- f32 -> bf16 converter (weights) ----------------
__global__ __launch_bounds__(256) void cvt_bf16_kernel(const float* __restrict__ in,
    u16* __restrict__ out, int n4) {
  int i = blockIdx.x * 256 + threadIdx.x;
  if (i >= n4) return;
  float4 v = ((const float4*)in)[i];
  ushort4_t o; o[0] = f2bf(v.x); o[1] = f2bf(v.y); o[2] = f2bf(v.z); o[3] = f2bf(v.w);
  ((ushort4_t*)out)[i] = o;
}

// ---------------- W_x f32(96x2048) -> bf16(128x2048), rows 96..127 zero ----------------
__global__ __launch_bounds__(256) void cvt_wx_kernel(const float* __restrict__ W_x,
    u16* __restrict__ out) {
  int i = blockIdx.x * 256 + threadIdx.x;   // over 128*2048/4 = 65536 float4 slots
  int row = i >> 9;                         // 512 float4 per row
  ushort4_t o;
  if (row < 96) {
    float4 v = ((const float4*)W_x)[i];
    o[0] = f2bf(v.x); o[1] = f2bf(v.y); o[2] = f2bf(v.z); o[3] = f2bf(v.w);
  } else {
    o[0] = 0; o[1] = 0; o[2] = 0; o[3] = 0;
  }
  ((ushort4_t*)out)[i] = o;
}

// ---------------- LayerNorm -> bf16 out ----------------
__global__ __launch_bounds__(256) void ln_kernel(const float* __restrict__ x,
    const float* __restrict__ ln_w, const float* __restrict__ ln_b,
    u16* __restrict__ xn) {
  int row = blockIdx.x;
  int tid = threadIdx.x;
  const float4* xr = (const float4*)(x + (size_t)row * DM);
  float4 v = xr[tid];
  float s  = v.x + v.y + v.z + v.w;
  float s2 = v.x*v.x + v.y*v.y + v.z*v.z + v.w*v.w;
#pragma unroll
  for (int o = 32; o > 0; o >>= 1) { s += __shfl_down(s, o, 64); s2 += __shfl_down(s2, o, 64); }
  __shared__ float red[2][4];
  __shared__ float mv[2];
  int wid = tid >> 6, lane = tid & 63;
  if (lane == 0) { red[0][wid] = s; red[1][wid] = s2; }
  __syncthreads();
  if (tid == 0) {
    float a  = red[0][0] + red[0][1] + red[0][2] + red[0][3];
    float b2 = red[1][0] + red[1][1] + red[1][2] + red[1][3];
    float mean = a * (1.f / DM);
    float var  = b2 * (1.f / DM) - mean * mean;
    mv[0] = mean; mv[1] = rsqrtf(var + 1e-5f);
  }
  __syncthreads();
  float mean = mv[0], inv = mv[1];
  float4 w = ((const float4*)ln_w)[tid];
  float4 b = ((const float4*)ln_b)[tid];
  ushort4_t o;
  o[0] = f2bf((v.x - mean) * inv * w.x + b.x);
  o[1] = f2bf((v.y - mean) * inv * w.y + b.y);
  o[2] = f2bf((v.z - mean) * inv * w.z + b.z);
  o[3] = f2bf((v.w - mean) * inv * w.w + b.w);
  *(ushort4_t*)(xn + (size_t)row * DM + tid * 4) = o;
}

// ---------------- 128-tile bf16 MFMA GEMM ------------------------------------------------
// MODE 0: bf16 out. MODE 2: f32 out + residual add.
// MODE 3: f16 out = min(softplus(v+bias)+1e-3, 0.1).
// MODE 4: K-split partial (bj = K-segment of 2); f32 partial to Cp + bj*MROWS*128.
template<int MODE>
__global__ __launch_bounds__(256) void gemm_mfma_nt(
    const u16* __restrict__ A, int lda,
    const u16* __restrict__ B, int ldb,
    void* __restrict__ Cp, int ldc,
    const float* __restrict__ Res, int K,
    const float* __restrict__ bias, u16* __restrict__ dl_out) {
  __shared__ __align__(16) u16 a_s[128 * 64];
  __shared__ __align__(16) u16 b_s[128 * 64];
  const int tid = threadIdx.x;
  const int w = tid >> 6, l = tid & 63;
  const int wr = w >> 1, wc = w & 1;
  const int nbx = gridDim.x, gy = gridDim.y;
  int lin = blockIdx.y * nbx + blockIdx.x;
  int xcd = lin & 7;
  int m = lin >> 3;
  int bi, bj;
  if (gy >= 8) {
    int njx = gy >> 3;
    bi = m / njx;
    bj = xcd * njx + m % njx;
  } else {
    int cpx = (nbx * gy) >> 3;
    int swz = xcd * cpx + m;
    bi = swz % nbx; bj = swz / nbx;
  }
  const int lrow = l >> 3;
  const int scol = ((l & 7) ^ lrow) * 16;

  f32x4 acc[4][4] = {};

  const int brow = (MODE == 4) ? 0 : bj;   // MODE4: bj selects K-segment, not N-tile
  const u16* Abase = A + (size_t)(bi * 128 + w * 8 + lrow) * lda;
  const u16* Bbase = B + (size_t)(brow * 128 + w * 8 + lrow) * ldb;

  int kbeg = 0, kend = K;
  if constexpr (MODE == 4) { kbeg = bj * (K >> 1); kend = kbeg + (K >> 1); }
  for (int k0 = kbeg; k0 < kend; k0 += 64) {
#pragma unroll
    for (int c = 0; c < 4; c++) {
      const char* ga = (const char*)(Abase + (size_t)(c * 32) * lda + k0) + scol;
      const char* gb = (const char*)(Bbase + (size_t)(c * 32) * ldb + k0) + scol;
      gload_lds16(ga, (char*)a_s + c * 4096 + w * 1024);
      gload_lds16(gb, (char*)b_s + c * 4096 + w * 1024);
    }
    __syncthreads();
#pragma unroll
    for (int kk = 0; kk < 2; kk++) {
      bf16x8 af[4], bfr[4];
#pragma unroll
      for (int m2 = 0; m2 < 4; m2++) {
        int fr = wr * 64 + m2 * 16 + (l & 15);
        int cb = (kk * 64 + ((l >> 4) << 4)) ^ ((fr & 7) << 4);
        af[m2] = *(const bf16x8*)((const char*)a_s + fr * 128 + cb);
      }
#pragma unroll
      for (int n = 0; n < 4; n++) {
        int fr = wc * 64 + n * 16 + (l & 15);
        int cb = (kk * 64 + ((l >> 4) << 4)) ^ ((fr & 7) << 4);
        bfr[n] = *(const bf16x8*)((const char*)b_s + fr * 128 + cb);
      }
#pragma unroll
      for (int m2 = 0; m2 < 4; m2++)
#pragma unroll
        for (int n = 0; n < 4; n++)
          acc[m2][n] = __builtin_amdgcn_mfma_f32_16x16x32_bf16(af[m2], bfr[n], acc[m2][n], 0, 0, 0);
    }
    __syncthreads();
  }
  const int col0 = ((MODE == 4) ? 0 : bj * 128) + wc * 64 + (l & 15);
  const int row0 = bi * 128 + wr * 64 + (l >> 4) * 4;
#pragma unroll
  for (int m2 = 0; m2 < 4; m2++)
#pragma unroll
    for (int n = 0; n < 4; n++) {
      int col = col0 + n * 16;
      float bv = 0.f;
      if constexpr (MODE == 3) bv = bias[col];
#pragma unroll
      for (int r = 0; r < 4; r++) {
        size_t row = (size_t)(row0 + m2 * 16 + r);
        float v = acc[m2][n][r];
        if constexpr (MODE == 0) {
          ((u16*)Cp)[row * ldc + col] = f2bf(v);
        } else if constexpr (MODE == 2) {
          v += Res[row * ldc + col];
          ((float*)Cp)[row * ldc + col] = v;
        } else if constexpr (MODE == 4) {
          ((float*)Cp)[(size_t)bj * ((size_t)MROWS * 128) + row * ldc + col] = v;
        } else {
          float s = v + bv;
          float sp = __logf(1.f + __expf(s));
          float dtv = fminf(sp + 1e-3f, 0.1f);
          ((u16*)Cp)[row * ldc + col] = f2h(dtv);
        }
      }
    }
}

// ---------------- xbc K-split merge: xbc = p0+p1 (in place over p0), dl = bf16(cols<64) ---
__global__ __launch_bounds__(256) void xbc_merge(const float* __restrict__ p0,
    const float* __restrict__ p1, float* __restrict__ xbc, u16* __restrict__ dl) {
  int i = blockIdx.x * 256 + threadIdx.x;   // over MROWS*128/4 float4 slots
  float4 a = ((const float4*)p0)[i];
  float4 b = ((const float4*)p1)[i];
  float4 s; s.x = a.x + b.x; s.y = a.y + b.y; s.z = a.z + b.z; s.w = a.w + b.w;
  ((float4*)xbc)[i] = s;
  int col = (i & 31) * 4;                   // 32 float4 per 128-col row
  if (col < 64) {
    int row = i >> 5;
    ushort4_t o; o[0] = f2bf(s.x); o[1] = f2bf(s.y); o[2] = f2bf(s.z); o[3] = f2bf(s.w);
    *(ushort4_t*)(dl + (size_t)row * 64 + col) = o;
  }
}

// ---------------- 256x256 8-phase pipelined bf16 GEMM (r8 schedule — measured best) ------
// 512 thr / 8 waves (2m x 4n); per-wave out 128x64; BK=64; LDS 128KB dynamic:
// A[2][256x64] | B[2][256x64], row-XOR swizzle ((row&7)<<4) both sides.
// Per tile t, phases issue exactly one prefetch part each:
// [A2,A1,A3 of t+1; B0,B1,B2,B3,A0 of t+2]; waits: vmcnt(8)@ph0, vmcnt(10)@ph4.
// B fragments live in regs after ph0/ph2 -> B LDS dead after ph2's barrier.
template<int MODE>
__global__ __launch_bounds__(512) void gemm256(
    const u16* __restrict__ A, int lda,
    const u16* __restrict__ B, int ldb,
    void* __restrict__ Cp, int ldc,
    const float* __restrict__ Res, int K) {
  extern __shared__ char smem[];          // 131072 B
  const int tid = threadIdx.x;
  const int w = tid >> 6, l = tid & 63;
  const int wm = w >> 2, wn = w & 3;
  const int nbx = gridDim.x, gy = gridDim.y;
  int lin = blockIdx.y * nbx + blockIdx.x;
  int xcd = lin & 7, mm = lin >> 3;
  int bi, bj;
  if (gy >= 8) { int njx = gy >> 3; bi = mm / njx; bj = xcd * njx + mm % njx; }
  else { int cpx = (nbx * gy) >> 3; int swz = xcd * cpx + mm; bi = swz % nbx; bj = swz / nbx; }
  const int lrow = l >> 3;
  const int scol = ((l & 7) ^ lrow) * 16;
  const int l15 = l & 15, lhi = (l >> 4) << 4;
  const u16* aRow = A + (size_t)(bi * 256 + w * 8 + lrow) * lda;
  const u16* bRow = B + (size_t)(bj * 256 + w * 8 + lrow) * ldb;
  char* As = smem;
  char* Bs = smem + 65536;

#define IS_A(s, k) gload_lds16((const char*)(aRow + (size_t)((k) * 64) * lda + (size_t)(s) * 64) + scol, \
                               As + ((((s) & 1)) << 15) + (k) * 8192 + w * 1024)
#define IS_B(s, k) gload_lds16((const char*)(bRow + (size_t)((k) * 64) * ldb + (size_t)(s) * 64) + scol, \
                               Bs + ((((s) & 1)) << 15) + (k) * 8192 + w * 1024)

  f32x4 acc[8][4] = {};
  bf16x8 bf[2][4];
  const int NT = K >> 6;

  // prologue: tile0 fully [B0..B3,A0,A2,A1,A3], tile1 first 5 [B0..B3,A0] (13 issues)
  IS_B(0, 0); IS_B(0, 1); IS_B(0, 2); IS_B(0, 3);
  IS_A(0, 0); IS_A(0, 2); IS_A(0, 1); IS_A(0, 3);
  IS_B(1, 0); IS_B(1, 1); IS_B(1, 2); IS_B(1, 3); IS_A(1, 0);

#define MFMA8(MLO, KK) do { \
    bf16x8 a0_ = ardA(MLO, KK), a1_ = ardA((MLO) + 1, KK); \
    __builtin_amdgcn_s_setprio(1); \
    _Pragma("unroll") \
    for (int n_ = 0; n_ < 4; n_++) { \
      acc[MLO][n_]       = __builtin_amdgcn_mfma_f32_16x16x32_bf16(a0_, bf[KK][n_], acc[MLO][n_], 0, 0, 0); \
      acc[(MLO) + 1][n_] = __builtin_amdgcn_mfma_f32_16x16x32_bf16(a1_, bf[KK][n_], acc[(MLO) + 1][n_], 0, 0, 0); \
    } \
    __builtin_amdgcn_s_setprio(0); \
  } while (0)

  for (int t = 0; t < NT; ++t) {
    const char* Ab = As + ((t & 1) << 15);
    const char* Bb = Bs + ((t & 1) << 15);
    auto ardA = [&](int m, int kk) {
      int fr = wm * 128 + m * 16 + l15;
      int cb = (kk * 64 + lhi) ^ ((fr & 7) << 4);
      return *(const bf16x8*)(Ab + fr * 128 + cb);
    };
    auto ardB = [&](int n, int kk) {
      int fr = wn * 64 + n * 16 + l15;
      int cb = (kk * 64 + lhi) ^ ((fr & 7) << 4);
      return *(const bf16x8*)(Bb + fr * 128 + cb);
    };
    // ---- ph0 ----
    if (t + 1 < NT) IS_A(t + 1, 2);
    FENCE();
    asm volatile("s_waitcnt vmcnt(8)" ::: "memory");
    __builtin_amdgcn_s_barrier();
    FENCE();
    bf[0][0] = ardB(0, 0); bf[0][1] = ardB(1, 0); bf[0][2] = ardB(2, 0); bf[0][3] = ardB(3, 0);
    MFMA8(0, 0);
    // ---- ph1 ----
    if (t + 1 < NT) IS_A(t + 1, 1);
    MFMA8(2, 0);
    // ---- ph2 ----
    if (t + 1 < NT) IS_A(t + 1, 3);
    bf[1][0] = ardB(0, 1); bf[1][1] = ardB(1, 1); bf[1][2] = ardB(2, 1); bf[1][3] = ardB(3, 1);
    MFMA8(0, 1);
    FENCE();
    __builtin_amdgcn_s_barrier();     // B LDS (cur buf) dead past here
    FENCE();
    // ---- ph3 ----
    if (t + 2 < NT) IS_B(t + 2, 0);
    MFMA8(2, 1);
    // ---- ph4 ----
    if (t + 2 < NT) IS_B(t + 2, 1);
    FENCE();
    asm volatile("s_waitcnt vmcnt(10)" ::: "memory");
    __builtin_amdgcn_s_barrier();
    FENCE();
    MFMA8(4, 0);
    // ---- ph5 ----
    if (t + 2 < NT) IS_B(t + 2, 2);
    MFMA8(6, 0);
    // ---- ph6 ----
    if (t + 2 < NT) IS_B(t + 2, 3);
    MFMA8(4, 1);
    // ---- ph7 ----
    if (t + 2 < NT) IS_A(t + 2, 0);
    MFMA8(6, 1);
  }
#undef MFMA8
#undef IS_A
#undef IS_B

  const int col0 = bj * 256 + wn * 64 + l15;
  const int row0 = bi * 256 + wm * 128 + (l >> 4) * 4;
#pragma unroll
  for (int m = 0; m < 8; m++)
#pragma unroll
    for (int n = 0; n < 4; n++) {
      int col = col0 + n * 16;
#pragma unroll
      for (int r = 0; r < 4; r++) {
        size_t row = (size_t)(row0 + m * 16 + r);
        float v = acc[m][n][r];
        if constexpr (MODE == 0) {
          ((u16*)Cp)[row * ldc + col] = f2bf(v);
        } else {
          v += Res[row * ldc + col];
          ((float*)Cp)[row * ldc + col] = v;
        }
      }
    }
}

// ---------------- causal depthwise conv (width 4) + SiLU; bf16 in, bf16 out ----------------
__global__ __launch_bounds__(256) void conv_silu_kernel(const u16* __restrict__ xz,
    const float* __restrict__ conv_w, const float* __restrict__ conv_b,
    u16* __restrict__ u) {
  size_t gid = (size_t)blockIdx.x * 256 + threadIdx.x;
  int c = (int)(gid & 255);
  size_t i = gid >> 8;
  int t = (int)(i & (TT - 1));
  int d0 = c * 8;
  const u16* base = xz + i * 4096 + d0;
  ushort8_t r0 = *(const ushort8_t*)base;
  ushort8_t r1 = 0, r2 = 0, r3 = 0;
  if (t >= 1) r1 = *(const ushort8_t*)(base - 4096);
  if (t >= 2) r2 = *(const ushort8_t*)(base - 2 * 4096);
  if (t >= 3) r3 = *(const ushort8_t*)(base - 3 * 4096);
  float cbv[8];
  *(float4*)&cbv[0] = *(const float4*)(conv_b + d0);
  *(float4*)&cbv[4] = *(const float4*)(conv_b + d0 + 4);
  ushort8_t o;
#pragma unroll
  for (int j = 0; j < 8; j++) {
    float4 w = *(const float4*)(conv_w + (size_t)(d0 + j) * 4);
    float a = cbv[j] + w.w * bf2f(r0[j]) + w.z * bf2f(r1[j])
            + w.y * bf2f(r2[j]) + w.x * bf2f(r3[j]);
    a = a * __builtin_amdgcn_rcpf(1.f + EXP2(-a * L2E));
    o[j] = f2bf(a);
  }
  *(ushort8_t*)(u + i * 2048 + d0) = o;
}

// ---------------- scan phase 1: local chunk scan from h=0; writes y_local (f16) over u ----
__global__ __launch_bounds__(256) void scan_part1(u16* u_g,
    const u16* __restrict__ dt_g, const float* __restrict__ xbc,
    const float* __restrict__ log_A, const float* __restrict__ D_param,
    float* __restrict__ hbuf, float* __restrict__ Sbuf) {
  int d0 = blockIdx.x * 128;
  int c  = blockIdx.y;
  int b  = blockIdx.z;
  int tid = threadIdx.x;
  int w = tid >> 6, l = tid & 63;
  int dl = tid >> 1, q = tid & 1, q8 = q << 3;
  int d = d0 + dl;
  __shared__ __align__(16) u16 u_s[2][SW][128];     // 8K
  __shared__ __align__(16) u16 dts[2][SW][128];     // 8K
  __shared__ __align__(16) float bc_s[2][SW][32];   // 4K (B | C)

  float A2[8];
  {
    float4 la0 = *(const float4*)(log_A + (size_t)d * 16 + q8);
    float4 la1 = *(const float4*)(log_A + (size_t)d * 16 + q8 + 4);
    A2[0] = -EXP2(la0.x * L2E) * L2E; A2[1] = -EXP2(la0.y * L2E) * L2E;
    A2[2] = -EXP2(la0.z * L2E) * L2E; A2[3] = -EXP2(la0.w * L2E) * L2E;
    A2[4] = -EXP2(la1.x * L2E) * L2E; A2[5] = -EXP2(la1.y * L2E) * L2E;
    A2[6] = -EXP2(la1.z * L2E) * L2E; A2[7] = -EXP2(la1.w * L2E) * L2E;
  }
  float Dp = D_param[d];
  float h[8] = {};
  float sdt = 0.f;
  size_t t0 = (size_t)b * TT + (size_t)c * CHL;
  const int sr = w * 4 + (l >> 4);        // staging row in window
  const int sc = (l & 15) * 8;            // staging col (u16 units)
  u16* up = u_g + t0 * 2048 + d;

#define P1STAGE(wnd, pb) { size_t i0_ = t0 + (size_t)(wnd) * SW;                          \
    gload_lds16(u_g  + (i0_ + sr) * 2048 + d0 + sc, (char*)u_s[pb] + w * 1024);           \
    gload_lds16(dt_g + (i0_ + sr) * 4096 + d0 + sc, (char*)dts[pb] + w * 1024);           \
    if (w < 2) gload_lds16(xbc + (i0_ + w * 8 + (l >> 3)) * XBCS + 64 + (l & 7) * 4,      \
                           (char*)bc_s[pb] + w * 1024); }

  P1STAGE(0, 0);
  for (int wnd = 0; wnd < CHL / SW; wnd++) {
    int pb = wnd & 1;
    __syncthreads();
    if (wnd + 1 < CHL / SW) P1STAGE(wnd + 1, pb ^ 1);
#pragma unroll 4
    for (int tt = 0; tt < SW; tt++) {
      float dtv = h2f(dts[pb][tt][dl]);
      float uv  = bf2f(u_s[pb][tt][dl]);
      sdt += dtv;
      float xin = dtv * uv;
      float yv = q ? 0.f : uv * Dp;
      float4 B0 = *(const float4*)&bc_s[pb][tt][q8];
      float4 B1 = *(const float4*)&bc_s[pb][tt][q8 + 4];
      float4 C0 = *(const float4*)&bc_s[pb][tt][16 + q8];
      float4 C1 = *(const float4*)&bc_s[pb][tt][16 + q8 + 4];
      h[0] = __builtin_fmaf(EXP2(dtv * A2[0]), h[0], xin * B0.x); yv = __builtin_fmaf(h[0], C0.x, yv);
      h[1] = __builtin_fmaf(EXP2(dtv * A2[1]), h[1], xin * B0.y); yv = __builtin_fmaf(h[1], C0.y, yv);
      h[2] = __builtin_fmaf(EXP2(dtv * A2[2]), h[2], xin * B0.z); yv = __builtin_fmaf(h[2], C0.z, yv);
      h[3] = __builtin_fmaf(EXP2(dtv * A2[3]), h[3], xin * B0.w); yv = __builtin_fmaf(h[3], C0.w, yv);
      h[4] = __builtin_fmaf(EXP2(dtv * A2[4]), h[4], xin * B1.x); yv = __builtin_fmaf(h[4], C1.x, yv);
      h[5] = __builtin_fmaf(EXP2(dtv * A2[5]), h[5], xin * B1.y); yv = __builtin_fmaf(h[5], C1.y, yv);
      h[6] = __builtin_fmaf(EXP2(dtv * A2[6]), h[6], xin * B1.z); yv = __builtin_fmaf(h[6], C1.z, yv);
      h[7] = __builtin_fmaf(EXP2(dtv * A2[7]), h[7], xin * B1.w); yv = __builtin_fmaf(h[7], C1.w, yv);
      yv += __shfl_xor(yv, 1, 64);
      if (q == 0) *up = f2h(yv);
      up += 2048;
    }
  }
  float* hp = hbuf + (((size_t)b * NCH + c) * 16 + q8) * DN + d;
#pragma unroll
  for (int k = 0; k < 8; k++) hp[(size_t)k * DN] = h[k];
  if (q == 0) Sbuf[((size_t)b * NCH + c) * DN + d] = sdt;
#undef P1STAGE
}

// ---------------- scan phase 2: sequential chunk combine (in-place h_end -> h_start) -------
__global__ __launch_bounds__(256) void scan_combine(const float* __restrict__ log_A,
    const float* __restrict__ Sbuf, float* __restrict__ hbuf) {
  int idx = blockIdx.x * 256 + threadIdx.x;    // over B*16*DN
  int dd = idx & (DN - 1), n = (idx >> 11) & 15, b = idx >> 15;
  float A2 = -EXP2(log_A[(size_t)dd * 16 + n] * L2E) * L2E;
  float h = 0.f;
#pragma unroll
  for (int c = 0; c < NCH; c++) {
    size_t off = (((size_t)b * NCH + c) * 16 + n) * DN + dd;
    float hl = hbuf[off];
    float P = EXP2(A2 * Sbuf[((size_t)b * NCH + c) * DN + dd]);
    hbuf[off] = h;
    h = hl + P * h;
  }
}

// ---------------- scan phase 3: y = (y_local + C.(exp(A*cum) o h_start)) * silu(z) --------
__global__ __launch_bounds__(256) void scan_part2(u16* yl,
    const u16* __restrict__ xz, const float* __restrict__ xbc,
    const u16* __restrict__ dt_g, const float* __restrict__ log_A,
    const float* __restrict__ hbuf) {
  int d0 = blockIdx.x * 128;
  int c  = blockIdx.y;
  int b  = blockIdx.z;
  int tid = threadIdx.x;
  int w = tid >> 6, l = tid & 63;
  int dl = tid >> 1, q = tid & 1, q8 = q << 3;
  int d = d0 + dl;
  __shared__ __align__(16) u16 yls[2][SW][128];     // 8K
  __shared__ __align__(16) u16 z_s[2][SW][128];     // 8K
  __shared__ __align__(16) u16 dts[2][SW][128];     // 8K
  __shared__ __align__(16) float c_s[2][SW][16];    // 2K

  float A2[8];
  {
    float4 la0 = *(const float4*)(log_A + (size_t)d * 16 + q8);
    float4 la1 = *(const float4*)(log_A + (size_t)d * 16 + q8 + 4);
    A2[0] = -EXP2(la0.x * L2E) * L2E; A2[1] = -EXP2(la0.y * L2E) * L2E;
    A2[2] = -EXP2(la0.z * L2E) * L2E; A2[3] = -EXP2(la0.w * L2E) * L2E;
    A2[4] = -EXP2(la1.x * L2E) * L2E; A2[5] = -EXP2(la1.y * L2E) * L2E;
    A2[6] = -EXP2(la1.z * L2E) * L2E; A2[7] = -EXP2(la1.w * L2E) * L2E;
  }
  float hs[8];
  {
    const float* hp = hbuf + (((size_t)b * NCH + c) * 16 + q8) * DN + d;
#pragma unroll
    for (int k = 0; k < 8; k++) hs[k] = hp[(size_t)k * DN];
  }
  float cum = 0.f;
  size_t t0 = (size_t)b * TT + (size_t)c * CHL;
  const int sr = w * 4 + (l >> 4);
  const int sc = (l & 15) * 8;
  u16* ylp = yl + t0 * 2048 + d;

#define P2STAGE(wnd, pb) { size_t i0_ = t0 + (size_t)(wnd) * SW;                          \
    gload_lds16(yl   + (i0_ + sr) * 2048 + d0 + sc, (char*)yls[pb] + w * 1024);           \
    gload_lds16(xz   + (i0_ + sr) * 4096 + 2048 + d0 + sc, (char*)z_s[pb] + w * 1024);    \
    gload_lds16(dt_g + (i0_ + sr) * 4096 + d0 + sc, (char*)dts[pb] + w * 1024);           \
    if (w == 0) gload_lds16(xbc + (i0_ + (l >> 2)) * XBCS + 80 + (l & 3) * 4,             \
                            (char*)c_s[pb]); }

  P2STAGE(0, 0);
  for (int wnd = 0; wnd < CHL / SW; wnd++) {
    int pb = wnd & 1;
    __syncthreads();
    if (wnd + 1 < CHL / SW) P2STAGE(wnd + 1, pb ^ 1);
#pragma unroll 4
    for (int tt = 0; tt < SW; tt++) {
      float dtv = h2f(dts[pb][tt][dl]);
      cum += dtv;
      float4 C0 = *(const float4*)&c_s[pb][tt][q8];
      float4 C1 = *(const float4*)&c_s[pb][tt][q8 + 4];
      float yv = C0.x * (EXP2(cum * A2[0]) * hs[0]) + C0.y * (EXP2(cum * A2[1]) * hs[1])
               + C0.z * (EXP2(cum * A2[2]) * hs[2]) + C0.w * (EXP2(cum * A2[3]) * hs[3])
               + C1.x * (EXP2(cum * A2[4]) * hs[4]) + C1.y * (EXP2(cum * A2[5]) * hs[5])
               + C1.z * (EXP2(cum * A2[6]) * hs[6]) + C1.w * (EXP2(cum * A2[7]) * hs[7]);
      if (q == 0) yv += h2f(yls[pb][tt][dl]);
      yv += __shfl_xor(yv, 1, 64);
      float zv = bf2f(z_s[pb][tt][dl]);
      float sig = __builtin_amdgcn_rcpf(1.f + EXP2(-zv * L2E));
      if (q == 0) *ylp = f2bf(yv * zv * sig);
      ylp += 2048;
    }
  }
#undef P2STAGE
}

extern "C" void kernel_launch(void* const* d_in, const int* in_sizes, int n_in,
                              void* d_out, int out_size, void* d_ws, size_t ws_size,
                              hipStream_t stream) {
  const float* x       = (const float*)d_in[0];
  const float* W_in    = (const float*)d_in[1];
  const float* conv_w  = (const float*)d_in[2];
  const float* conv_b  = (const float*)d_in[3];
  const float* W_x     = (const float*)d_in[4];
  const float* W_dt    = (const float*)d_in[5];
  const float* b_dt    = (const float*)d_in[6];
  const float* log_A   = (const float*)d_in[7];
  const float* D_param = (const float*)d_in[8];
  const float* W_out   = (const float*)d_in[9];
  const float* ln_w    = (const float*)d_in[10];
  const float* ln_b    = (const float*)d_in[11];
  float* out = (float*)d_out;

  size_t need = (size_t)MROWS * 4096 * 2 + (size_t)MROWS * DN * 2 + (size_t)MROWS * 96 * 4;
  if (ws_size < need) return;
  u16*   xz  = (u16*)d_ws;                        // 16384 x 4096 bf16 (x_inner | z)
  u16*   u   = xz + (size_t)MROWS * 4096;         // 16384 x 2048 bf16 (u -> y_local -> y)
  u16*   W_out_b = (u16*)(u + (size_t)MROWS * DN);// 4MiB, gemm2 staging

  // d_out (64MiB) staging: all dead before gemm2 fully overwrites d_out
  u16*   xn_b    = (u16*)d_out;                                  // [0,32)MiB, dead after gemm1
  float* xbc_p   = (float*)d_out;                                // [0,16)MiB: K-split partials
  float* xbc     = (float*)d_out;                                // [0,8)MiB final (over part0)
  float* hbuf    = (float*)((char*)d_out + (8u << 20));          // [8,40)MiB (after merge)
  u16*   W_in_b  = (u16*)((char*)d_out + (40u << 20));           // [40,48)MiB
  float* Sbuf    = (float*)((char*)d_out + (48u << 20));         // [48,50)MiB
  u16*   W_x_b   = (u16*)((char*)d_out + (50u << 20));           // [50,50.5)MiB
  u16*   W_dt_b  = (u16*)((char*)d_out + (50u << 20) + (512u << 10)); // [50.5,50.75)
  u16*   dl_b    = (u16*)((char*)d_out + (51u << 20));           // [51,53)MiB

  // one-time opt-in for 128KB dynamic LDS; fall back to 128-tile GEMM if unavailable
  static int use256 = -1;
  if (use256 < 0) {
    hipError_t e0 = hipFuncSetAttribute(reinterpret_cast<const void*>(&gemm256<0>),
        hipFuncAttributeMaxDynamicSharedMemorySize, 131072);
    hipError_t e2 = hipFuncSetAttribute(reinterpret_cast<const void*>(&gemm256<2>),
        hipFuncAttributeMaxDynamicSharedMemorySize, 131072);
    use256 = (e0 == hipSuccess && e2 == hipSuccess) ? 1 : 0;
  }

  cvt_wx_kernel<<<(128 * 2048 / 4) / 256, 256, 0, stream>>>(W_x, W_x_b);
  cvt_bf16_kernel<<<(2048 * 64 / 4) / 256, 256, 0, stream>>>(W_dt, W_dt_b, 2048 * 64 / 4);
  ln_kernel<<<MROWS, 256, 0, stream>>>(x, ln_w, ln_b, xn_b);
  cvt_bf16_kernel<<<(4096 * 1024 / 4) / 256, 256, 0, stream>>>(W_in, W_in_b, 4096 * 1024 / 4);
  if (use256) {
    gemm256<0><<<dim3(MROWS / 256, 4096 / 256), 512, 131072, stream>>>(
        xn_b, DM, W_in_b, DM, xz, 4096, nullptr, DM);
  } else {
    gemm_mfma_nt<0><<<dim3(MROWS / 128, 4096 / 128), 256, 0, stream>>>(
        xn_b, DM, W_in_b, DM, xz, 4096, nullptr, DM, nullptr, nullptr);
  }
  conv_silu_kernel<<<MROWS, 256, 0, stream>>>(xz, conv_w, conv_b, u);
  // xbc = u @ W_x.T via 2-way K-split (256 blocks = 1/CU) + merge (also emits dl bf16)
  gemm_mfma_nt<4><<<dim3(MROWS / 128, 2), 256, 0, stream>>>(
      u, DN, W_x_b, DN, xbc_p, XBCS, nullptr, DN, nullptr, nullptr);
  xbc_merge<<<(MROWS * 128 / 4) / 256, 256, 0, stream>>>(
      xbc_p, xbc_p + (size_t)MROWS * 128, xbc, dl_b);
  // dt = min(softplus(dl @ W_dt.T + b_dt)+1e-3, 0.1) -> f16 into dead x_inner cols of xz
  gemm_mfma_nt<3><<<dim3(MROWS / 128, DN / 128), 256, 0, stream>>>(
      dl_b, 64, W_dt_b, 64, xz, 4096, nullptr, 64, b_dt, nullptr);
  scan_part1<<<dim3(DN / 128, NCH, 4), 256, 0, stream>>>(
      u, xz, xbc, log_A, D_param, hbuf, Sbuf);
  scan_combine<<<4 * DN * 16 / 256, 256, 0, stream>>>(log_A, Sbuf, hbuf);
  scan_part2<<<dim3(DN / 128, NCH, 4), 256, 0, stream>>>(
      u, xz, xbc, xz, log_A, hbuf);
  cvt_bf16_kernel<<<(1024 * 2048 / 4) / 256, 256, 0, stream>>>(W_out, W_out_b, 1024 * 2048 / 4);
  if (use256) {
    gemm256<2><<<dim3(MROWS / 256, 1024 / 256), 512, 131072, stream>>>(
        u, DN, W_out_b, DN, out, DM, x, DN);
  } else {
    gemm_mfma_nt<2><<<dim3(MROWS / 128, 1024 / 128), 256, 0, stream>>>(
        u, DN, W_out_b, DN, out, DM, x, DN, nullptr, nullptr);
  }
}

// Round 11
// 598.874 us; speedup vs baseline: 1.3712x; 1.0077x over previous
//
#include <hip/hip_runtime.h>
#include <cstdint>
#include <cstddef>

#define TT 4096
#define DM 1024
#define DN 2048
#define MROWS 16384  // B*T
#define NCH 64       // scan chunks per sequence
#define CHL 64       // chunk length (TT/NCH)
#define SW 16        // staging window inside a chunk
#define XBCS 128     // xbc row stride (f32), padded from 96 for MFMA GEMM

typedef unsigned short u16;
typedef u16 ushort8_t __attribute__((ext_vector_type(8)));
typedef u16 ushort4_t __attribute__((ext_vector_type(4)));
typedef short bf16x8 __attribute__((ext_vector_type(8)));   // MFMA A/B frag (4 VGPR)
typedef float f32x4 __attribute__((ext_vector_type(4)));    // MFMA C/D frag

#define EXP2(x) __builtin_amdgcn_exp2f(x)
#define L2E 1.44269504f

__device__ __forceinline__ float bf2f(u16 b) {
  return __uint_as_float(((unsigned int)b) << 16);
}
__device__ __forceinline__ u16 f2bf(float f) {
  unsigned int u = __float_as_uint(f);
  u = u + 0x7FFFu + ((u >> 16) & 1u);   // round-to-nearest-even
  return (u16)(u >> 16);
}
__device__ __forceinline__ u16 f2h(float f) {
  _Float16 h = (_Float16)f;
  return __builtin_bit_cast(u16, h);
}
__device__ __forceinline__ float h2f(u16 v) {
  return (float)__builtin_bit_cast(_Float16, v);
}

__device__ __forceinline__ void gload_lds16(const void* g, void* l) {
  __builtin_amdgcn_global_load_lds(
      (const __attribute__((address_space(1))) unsigned int*)g,
      (__attribute__((address_space(3))) unsigned int*)l, 16, 0, 0);
}

#define FENCE() asm volatile("" ::: "memory")

// ---------------- f32 -> bf16 converter (W_out late staging) ----------------
__global__ __launch_bounds__(256) void cvt_bf16_kernel(const float* __restrict__ in,
    u16* __restrict__ out, int n4) {
  int i = blockIdx.x * 256 + threadIdx.x;
  if (i >= n4) return;
  float4 v = ((const float4*)in)[i];
  ushort4_t o; o[0] = f2bf(v.x); o[1] = f2bf(v.y); o[2] = f2bf(v.z); o[3] = f2bf(v.w);
  ((ushort4_t*)out)[i] = o;
}

// ---------------- fused weight converts: W_in | W_x (pad 96->128, zero tail) | W_dt ------
__global__ __launch_bounds__(256) void cvt_weights_kernel(
    const float* __restrict__ W_in, u16* __restrict__ W_in_b,
    const float* __restrict__ W_x, u16* __restrict__ W_x_b,
    const float* __restrict__ W_dt, u16* __restrict__ W_dt_b) {
  int b = blockIdx.x, t = threadIdx.x;
  if (b < 4096) {                                  // W_in: 4096x1024 f32
    int i = b * 256 + t;
    float4 v = ((const float4*)W_in)[i];
    ushort4_t o; o[0] = f2bf(v.x); o[1] = f2bf(v.y); o[2] = f2bf(v.z); o[3] = f2bf(v.w);
    ((ushort4_t*)W_in_b)[i] = o;
  } else if (b < 4352) {                           // W_x -> 128x2048 bf16 (rows>=96 zero)
    int i = (b - 4096) * 256 + t;
    int row = i >> 9;                              // 512 float4 per row
    ushort4_t o;
    if (row < 96) {
      float4 v = ((const float4*)W_x)[i];
      o[0] = f2bf(v.x); o[1] = f2bf(v.y); o[2] = f2bf(v.z); o[3] = f2bf(v.w);
    } else {
      o[0] = 0; o[1] = 0; o[2] = 0; o[3] = 0;
    }
    ((ushort4_t*)W_x_b)[i] = o;
  } else {                                         // W_dt: 2048x64 f32
    int i = (b - 4352) * 256 + t;
    float4 v = ((const float4*)W_dt)[i];
    ushort4_t o; o[0] = f2bf(v.x); o[1] = f2bf(v.y); o[2] = f2bf(v.z); o[3] = f2bf(v.w);
    ((ushort4_t*)W_dt_b)[i] = o;
  }
}

// ---------------- LayerNorm -> bf16 out ----------------
__global__ __launch_bounds__(256) void ln_kernel(const float* __restrict__ x,
    const float* __restrict__ ln_w, const float* __restrict__ ln_b,
    u16* __restrict__ xn) {
  int row = blockIdx.x;
  int tid = threadIdx.x;
  const float4* xr = (const float4*)(x + (size_t)row * DM);
  float4 v = xr[tid];
  float s  = v.x + v.y + v.z + v.w;
  float s2 = v.x*v.x + v.y*v.y + v.z*v.z + v.w*v.w;
#pragma unroll
  for (int o = 32; o > 0; o >>= 1) { s += __shfl_down(s, o, 64); s2 += __shfl_down(s2, o, 64); }
  __shared__ float red[2][4];
  __shared__ float mv[2];
  int wid = tid >> 6, lane = tid & 63;
  if (lane == 0) { red[0][wid] = s; red[1][wid] = s2; }
  __syncthreads();
  if (tid == 0) {
    float a  = red[0][0] + red[0][1] + red[0][2] + red[0][3];
    float b2 = red[1][0] + red[1][1] + red[1][2] + red[1][3];
    float mean = a * (1.f / DM);
    float var  = b2 * (1.f / DM) - mean * mean;
    mv[0] = mean; mv[1] = rsqrtf(var + 1e-5f);
  }
  __syncthreads();
  float mean = mv[0], inv = mv[1];
  float4 w = ((const float4*)ln_w)[tid];
  float4 b = ((const float4*)ln_b)[tid];
  ushort4_t o;
  o[0] = f2bf((v.x - mean) * inv * w.x + b.x);
  o[1] = f2bf((v.y - mean) * inv * w.y + b.y);
  o[2] = f2bf((v.z - mean) * inv * w.z + b.z);
  o[3] = f2bf((v.w - mean) * inv * w.w + b.w);
  *(ushort4_t*)(xn + (size_t)row * DM + tid * 4) = o;
}

// ---------------- 128-tile bf16 MFMA GEMM ------------------------------------------------
// MODE 0: bf16 out. MODE 2: f32 out + residual add (nontemporal).
// MODE 3: f16 out = min(softplus(v+bias)+1e-3, 0.1).
// MODE 4: K-split partial (bj = K-quarter of 4); f32 partial to Cp + bj*MROWS*128.
template<int MODE>
__global__ __launch_bounds__(256) void gemm_mfma_nt(
    const u16* __restrict__ A, int lda,
    const u16* __restrict__ B, int ldb,
    void* __restrict__ Cp, int ldc,
    const float* __restrict__ Res, int K,
    const float* __restrict__ bias, u16* __restrict__ dl_out) {
  __shared__ __align__(16) u16 a_s[128 * 64];
  __shared__ __align__(16) u16 b_s[128 * 64];
  const int tid = threadIdx.x;
  const int w = tid >> 6, l = tid & 63;
  const int wr = w >> 1, wc = w & 1;
  const int nbx = gridDim.x, gy = gridDim.y;
  int lin = blockIdx.y * nbx + blockIdx.x;
  int xcd = lin & 7;
  int m = lin >> 3;
  int bi, bj;
  if (gy >= 8) {
    int njx = gy >> 3;
    bi = m / njx;
    bj = xcd * njx + m % njx;
  } else {
    int cpx = (nbx * gy) >> 3;
    int swz = xcd * cpx + m;
    bi = swz % nbx; bj = swz / nbx;
  }
  const int lrow = l >> 3;
  const int scol = ((l & 7) ^ lrow) * 16;

  f32x4 acc[4][4] = {};

  const int brow = (MODE == 4) ? 0 : bj;   // MODE4: bj selects K-segment, not N-tile
  const u16* Abase = A + (size_t)(bi * 128 + w * 8 + lrow) * lda;
  const u16* Bbase = B + (size_t)(brow * 128 + w * 8 + lrow) * ldb;

  int kbeg = 0, kend = K;
  if constexpr (MODE == 4) { kbeg = bj * (K >> 2); kend = kbeg + (K >> 2); }
  for (int k0 = kbeg; k0 < kend; k0 += 64) {
#pragma unroll
    for (int c = 0; c < 4; c++) {
      const char* ga = (const char*)(Abase + (size_t)(c * 32) * lda + k0) + scol;
      const char* gb = (const char*)(Bbase + (size_t)(c * 32) * ldb + k0) + scol;
      gload_lds16(ga, (char*)a_s + c * 4096 + w * 1024);
      gload_lds16(gb, (char*)b_s + c * 4096 + w * 1024);
    }
    __syncthreads();
#pragma unroll
    for (int kk = 0; kk < 2; kk++) {
      bf16x8 af[4], bfr[4];
#pragma unroll
      for (int m2 = 0; m2 < 4; m2++) {
        int fr = wr * 64 + m2 * 16 + (l & 15);
        int cb = (kk * 64 + ((l >> 4) << 4)) ^ ((fr & 7) << 4);
        af[m2] = *(const bf16x8*)((const char*)a_s + fr * 128 + cb);
      }
#pragma unroll
      for (int n = 0; n < 4; n++) {
        int fr = wc * 64 + n * 16 + (l & 15);
        int cb = (kk * 64 + ((l >> 4) << 4)) ^ ((fr & 7) << 4);
        bfr[n] = *(const bf16x8*)((const char*)b_s + fr * 128 + cb);
      }
#pragma unroll
      for (int m2 = 0; m2 < 4; m2++)
#pragma unroll
        for (int n = 0; n < 4; n++)
          acc[m2][n] = __builtin_amdgcn_mfma_f32_16x16x32_bf16(af[m2], bfr[n], acc[m2][n], 0, 0, 0);
    }
    __syncthreads();
  }
  const int col0 = ((MODE == 4) ? 0 : bj * 128) + wc * 64 + (l & 15);
  const int row0 = bi * 128 + wr * 64 + (l >> 4) * 4;
#pragma unroll
  for (int m2 = 0; m2 < 4; m2++)
#pragma unroll
    for (int n = 0; n < 4; n++) {
      int col = col0 + n * 16;
      float bv = 0.f;
      if constexpr (MODE == 3) bv = bias[col];
#pragma unroll
      for (int r = 0; r < 4; r++) {
        size_t row = (size_t)(row0 + m2 * 16 + r);
        float v = acc[m2][n][r];
        if constexpr (MODE == 0) {
          ((u16*)Cp)[row * ldc + col] = f2bf(v);
        } else if constexpr (MODE == 2) {
          v += __builtin_nontemporal_load(&Res[row * ldc + col]);
          __builtin_nontemporal_store(v, &((float*)Cp)[row * ldc + col]);
        } else if constexpr (MODE == 4) {
          ((float*)Cp)[(size_t)bj * ((size_t)MROWS * 128) + row * ldc + col] = v;
        } else {
          float s = v + bv;
          float sp = __logf(1.f + __expf(s));
          float dtv = fminf(sp + 1e-3f, 0.1f);
          ((u16*)Cp)[row * ldc + col] = f2h(dtv);
        }
      }
    }
}

// ---------------- xbc K-split merge: xbc = p0+p1+p2+p3 (in place over p0), dl bf16 -------
__global__ __launch_bounds__(256) void xbc_merge(const float* __restrict__ p,
    float* __restrict__ xbc, u16* __restrict__ dl) {
  int i = blockIdx.x * 256 + threadIdx.x;        // over MROWS*128/4 float4 slots
  const size_t PS = (size_t)MROWS * 128 / 4;     // partial stride in float4
  float4 a = ((const float4*)p)[i];
  float4 b = ((const float4*)p)[i + PS];
  float4 c = ((const float4*)p)[i + 2 * PS];
  float4 d = ((const float4*)p)[i + 3 * PS];
  float4 s;
  s.x = (a.x + b.x) + (c.x + d.x);
  s.y = (a.y + b.y) + (c.y + d.y);
  s.z = (a.z + b.z) + (c.z + d.z);
  s.w = (a.w + b.w) + (c.w + d.w);
  ((float4*)xbc)[i] = s;
  int col = (i & 31) * 4;                        // 32 float4 per 128-col row
  if (col < 64) {
    int row = i >> 5;
    ushort4_t o; o[0] = f2bf(s.x); o[1] = f2bf(s.y); o[2] = f2bf(s.z); o[3] = f2bf(s.w);
    *(ushort4_t*)(dl + (size_t)row * 64 + col) = o;
  }
}

// ---------------- 256x256 8-phase pipelined bf16 GEMM (r8 schedule — measured best) ------
// Per tile t, phases issue exactly one prefetch part each:
// [A2,A1,A3 of t+1; B0,B1,B2,B3,A0 of t+2]; waits: vmcnt(8)@ph0, vmcnt(10)@ph4.
template<int MODE>
__global__ __launch_bounds__(512) void gemm256(
    const u16* __restrict__ A, int lda,
    const u16* __restrict__ B, int ldb,
    void* __restrict__ Cp, int ldc,
    const float* __restrict__ Res, int K) {
  extern __shared__ char smem[];          // 131072 B
  const int tid = threadIdx.x;
  const int w = tid >> 6, l = tid & 63;
  const int wm = w >> 2, wn = w & 3;
  const int nbx = gridDim.x, gy = gridDim.y;
  int lin = blockIdx.y * nbx + blockIdx.x;
  int xcd = lin & 7, mm = lin >> 3;
  int bi, bj;
  if (gy >= 8) { int njx = gy >> 3; bi = mm / njx; bj = xcd * njx + mm % njx; }
  else { int cpx = (nbx * gy) >> 3; int swz = xcd * cpx + mm; bi = swz % nbx; bj = swz / nbx; }
  const int lrow = l >> 3;
  const int scol = ((l & 7) ^ lrow) * 16;
  const int l15 = l & 15, lhi = (l >> 4) << 4;
  const u16* aRow = A + (size_t)(bi * 256 + w * 8 + lrow) * lda;
  const u16* bRow = B + (size_t)(bj * 256 + w * 8 + lrow) * ldb;
  char* As = smem;
  char* Bs = smem + 65536;

#define IS_A(s, k) gload_lds16((const char*)(aRow + (size_t)((k) * 64) * lda + (size_t)(s) * 64) + scol, \
                               As + ((((s) & 1)) << 15) + (k) * 8192 + w * 1024)
#define IS_B(s, k) gload_lds16((const char*)(bRow + (size_t)((k) * 64) * ldb + (size_t)(s) * 64) + scol, \
                               Bs + ((((s) & 1)) << 15) + (k) * 8192 + w * 1024)

  f32x4 acc[8][4] = {};
  bf16x8 bf[2][4];
  const int NT = K >> 6;

  // prologue: tile0 fully [B0..B3,A0,A2,A1,A3], tile1 first 5 [B0..B3,A0] (13 issues)
  IS_B(0, 0); IS_B(0, 1); IS_B(0, 2); IS_B(0, 3);
  IS_A(0, 0); IS_A(0, 2); IS_A(0, 1); IS_A(0, 3);
  IS_B(1, 0); IS_B(1, 1); IS_B(1, 2); IS_B(1, 3); IS_A(1, 0);

#define MFMA8(MLO, KK) do { \
    bf16x8 a0_ = ardA(MLO, KK), a1_ = ardA((MLO) + 1, KK); \
    __builtin_amdgcn_s_setprio(1); \
    _Pragma("unroll") \
    for (int n_ = 0; n_ < 4; n_++) { \
      acc[MLO][n_]       = __builtin_amdgcn_mfma_f32_16x16x32_bf16(a0_, bf[KK][n_], acc[MLO][n_], 0, 0, 0); \
      acc[(MLO) + 1][n_] = __builtin_amdgcn_mfma_f32_16x16x32_bf16(a1_, bf[KK][n_], acc[(MLO) + 1][n_], 0, 0, 0); \
    } \
    __builtin_amdgcn_s_setprio(0); \
  } while (0)

  for (int t = 0; t < NT; ++t) {
    const char* Ab = As + ((t & 1) << 15);
    const char* Bb = Bs + ((t & 1) << 15);
    auto ardA = [&](int m, int kk) {
      int fr = wm * 128 + m * 16 + l15;
      int cb = (kk * 64 + lhi) ^ ((fr & 7) << 4);
      return *(const bf16x8*)(Ab + fr * 128 + cb);
    };
    auto ardB = [&](int n, int kk) {
      int fr = wn * 64 + n * 16 + l15;
      int cb = (kk * 64 + lhi) ^ ((fr & 7) << 4);
      return *(const bf16x8*)(Bb + fr * 128 + cb);
    };
    // ---- ph0 ----
    if (t + 1 < NT) IS_A(t + 1, 2);
    FENCE();
    asm volatile("s_waitcnt vmcnt(8)" ::: "memory");
    __builtin_amdgcn_s_barrier();
    FENCE();
    bf[0][0] = ardB(0, 0); bf[0][1] = ardB(1, 0); bf[0][2] = ardB(2, 0); bf[0][3] = ardB(3, 0);
    MFMA8(0, 0);
    // ---- ph1 ----
    if (t + 1 < NT) IS_A(t + 1, 1);
    MFMA8(2, 0);
    // ---- ph2 ----
    if (t + 1 < NT) IS_A(t + 1, 3);
    bf[1][0] = ardB(0, 1); bf[1][1] = ardB(1, 1); bf[1][2] = ardB(2, 1); bf[1][3] = ardB(3, 1);
    MFMA8(0, 1);
    FENCE();
    __builtin_amdgcn_s_barrier();     // B LDS (cur buf) dead past here
    FENCE();
    // ---- ph3 ----
    if (t + 2 < NT) IS_B(t + 2, 0);
    MFMA8(2, 1);
    // ---- ph4 ----
    if (t + 2 < NT) IS_B(t + 2, 1);
    FENCE();
    asm volatile("s_waitcnt vmcnt(10)" ::: "memory");
    __builtin_amdgcn_s_barrier();
    FENCE();
    MFMA8(4, 0);
    // ---- ph5 ----
    if (t + 2 < NT) IS_B(t + 2, 2);
    MFMA8(6, 0);
    // ---- ph6 ----
    if (t + 2 < NT) IS_B(t + 2, 3);
    MFMA8(4, 1);
    // ---- ph7 ----
    if (t + 2 < NT) IS_A(t + 2, 0);
    MFMA8(6, 1);
  }
#undef MFMA8
#undef IS_A
#undef IS_B

  const int col0 = bj * 256 + wn * 64 + l15;
  const int row0 = bi * 256 + wm * 128 + (l >> 4) * 4;
#pragma unroll
  for (int m = 0; m < 8; m++)
#pragma unroll
    for (int n = 0; n < 4; n++) {
      int col = col0 + n * 16;
#pragma unroll
      for (int r = 0; r < 4; r++) {
        size_t row = (size_t)(row0 + m * 16 + r);
        float v = acc[m][n][r];
        if constexpr (MODE == 0) {
          ((u16*)Cp)[row * ldc + col] = f2bf(v);
        } else {
          v += __builtin_nontemporal_load(&Res[row * ldc + col]);
          __builtin_nontemporal_store(v, &((float*)Cp)[row * ldc + col]);
        }
      }
    }
}

// ---------------- causal depthwise conv (width 4) + SiLU; bf16 in, bf16 out ----------------
__global__ __launch_bounds__(256) void conv_silu_kernel(const u16* __restrict__ xz,
    const float* __restrict__ conv_w, const float* __restrict__ conv_b,
    u16* __restrict__ u) {
  size_t gid = (size_t)blockIdx.x * 256 + threadIdx.x;
  int c = (int)(gid & 255);
  size_t i = gid >> 8;
  int t = (int)(i & (TT - 1));
  int d0 = c * 8;
  const u16* base = xz + i * 4096 + d0;
  ushort8_t r0 = *(const ushort8_t*)base;
  ushort8_t r1 = 0, r2 = 0, r3 = 0;
  if (t >= 1) r1 = *(const ushort8_t*)(base - 4096);
  if (t >= 2) r2 = *(const ushort8_t*)(base - 2 * 4096);
  if (t >= 3) r3 = *(const ushort8_t*)(base - 3 * 4096);
  float cbv[8];
  *(float4*)&cbv[0] = *(const float4*)(conv_b + d0);
  *(float4*)&cbv[4] = *(const float4*)(conv_b + d0 + 4);
  ushort8_t o;
#pragma unroll
  for (int j = 0; j < 8; j++) {
    float4 w = *(const float4*)(conv_w + (size_t)(d0 + j) * 4);
    float a = cbv[j] + w.w * bf2f(r0[j]) + w.z * bf2f(r1[j])
            + w.y * bf2f(r2[j]) + w.x * bf2f(r3[j]);
    a = a * __builtin_amdgcn_rcpf(1.f + EXP2(-a * L2E));
    o[j] = f2bf(a);
  }
  *(ushort8_t*)(u + i * 2048 + d0) = o;
}

// ---------------- scan phase 1: local chunk scan from h=0; y_local (f16) over u ----------
// hbuf is f16 [b][c][n][d].
__global__ __launch_bounds__(256) void scan_part1(u16* u_g,
    const u16* __restrict__ dt_g, const float* __restrict__ xbc,
    const float* __restrict__ log_A, const float* __restrict__ D_param,
    u16* __restrict__ hbuf, float* __restrict__ Sbuf) {
  int d0 = blockIdx.x * 128;
  int c  = blockIdx.y;
  int b  = blockIdx.z;
  int tid = threadIdx.x;
  int w = tid >> 6, l = tid & 63;
  int dl = tid >> 1, q = tid & 1, q8 = q << 3;
  int d = d0 + dl;
  __shared__ __align__(16) u16 u_s[2][SW][128];     // 8K
  __shared__ __align__(16) u16 dts[2][SW][128];     // 8K
  __shared__ __align__(16) float bc_s[2][SW][32];   // 4K (B | C)

  float A2[8];
  {
    float4 la0 = *(const float4*)(log_A + (size_t)d * 16 + q8);
    float4 la1 = *(const float4*)(log_A + (size_t)d * 16 + q8 + 4);
    A2[0] = -EXP2(la0.x * L2E) * L2E; A2[1] = -EXP2(la0.y * L2E) * L2E;
    A2[2] = -EXP2(la0.z * L2E) * L2E; A2[3] = -EXP2(la0.w * L2E) * L2E;
    A2[4] = -EXP2(la1.x * L2E) * L2E; A2[5] = -EXP2(la1.y * L2E) * L2E;
    A2[6] = -EXP2(la1.z * L2E) * L2E; A2[7] = -EXP2(la1.w * L2E) * L2E;
  }
  float Dp = D_param[d];
  float h[8] = {};
  float sdt = 0.f;
  size_t t0 = (size_t)b * TT + (size_t)c * CHL;
  const int sr = w * 4 + (l >> 4);        // staging row in window
  const int sc = (l & 15) * 8;            // staging col (u16 units)
  u16* up = u_g + t0 * 2048 + d;

#define P1STAGE(wnd, pb) { size_t i0_ = t0 + (size_t)(wnd) * SW;                          \
    gload_lds16(u_g  + (i0_ + sr) * 2048 + d0 + sc, (char*)u_s[pb] + w * 1024);           \
    gload_lds16(dt_g + (i0_ + sr) * 4096 + d0 + sc, (char*)dts[pb] + w * 1024);           \
    if (w < 2) gload_lds16(xbc + (i0_ + w * 8 + (l >> 3)) * XBCS + 64 + (l & 7) * 4,      \
                           (char*)bc_s[pb] + w * 1024); }

  P1STAGE(0, 0);
  for (int wnd = 0; wnd < CHL / SW; wnd++) {
    int pb = wnd & 1;
    __syncthreads();
    if (wnd + 1 < CHL / SW) P1STAGE(wnd + 1, pb ^ 1);
#pragma unroll 4
    for (int tt = 0; tt < SW; tt++) {
      float dtv = h2f(dts[pb][tt][dl]);
      float uv  = bf2f(u_s[pb][tt][dl]);
      sdt += dtv;
      float xin = dtv * uv;
      float yv = q ? 0.f : uv * Dp;
      float4 B0 = *(const float4*)&bc_s[pb][tt][q8];
      float4 B1 = *(const float4*)&bc_s[pb][tt][q8 + 4];
      float4 C0 = *(const float4*)&bc_s[pb][tt][16 + q8];
      float4 C1 = *(const float4*)&bc_s[pb][tt][16 + q8 + 4];
      h[0] = __builtin_fmaf(EXP2(dtv * A2[0]), h[0], xin * B0.x); yv = __builtin_fmaf(h[0], C0.x, yv);
      h[1] = __builtin_fmaf(EXP2(dtv * A2[1]), h[1], xin * B0.y); yv = __builtin_fmaf(h[1], C0.y, yv);
      h[2] = __builtin_fmaf(EXP2(dtv * A2[2]), h[2], xin * B0.z); yv = __builtin_fmaf(h[2], C0.z, yv);
      h[3] = __builtin_fmaf(EXP2(dtv * A2[3]), h[3], xin * B0.w); yv = __builtin_fmaf(h[3], C0.w, yv);
      h[4] = __builtin_fmaf(EXP2(dtv * A2[4]), h[4], xin * B1.x); yv = __builtin_fmaf(h[4], C1.x, yv);
      h[5] = __builtin_fmaf(EXP2(dtv * A2[5]), h[5], xin * B1.y); yv = __builtin_fmaf(h[5], C1.y, yv);
      h[6] = __builtin_fmaf(EXP2(dtv * A2[6]), h[6], xin * B1.z); yv = __builtin_fmaf(h[6], C1.z, yv);
      h[7] = __builtin_fmaf(EXP2(dtv * A2[7]), h[7], xin * B1.w); yv = __builtin_fmaf(h[7], C1.w, yv);
      yv += __shfl_xor(yv, 1, 64);
      if (q == 0) *up = f2h(yv);
      up += 2048;
    }
  }
  u16* hp = hbuf + (((size_t)b * NCH + c) * 16 + q8) * DN + d;
#pragma unroll
  for (int k = 0; k < 8; k++) hp[(size_t)k * DN] = f2h(h[k]);
  if (q == 0) Sbuf[((size_t)b * NCH + c) * DN + d] = sdt;
#undef P1STAGE
}

// ---------------- scan phase 2: sequential chunk combine (f16 hbuf, in place) -------------
__global__ __launch_bounds__(256) void scan_combine(const float* __restrict__ log_A,
    const float* __restrict__ Sbuf, u16* __restrict__ hbuf) {
  int idx = blockIdx.x * 256 + threadIdx.x;    // over B*16*DN
  int dd = idx & (DN - 1), n = (idx >> 11) & 15, b = idx >> 15;
  float A2 = -EXP2(log_A[(size_t)dd * 16 + n] * L2E) * L2E;
  float h = 0.f;
#pragma unroll
  for (int c = 0; c < NCH; c++) {
    size_t off = (((size_t)b * NCH + c) * 16 + n) * DN + dd;
    float hl = h2f(hbuf[off]);
    float P = EXP2(A2 * Sbuf[((size_t)b * NCH + c) * DN + dd]);
    hbuf[off] = f2h(h);
    h = hl + P * h;
  }
}

// ---------------- scan phase 3: y = (y_local + C.(exp(A*cum) o h_start)) * silu(z) --------
__global__ __launch_bounds__(256) void scan_part2(u16* yl,
    const u16* __restrict__ xz, const float* __restrict__ xbc,
    const u16* __restrict__ dt_g, const float* __restrict__ log_A,
    const u16* __restrict__ hbuf) {
  int d0 = blockIdx.x * 128;
  int c  = blockIdx.y;
  int b  = blockIdx.z;
  int tid = threadIdx.x;
  int w = tid >> 6, l = tid & 63;
  int dl = tid >> 1, q = tid & 1, q8 = q << 3;
  int d = d0 + dl;
  __shared__ __align__(16) u16 yls[2][SW][128];     // 8K
  __shared__ __align__(16) u16 z_s[2][SW][128];     // 8K
  __shared__ __align__(16) u16 dts[2][SW][128];     // 8K
  __shared__ __align__(16) float c_s[2][SW][16];    // 2K

  float A2[8];
  {
    float4 la0 = *(const float4*)(log_A + (size_t)d * 16 + q8);
    float4 la1 = *(const float4*)(log_A + (size_t)d * 16 + q8 + 4);
    A2[0] = -EXP2(la0.x * L2E) * L2E; A2[1] = -EXP2(la0.y * L2E) * L2E;
    A2[2] = -EXP2(la0.z * L2E) * L2E; A2[3] = -EXP2(la0.w * L2E) * L2E;
    A2[4] = -EXP2(la1.x * L2E) * L2E; A2[5] = -EXP2(la1.y * L2E) * L2E;
    A2[6] = -EXP2(la1.z * L2E) * L2E; A2[7] = -EXP2(la1.w * L2E) * L2E;
  }
  float hs[8];
  {
    const u16* hp = hbuf + (((size_t)b * NCH + c) * 16 + q8) * DN + d;
#pragma unroll
    for (int k = 0; k < 8; k++) hs[k] = h2f(hp[(size_t)k * DN]);
  }
  float cum = 0.f;
  size_t t0 = (size_t)b * TT + (size_t)c * CHL;
  const int sr = w * 4 + (l >> 4);
  const int sc = (l & 15) * 8;
  u16* ylp = yl + t0 * 2048 + d;

#define P2STAGE(wnd, pb) { size_t i0_ = t0 + (size_t)(wnd) * SW;                          \
    gload_lds16(yl   + (i0_ + sr) * 2048 + d0 + sc, (char*)yls[pb] + w * 1024);           \
    gload_lds16(xz   + (i0_ + sr) * 4096 + 2048 + d0 + sc, (char*)z_s[pb] + w * 1024);    \
    gload_lds16(dt_g + (i0_ + sr) * 4096 + d0 + sc, (char*)dts[pb] + w * 1024);           \
    if (w == 0) gload_lds16(xbc + (i0_ + (l >> 2)) * XBCS + 80 + (l & 3) * 4,             \
                            (char*)c_s[pb]); }

  P2STAGE(0, 0);
  for (int wnd = 0; wnd < CHL / SW; wnd++) {
    int pb = wnd & 1;
    __syncthreads();
    if (wnd + 1 < CHL / SW) P2STAGE(wnd + 1, pb ^ 1);
#pragma unroll 4
    for (int tt = 0; tt < SW; tt++) {
      float dtv = h2f(dts[pb][tt][dl]);
      cum += dtv;
      float4 C0 = *(const float4*)&c_s[pb][tt][q8];
      float4 C1 = *(const float4*)&c_s[pb][tt][q8 + 4];
      float yv = C0.x * (EXP2(cum * A2[0]) * hs[0]) + C0.y * (EXP2(cum * A2[1]) * hs[1])
               + C0.z * (EXP2(cum * A2[2]) * hs[2]) + C0.w * (EXP2(cum * A2[3]) * hs[3])
               + C1.x * (EXP2(cum * A2[4]) * hs[4]) + C1.y * (EXP2(cum * A2[5]) * hs[5])
               + C1.z * (EXP2(cum * A2[6]) * hs[6]) + C1.w * (EXP2(cum * A2[7]) * hs[7]);
      if (q == 0) yv += h2f(yls[pb][tt][dl]);
      yv += __shfl_xor(yv, 1, 64);
      float zv = bf2f(z_s[pb][tt][dl]);
      float sig = __builtin_amdgcn_rcpf(1.f + EXP2(-zv * L2E));
      if (q == 0) *ylp = f2bf(yv * zv * sig);
      ylp += 2048;
    }
  }
#undef P2STAGE
}

extern "C" void kernel_launch(void* const* d_in, const int* in_sizes, int n_in,
                              void* d_out, int out_size, void* d_ws, size_t ws_size,
                              hipStream_t stream) {
  const float* x       = (const float*)d_in[0];
  const float* W_in    = (const float*)d_in[1];
  const float* conv_w  = (const float*)d_in[2];
  const float* conv_b  = (const float*)d_in[3];
  const float* W_x     = (const float*)d_in[4];
  const float* W_dt    = (const float*)d_in[5];
  const float* b_dt    = (const float*)d_in[6];
  const float* log_A   = (const float*)d_in[7];
  const float* D_param = (const float*)d_in[8];
  const float* W_out   = (const float*)d_in[9];
  const float* ln_w    = (const float*)d_in[10];
  const float* ln_b    = (const float*)d_in[11];
  float* out = (float*)d_out;

  size_t need = (size_t)MROWS * 4096 * 2 + (size_t)MROWS * DN * 2 + (size_t)MROWS * 96 * 4;
  if (ws_size < need) return;
  u16*   xz  = (u16*)d_ws;                        // 16384 x 4096 bf16 (x_inner | z)
  u16*   u   = xz + (size_t)MROWS * 4096;         // 16384 x 2048 bf16 (u -> y_local -> y)
  u16*   W_out_b = (u16*)(u + (size_t)MROWS * DN);// 4MiB, gemm2 staging

  // d_out (64MiB) staging: all dead before gemm2 fully overwrites d_out
  u16*   xn_b    = (u16*)d_out;                                  // [0,32)MiB, dead after gemm1
  float* xbc_p   = (float*)d_out;                                // [0,32)MiB: 4 K-split partials
  float* xbc     = (float*)d_out;                                // [0,8)MiB final (over part0)
  u16*   hbuf    = (u16*)((char*)d_out + (32u << 20));           // [32,48)MiB f16 (after merge)
  u16*   W_in_b  = (u16*)((char*)d_out + (40u << 20));           // [40,48)MiB, dead after gemm1
  float* Sbuf    = (float*)((char*)d_out + (48u << 20));         // [48,50)MiB
  u16*   W_x_b   = (u16*)((char*)d_out + (50u << 20));           // [50,50.5)MiB
  u16*   W_dt_b  = (u16*)((char*)d_out + (50u << 20) + (512u << 10)); // [50.5,50.75)
  u16*   dl_b    = (u16*)((char*)d_out + (51u << 20));           // [51,53)MiB

  // one-time opt-in for 128KB dynamic LDS; fall back to 128-tile GEMM if unavailable
  static int use256 = -1;
  if (use256 < 0) {
    hipError_t e0 = hipFuncSetAttribute(reinterpret_cast<const void*>(&gemm256<0>),
        hipFuncAttributeMaxDynamicSharedMemorySize, 131072);
    hipError_t e2 = hipFuncSetAttribute(reinterpret_cast<const void*>(&gemm256<2>),
        hipFuncAttributeMaxDynamicSharedMemorySize, 131072);
    use256 = (e0 == hipSuccess && e2 == hipSuccess) ? 1 : 0;
  }

  cvt_weights_kernel<<<4480, 256, 0, stream>>>(W_in, W_in_b, W_x, W_x_b, W_dt, W_dt_b);
  ln_kernel<<<MROWS, 256, 0, stream>>>(x, ln_w, ln_b, xn_b);
  if (use256) {
    gemm256<0><<<dim3(MROWS / 256, 4096 / 256), 512, 131072, stream>>>(
        xn_b, DM, W_in_b, DM, xz, 4096, nullptr, DM);
  } else {
    gemm_mfma_nt<0><<<dim3(MROWS / 128, 4096 / 128), 256, 0, stream>>>(
        xn_b, DM, W_in_b, DM, xz, 4096, nullptr, DM, nullptr, nullptr);
  }
  conv_silu_kernel<<<MROWS, 256, 0, stream>>>(xz, conv_w, conv_b, u);
  // xbc = u @ W_x.T via 4-way K-split (512 blocks = 2/CU) + merge (also emits dl bf16)
  gemm_mfma_nt<4><<<dim3(MROWS / 128, 4), 256, 0, stream>>>(
      u, DN, W_x_b, DN, xbc_p, XBCS, nullptr, DN, nullptr, nullptr);
  xbc_merge<<<(MROWS * 128 / 4) / 256, 256, 0, stream>>>(xbc_p, xbc, dl_b);
  // dt = min(softplus(dl @ W_dt.T + b_dt)+1e-3, 0.1) -> f16 into dead x_inner cols of xz
  gemm_mfma_nt<3><<<dim3(MROWS / 128, DN / 128), 256, 0, stream>>>(
      dl_b, 64, W_dt_b, 64, xz, 4096, nullptr, 64, b_dt, nullptr);
  scan_part1<<<dim3(DN / 128, NCH, 4), 256, 0, stream>>>(
      u, xz, xbc, log_A, D_param, hbuf, Sbuf);
  scan_combine<<<4 * DN * 16 / 256, 256, 0, stream>>>(log_A, Sbuf, hbuf);
  scan_part2<<<dim3(DN / 128, NCH, 4), 256, 0, stream>>>(
      u, xz, xbc, xz, log_A, hbuf);
  cvt_bf16_kernel<<<(1024 * 2048 / 4) / 256, 256, 0, stream>>>(W_out, W_out_b, 1024 * 2048 / 4);
  if (use256) {
    gemm256<2><<<dim3(MROWS / 256, 1024 / 256), 512, 131072, stream>>>(
        u, DN, W_out_b, DN, out, DM, x, DN);
  } else {
    gemm_mfma_nt<2><<<dim3(MROWS / 128, 1024 / 128), 256, 0, stream>>>(
        u, DN, W_out_b, DN, out, DM, x, DN, nullptr, nullptr);
  }
}

// Round 13
// 588.232 us; speedup vs baseline: 1.3960x; 1.0181x over previous
//
#include <hip/hip_runtime.h>
#include <cstdint>
#include <cstddef>

#define TT 4096
#define DM 1024
#define DN 2048
#define MROWS 16384  // B*T
#define NCH 64       // scan chunks per sequence
#define CHL 64       // chunk length (TT/NCH)
#define SW 16        // staging window inside a chunk
#define XBCS 128     // xbc row stride (f32), padded from 96 for MFMA GEMM

typedef unsigned short u16;
typedef u16 ushort8_t __attribute__((ext_vector_type(8)));
typedef u16 ushort4_t __attribute__((ext_vector_type(4)));
typedef short bf16x8 __attribute__((ext_vector_type(8)));   // MFMA A/B frag (4 VGPR)
typedef float f32x4 __attribute__((ext_vector_type(4)));    // MFMA C/D frag (native vec)

#define EXP2(x) __builtin_amdgcn_exp2f(x)
#define L2E 1.44269504f

__device__ __forceinline__ float bf2f(u16 b) {
  return __uint_as_float(((unsigned int)b) << 16);
}
__device__ __forceinline__ u16 f2bf(float f) {
  unsigned int u = __float_as_uint(f);
  u = u + 0x7FFFu + ((u >> 16) & 1u);   // round-to-nearest-even
  return (u16)(u >> 16);
}
__device__ __forceinline__ u16 f2h(float f) {
  _Float16 h = (_Float16)f;
  return __builtin_bit_cast(u16, h);
}
__device__ __forceinline__ float h2f(u16 v) {
  return (float)__builtin_bit_cast(_Float16, v);
}

__device__ __forceinline__ void gload_lds16(const void* g, void* l) {
  __builtin_amdgcn_global_load_lds(
      (const __attribute__((address_space(1))) unsigned int*)g,
      (__attribute__((address_space(3))) unsigned int*)l, 16, 0, 0);
}

#define FENCE() asm volatile("" ::: "memory")

// ---------------- fused weight converts: W_in | W_x (pad 96->128) | W_dt | W_out ---------
__global__ __launch_bounds__(256) void cvt_weights_kernel(
    const float* __restrict__ W_in, u16* __restrict__ W_in_b,
    const float* __restrict__ W_x, u16* __restrict__ W_x_b,
    const float* __restrict__ W_dt, u16* __restrict__ W_dt_b,
    const float* __restrict__ W_out, u16* __restrict__ W_out_b) {
  int b = blockIdx.x, t = threadIdx.x;
  if (b < 4096) {                                  // W_in: 4096x1024 f32
    int i = b * 256 + t;
    float4 v = ((const float4*)W_in)[i];
    ushort4_t o; o[0] = f2bf(v.x); o[1] = f2bf(v.y); o[2] = f2bf(v.z); o[3] = f2bf(v.w);
    ((ushort4_t*)W_in_b)[i] = o;
  } else if (b < 4352) {                           // W_x -> 128x2048 bf16 (rows>=96 zero)
    int i = (b - 4096) * 256 + t;
    int row = i >> 9;                              // 512 float4 per row
    ushort4_t o;
    if (row < 96) {
      float4 v = ((const float4*)W_x)[i];
      o[0] = f2bf(v.x); o[1] = f2bf(v.y); o[2] = f2bf(v.z); o[3] = f2bf(v.w);
    } else {
      o[0] = 0; o[1] = 0; o[2] = 0; o[3] = 0;
    }
    ((ushort4_t*)W_x_b)[i] = o;
  } else if (b < 4384) {                           // W_dt: 2048x64 f32
    int i = (b - 4352) * 256 + t;
    float4 v = ((const float4*)W_dt)[i];
    ushort4_t o; o[0] = f2bf(v.x); o[1] = f2bf(v.y); o[2] = f2bf(v.z); o[3] = f2bf(v.w);
    ((ushort4_t*)W_dt_b)[i] = o;
  } else {                                         // W_out: 1024x2048 f32
    int i = (b - 4384) * 256 + t;
    float4 v = ((const float4*)W_out)[i];
    ushort4_t o; o[0] = f2bf(v.x); o[1] = f2bf(v.y); o[2] = f2bf(v.z); o[3] = f2bf(v.w);
    ((ushort4_t*)W_out_b)[i] = o;
  }
}

// ---------------- LayerNorm -> bf16 out (x streamed nontemporal: not re-read soon) -------
__global__ __launch_bounds__(256) void ln_kernel(const float* __restrict__ x,
    const float* __restrict__ ln_w, const float* __restrict__ ln_b,
    u16* __restrict__ xn) {
  int row = blockIdx.x;
  int tid = threadIdx.x;
  const f32x4* xr = (const f32x4*)(x + (size_t)row * DM);   // ext_vector: NT-load-legal
  f32x4 vv = __builtin_nontemporal_load(&xr[tid]);
  float4 v; v.x = vv[0]; v.y = vv[1]; v.z = vv[2]; v.w = vv[3];
  float s  = v.x + v.y + v.z + v.w;
  float s2 = v.x*v.x + v.y*v.y + v.z*v.z + v.w*v.w;
#pragma unroll
  for (int o = 32; o > 0; o >>= 1) { s += __shfl_down(s, o, 64); s2 += __shfl_down(s2, o, 64); }
  __shared__ float red[2][4];
  __shared__ float mv[2];
  int wid = tid >> 6, lane = tid & 63;
  if (lane == 0) { red[0][wid] = s; red[1][wid] = s2; }
  __syncthreads();
  if (tid == 0) {
    float a  = red[0][0] + red[0][1] + red[0][2] + red[0][3];
    float b2 = red[1][0] + red[1][1] + red[1][2] + red[1][3];
    float mean = a * (1.f / DM);
    float var  = b2 * (1.f / DM) - mean * mean;
    mv[0] = mean; mv[1] = rsqrtf(var + 1e-5f);
  }
  __syncthreads();
  float mean = mv[0], inv = mv[1];
  float4 w = ((const float4*)ln_w)[tid];
  float4 b = ((const float4*)ln_b)[tid];
  ushort4_t o;
  o[0] = f2bf((v.x - mean) * inv * w.x + b.x);
  o[1] = f2bf((v.y - mean) * inv * w.y + b.y);
  o[2] = f2bf((v.z - mean) * inv * w.z + b.z);
  o[3] = f2bf((v.w - mean) * inv * w.w + b.w);
  *(ushort4_t*)(xn + (size_t)row * DM + tid * 4) = o;
}

// ---------------- 128-tile bf16 MFMA GEMM ------------------------------------------------
// MODE 0: bf16 out. MODE 2: f32 out + residual add (nontemporal).
// MODE 3: f16 out = min(softplus(v+bias)+1e-3, 0.1).
// MODE 4: K-split partial (bj = K-quarter of 4); f32 partial to Cp + bj*MROWS*128.
template<int MODE>
__global__ __launch_bounds__(256) void gemm_mfma_nt(
    const u16* __restrict__ A, int lda,
    const u16* __restrict__ B, int ldb,
    void* __restrict__ Cp, int ldc,
    const float* __restrict__ Res, int K,
    const float* __restrict__ bias, u16* __restrict__ dl_out) {
  __shared__ __align__(16) u16 a_s[128 * 64];
  __shared__ __align__(16) u16 b_s[128 * 64];
  const int tid = threadIdx.x;
  const int w = tid >> 6, l = tid & 63;
  const int wr = w >> 1, wc = w & 1;
  const int nbx = gridDim.x, gy = gridDim.y;
  int lin = blockIdx.y * nbx + blockIdx.x;
  int xcd = lin & 7;
  int m = lin >> 3;
  int bi, bj;
  if (gy >= 8) {
    int njx = gy >> 3;
    bi = m / njx;
    bj = xcd * njx + m % njx;
  } else {
    int cpx = (nbx * gy) >> 3;
    int swz = xcd * cpx + m;
    bi = swz % nbx; bj = swz / nbx;
  }
  const int lrow = l >> 3;
  const int scol = ((l & 7) ^ lrow) * 16;

  f32x4 acc[4][4] = {};

  const int brow = (MODE == 4) ? 0 : bj;   // MODE4: bj selects K-segment, not N-tile
  const u16* Abase = A + (size_t)(bi * 128 + w * 8 + lrow) * lda;
  const u16* Bbase = B + (size_t)(brow * 128 + w * 8 + lrow) * ldb;

  int kbeg = 0, kend = K;
  if constexpr (MODE == 4) { kbeg = bj * (K >> 2); kend = kbeg + (K >> 2); }
  for (int k0 = kbeg; k0 < kend; k0 += 64) {
#pragma unroll
    for (int c = 0; c < 4; c++) {
      const char* ga = (const char*)(Abase + (size_t)(c * 32) * lda + k0) + scol;
      const char* gb = (const char*)(Bbase + (size_t)(c * 32) * ldb + k0) + scol;
      gload_lds16(ga, (char*)a_s + c * 4096 + w * 1024);
      gload_lds16(gb, (char*)b_s + c * 4096 + w * 1024);
    }
    __syncthreads();
#pragma unroll
    for (int kk = 0; kk < 2; kk++) {
      bf16x8 af[4], bfr[4];
#pragma unroll
      for (int m2 = 0; m2 < 4; m2++) {
        int fr = wr * 64 + m2 * 16 + (l & 15);
        int cb = (kk * 64 + ((l >> 4) << 4)) ^ ((fr & 7) << 4);
        af[m2] = *(const bf16x8*)((const char*)a_s + fr * 128 + cb);
      }
#pragma unroll
      for (int n = 0; n < 4; n++) {
        int fr = wc * 64 + n * 16 + (l & 15);
        int cb = (kk * 64 + ((l >> 4) << 4)) ^ ((fr & 7) << 4);
        bfr[n] = *(const bf16x8*)((const char*)b_s + fr * 128 + cb);
      }
#pragma unroll
      for (int m2 = 0; m2 < 4; m2++)
#pragma unroll
        for (int n = 0; n < 4; n++)
          acc[m2][n] = __builtin_amdgcn_mfma_f32_16x16x32_bf16(af[m2], bfr[n], acc[m2][n], 0, 0, 0);
    }
    __syncthreads();
  }
  const int col0 = ((MODE == 4) ? 0 : bj * 128) + wc * 64 + (l & 15);
  const int row0 = bi * 128 + wr * 64 + (l >> 4) * 4;
#pragma unroll
  for (int m2 = 0; m2 < 4; m2++)
#pragma unroll
    for (int n = 0; n < 4; n++) {
      int col = col0 + n * 16;
      float bv = 0.f;
      if constexpr (MODE == 3) bv = bias[col];
#pragma unroll
      for (int r = 0; r < 4; r++) {
        size_t row = (size_t)(row0 + m2 * 16 + r);
        float v = acc[m2][n][r];
        if constexpr (MODE == 0) {
          ((u16*)Cp)[row * ldc + col] = f2bf(v);
        } else if constexpr (MODE == 2) {
          v += __builtin_nontemporal_load(&Res[row * ldc + col]);
          __builtin_nontemporal_store(v, &((float*)Cp)[row * ldc + col]);
        } else if constexpr (MODE == 4) {
          ((float*)Cp)[(size_t)bj * ((size_t)MROWS * 128) + row * ldc + col] = v;
        } else {
          float s = v + bv;
          float sp = __logf(1.f + __expf(s));
          float dtv = fminf(sp + 1e-3f, 0.1f);
          ((u16*)Cp)[row * ldc + col] = f2h(dtv);
        }
      }
    }
}

// ---------------- xbc K-split merge: xbc = p0+p1+p2+p3 (in place over p0), dl bf16 -------
__global__ __launch_bounds__(256) void xbc_merge(const float* __restrict__ p,
    float* __restrict__ xbc, u16* __restrict__ dl) {
  int i = blockIdx.x * 256 + threadIdx.x;        // over MROWS*128/4 float4 slots
  const size_t PS = (size_t)MROWS * 128 / 4;     // partial stride in float4
  float4 a = ((const float4*)p)[i];
  float4 b = ((const float4*)p)[i + PS];
  float4 c = ((const float4*)p)[i + 2 * PS];
  float4 d = ((const float4*)p)[i + 3 * PS];
  float4 s;
  s.x = (a.x + b.x) + (c.x + d.x);
  s.y = (a.y + b.y) + (c.y + d.y);
  s.z = (a.z + b.z) + (c.z + d.z);
  s.w = (a.w + b.w) + (c.w + d.w);
  ((float4*)xbc)[i] = s;
  int col = (i & 31) * 4;                        // 32 float4 per 128-col row
  if (col < 64) {
    int row = i >> 5;
    ushort4_t o; o[0] = f2bf(s.x); o[1] = f2bf(s.y); o[2] = f2bf(s.z); o[3] = f2bf(s.w);
    *(ushort4_t*)(dl + (size_t)row * 64 + col) = o;
  }
}

// ---------------- 256x256 8-phase pipelined bf16 GEMM (r8 schedule — measured best) ------
// Per tile t, phases issue exactly one prefetch part each:
// [A2,A1,A3 of t+1; B0,B1,B2,B3,A0 of t+2]; waits: vmcnt(8)@ph0, vmcnt(10)@ph4.
// MODE 0 (gemm1): z-half (bj>=8) stores nontemporal — z not read until scan_part2,
// keeping A/B panels L3-resident shortens gate-wait load-return latency.
template<int MODE>
__global__ __launch_bounds__(512) void gemm256(
    const u16* __restrict__ A, int lda,
    const u16* __restrict__ B, int ldb,
    void* __restrict__ Cp, int ldc,
    const float* __restrict__ Res, int K) {
  extern __shared__ char smem[];          // 131072 B
  const int tid = threadIdx.x;
  const int w = tid >> 6, l = tid & 63;
  const int wm = w >> 2, wn = w & 3;
  const int nbx = gridDim.x, gy = gridDim.y;
  int lin = blockIdx.y * nbx + blockIdx.x;
  int xcd = lin & 7, mm = lin >> 3;
  int bi, bj;
  if (gy >= 8) { int njx = gy >> 3; bi = mm / njx; bj = xcd * njx + mm % njx; }
  else { int cpx = (nbx * gy) >> 3; int swz = xcd * cpx + mm; bi = swz % nbx; bj = swz / nbx; }
  const int lrow = l >> 3;
  const int scol = ((l & 7) ^ lrow) * 16;
  const int l15 = l & 15, lhi = (l >> 4) << 4;
  const u16* aRow = A + (size_t)(bi * 256 + w * 8 + lrow) * lda;
  const u16* bRow = B + (size_t)(bj * 256 + w * 8 + lrow) * ldb;
  char* As = smem;
  char* Bs = smem + 65536;

#define IS_A(s, k) gload_lds16((const char*)(aRow + (size_t)((k) * 64) * lda + (size_t)(s) * 64) + scol, \
                               As + ((((s) & 1)) << 15) + (k) * 8192 + w * 1024)
#define IS_B(s, k) gload_lds16((const char*)(bRow + (size_t)((k) * 64) * ldb + (size_t)(s) * 64) + scol, \
                               Bs + ((((s) & 1)) << 15) + (k) * 8192 + w * 1024)

  f32x4 acc[8][4] = {};
  bf16x8 bf[2][4];
  const int NT = K >> 6;

  // prologue: tile0 fully [B0..B3,A0,A2,A1,A3], tile1 first 5 [B0..B3,A0] (13 issues)
  IS_B(0, 0); IS_B(0, 1); IS_B(0, 2); IS_B(0, 3);
  IS_A(0, 0); IS_A(0, 2); IS_A(0, 1); IS_A(0, 3);
  IS_B(1, 0); IS_B(1, 1); IS_B(1, 2); IS_B(1, 3); IS_A(1, 0);

#define MFMA8(MLO, KK) do { \
    bf16x8 a0_ = ardA(MLO, KK), a1_ = ardA((MLO) + 1, KK); \
    __builtin_amdgcn_s_setprio(1); \
    _Pragma("unroll") \
    for (int n_ = 0; n_ < 4; n_++) { \
      acc[MLO][n_]       = __builtin_amdgcn_mfma_f32_16x16x32_bf16(a0_, bf[KK][n_], acc[MLO][n_], 0, 0, 0); \
      acc[(MLO) + 1][n_] = __builtin_amdgcn_mfma_f32_16x16x32_bf16(a1_, bf[KK][n_], acc[(MLO) + 1][n_], 0, 0, 0); \
    } \
    __builtin_amdgcn_s_setprio(0); \
  } while (0)

  for (int t = 0; t < NT; ++t) {
    const char* Ab = As + ((t & 1) << 15);
    const char* Bb = Bs + ((t & 1) << 15);
    auto ardA = [&](int m, int kk) {
      int fr = wm * 128 + m * 16 + l15;
      int cb = (kk * 64 + lhi) ^ ((fr & 7) << 4);
      return *(const bf16x8*)(Ab + fr * 128 + cb);
    };
    auto ardB = [&](int n, int kk) {
      int fr = wn * 64 + n * 16 + l15;
      int cb = (kk * 64 + lhi) ^ ((fr & 7) << 4);
      return *(const bf16x8*)(Bb + fr * 128 + cb);
    };
    // ---- ph0 ----
    if (t + 1 < NT) IS_A(t + 1, 2);
    FENCE();
    asm volatile("s_waitcnt vmcnt(8)" ::: "memory");
    __builtin_amdgcn_s_barrier();
    FENCE();
    bf[0][0] = ardB(0, 0); bf[0][1] = ardB(1, 0); bf[0][2] = ardB(2, 0); bf[0][3] = ardB(3, 0);
    MFMA8(0, 0);
    // ---- ph1 ----
    if (t + 1 < NT) IS_A(t + 1, 1);
    MFMA8(2, 0);
    // ---- ph2 ----
    if (t + 1 < NT) IS_A(t + 1, 3);
    bf[1][0] = ardB(0, 1); bf[1][1] = ardB(1, 1); bf[1][2] = ardB(2, 1); bf[1][3] = ardB(3, 1);
    MFMA8(0, 1);
    FENCE();
    __builtin_amdgcn_s_barrier();     // B LDS (cur buf) dead past here
    FENCE();
    // ---- ph3 ----
    if (t + 2 < NT) IS_B(t + 2, 0);
    MFMA8(2, 1);
    // ---- ph4 ----
    if (t + 2 < NT) IS_B(t + 2, 1);
    FENCE();
    asm volatile("s_waitcnt vmcnt(10)" ::: "memory");
    __builtin_amdgcn_s_barrier();
    FENCE();
    MFMA8(4, 0);
    // ---- ph5 ----
    if (t + 2 < NT) IS_B(t + 2, 2);
    MFMA8(6, 0);
    // ---- ph6 ----
    if (t + 2 < NT) IS_B(t + 2, 3);
    MFMA8(4, 1);
    // ---- ph7 ----
    if (t + 2 < NT) IS_A(t + 2, 0);
    MFMA8(6, 1);
  }
#undef MFMA8
#undef IS_A
#undef IS_B

  const int col0 = bj * 256 + wn * 64 + l15;
  const int row0 = bi * 256 + wm * 128 + (l >> 4) * 4;
  const bool ntst = (MODE == 0) && (bj >= 8);   // z-half of xz: bypass L2/L3
#pragma unroll
  for (int m = 0; m < 8; m++)
#pragma unroll
    for (int n = 0; n < 4; n++) {
      int col = col0 + n * 16;
#pragma unroll
      for (int r = 0; r < 4; r++) {
        size_t row = (size_t)(row0 + m * 16 + r);
        float v = acc[m][n][r];
        if constexpr (MODE == 0) {
          u16 bv = f2bf(v);
          if (ntst) __builtin_nontemporal_store(bv, &((u16*)Cp)[row * ldc + col]);
          else      ((u16*)Cp)[row * ldc + col] = bv;
        } else {
          v += __builtin_nontemporal_load(&Res[row * ldc + col]);
          __builtin_nontemporal_store(v, &((float*)Cp)[row * ldc + col]);
        }
      }
    }
}

// ---------------- causal depthwise conv (width 4) + SiLU; bf16 in, bf16 out ----------------
__global__ __launch_bounds__(256) void conv_silu_kernel(const u16* __restrict__ xz,
    const float* __restrict__ conv_w, const float* __restrict__ conv_b,
    u16* __restrict__ u) {
  size_t gid = (size_t)blockIdx.x * 256 + threadIdx.x;
  int c = (int)(gid & 255);
  size_t i = gid >> 8;
  int t = (int)(i & (TT - 1));
  int d0 = c * 8;
  const u16* base = xz + i * 4096 + d0;
  ushort8_t r0 = *(const ushort8_t*)base;
  ushort8_t r1 = 0, r2 = 0, r3 = 0;
  if (t >= 1) r1 = *(const ushort8_t*)(base - 4096);
  if (t >= 2) r2 = *(const ushort8_t*)(base - 2 * 4096);
  if (t >= 3) r3 = *(const ushort8_t*)(base - 3 * 4096);
  float cbv[8];
  *(float4*)&cbv[0] = *(const float4*)(conv_b + d0);
  *(float4*)&cbv[4] = *(const float4*)(conv_b + d0 + 4);
  ushort8_t o;
#pragma unroll
  for (int j = 0; j < 8; j++) {
    float4 w = *(const float4*)(conv_w + (size_t)(d0 + j) * 4);
    float a = cbv[j] + w.w * bf2f(r0[j]) + w.z * bf2f(r1[j])
            + w.y * bf2f(r2[j]) + w.x * bf2f(r3[j]);
    a = a * __builtin_amdgcn_rcpf(1.f + EXP2(-a * L2E));
    o[j] = f2bf(a);
  }
  *(ushort8_t*)(u + i * 2048 + d0) = o;
}

// ---------------- scan phase 1: local chunk scan from h=0; y_local (f16) over u ----------
// hbuf is f16 [b][c][n][d].
__global__ __launch_bounds__(256) void scan_part1(u16* u_g,
    const u16* __restrict__ dt_g, const float* __restrict__ xbc,
    const float* __restrict__ log_A, const float* __restrict__ D_param,
    u16* __restrict__ hbuf, float* __restrict__ Sbuf) {
  int d0 = blockIdx.x * 128;
  int c  = blockIdx.y;
  int b  = blockIdx.z;
  int tid = threadIdx.x;
  int w = tid >> 6, l = tid & 63;
  int dl = tid >> 1, q = tid & 1, q8 = q << 3;
  int d = d0 + dl;
  __shared__ __align__(16) u16 u_s[2][SW][128];     // 8K
  __shared__ __align__(16) u16 dts[2][SW][128];     // 8K
  __shared__ __align__(16) float bc_s[2][SW][32];   // 4K (B | C)

  float A2[8];
  {
    float4 la0 = *(const float4*)(log_A + (size_t)d * 16 + q8);
    float4 la1 = *(const float4*)(log_A + (size_t)d * 16 + q8 + 4);
    A2[0] = -EXP2(la0.x * L2E) * L2E; A2[1] = -EXP2(la0.y * L2E) * L2E;
    A2[2] = -EXP2(la0.z * L2E) * L2E; A2[3] = -EXP2(la0.w * L2E) * L2E;
    A2[4] = -EXP2(la1.x * L2E) * L2E; A2[5] = -EXP2(la1.y * L2E) * L2E;
    A2[6] = -EXP2(la1.z * L2E) * L2E; A2[7] = -EXP2(la1.w * L2E) * L2E;
  }
  float Dp = D_param[d];
  float h[8] = {};
  float sdt = 0.f;
  size_t t0 = (size_t)b * TT + (size_t)c * CHL;
  const int sr = w * 4 + (l >> 4);        // staging row in window
  const int sc = (l & 15) * 8;            // staging col (u16 units)
  u16* up = u_g + t0 * 2048 + d;

#define P1STAGE(wnd, pb) { size_t i0_ = t0 + (size_t)(wnd) * SW;                          \
    gload_lds16(u_g  + (i0_ + sr) * 2048 + d0 + sc, (char*)u_s[pb] + w * 1024);           \
    gload_lds16(dt_g + (i0_ + sr) * 4096 + d0 + sc, (char*)dts[pb] + w * 1024);           \
    if (w < 2) gload_lds16(xbc + (i0_ + w * 8 + (l >> 3)) * XBCS + 64 + (l & 7) * 4,      \
                           (char*)bc_s[pb] + w * 1024); }

  P1STAGE(0, 0);
  for (int wnd = 0; wnd < CHL / SW; wnd++) {
    int pb = wnd & 1;
    __syncthreads();
    if (wnd + 1 < CHL / SW) P1STAGE(wnd + 1, pb ^ 1);
#pragma unroll 4
    for (int tt = 0; tt < SW; tt++) {
      float dtv = h2f(dts[pb][tt][dl]);
      float uv  = bf2f(u_s[pb][tt][dl]);
      sdt += dtv;
      float xin = dtv * uv;
      float yv = q ? 0.f : uv * Dp;
      float4 B0 = *(const float4*)&bc_s[pb][tt][q8];
      float4 B1 = *(const float4*)&bc_s[pb][tt][q8 + 4];
      float4 C0 = *(const float4*)&bc_s[pb][tt][16 + q8];
      float4 C1 = *(const float4*)&bc_s[pb][tt][16 + q8 + 4];
      h[0] = __builtin_fmaf(EXP2(dtv * A2[0]), h[0], xin * B0.x); yv = __builtin_fmaf(h[0], C0.x, yv);
      h[1] = __builtin_fmaf(EXP2(dtv * A2[1]), h[1], xin * B0.y); yv = __builtin_fmaf(h[1], C0.y, yv);
      h[2] = __builtin_fmaf(EXP2(dtv * A2[2]), h[2], xin * B0.z); yv = __builtin_fmaf(h[2], C0.z, yv);
      h[3] = __builtin_fmaf(EXP2(dtv * A2[3]), h[3], xin * B0.w); yv = __builtin_fmaf(h[3], C0.w, yv);
      h[4] = __builtin_fmaf(EXP2(dtv * A2[4]), h[4], xin * B1.x); yv = __builtin_fmaf(h[4], C1.x, yv);
      h[5] = __builtin_fmaf(EXP2(dtv * A2[5]), h[5], xin * B1.y); yv = __builtin_fmaf(h[5], C1.y, yv);
      h[6] = __builtin_fmaf(EXP2(dtv * A2[6]), h[6], xin * B1.z); yv = __builtin_fmaf(h[6], C1.z, yv);
      h[7] = __builtin_fmaf(EXP2(dtv * A2[7]), h[7], xin * B1.w); yv = __builtin_fmaf(h[7], C1.w, yv);
      yv += __shfl_xor(yv, 1, 64);
      if (q == 0) *up = f2h(yv);
      up += 2048;
    }
  }
  u16* hp = hbuf + (((size_t)b * NCH + c) * 16 + q8) * DN + d;
#pragma unroll
  for (int k = 0; k < 8; k++) hp[(size_t)k * DN] = f2h(h[k]);
  if (q == 0) Sbuf[((size_t)b * NCH + c) * DN + d] = sdt;
#undef P1STAGE
}

// ---------------- scan phase 2: sequential chunk combine (f16 hbuf, in place) -------------
__global__ __launch_bounds__(256) void scan_combine(const float* __restrict__ log_A,
    const float* __restrict__ Sbuf, u16* __restrict__ hbuf) {
  int idx = blockIdx.x * 256 + threadIdx.x;    // over B*16*DN
  int dd = idx & (DN - 1), n = (idx >> 11) & 15, b = idx >> 15;
  float A2 = -EXP2(log_A[(size_t)dd * 16 + n] * L2E) * L2E;
  float h = 0.f;
#pragma unroll
  for (int c = 0; c < NCH; c++) {
    size_t off = (((size_t)b * NCH + c) * 16 + n) * DN + dd;
    float hl = h2f(hbuf[off]);
    float P = EXP2(A2 * Sbuf[((size_t)b * NCH + c) * DN + dd]);
    hbuf[off] = f2h(h);
    h = hl + P * h;
  }
}

// ---------------- scan phase 3: y = (y_local + C.(exp(A*cum) o h_start)) * silu(z) --------
__global__ __launch_bounds__(256) void scan_part2(u16* yl,
    const u16* __restrict__ xz, const float* __restrict__ xbc,
    const u16* __restrict__ dt_g, const float* __restrict__ log_A,
    const u16* __restrict__ hbuf) {
  int d0 = blockIdx.x * 128;
  int c  = blockIdx.y;
  int b  = blockIdx.z;
  int tid = threadIdx.x;
  int w = tid >> 6, l = tid & 63;
  int dl = tid >> 1, q = tid & 1, q8 = q << 3;
  int d = d0 + dl;
  __shared__ __align__(16) u16 yls[2][SW][128];     // 8K
  __shared__ __align__(16) u16 z_s[2][SW][128];     // 8K
  __shared__ __align__(16) u16 dts[2][SW][128];     // 8K
  __shared__ __align__(16) float c_s[2][SW][16];    // 2K

  float A2[8];
  {
    float4 la0 = *(const float4*)(log_A + (size_t)d * 16 + q8);
    float4 la1 = *(const float4*)(log_A + (size_t)d * 16 + q8 + 4);
    A2[0] = -EXP2(la0.x * L2E) * L2E; A2[1] = -EXP2(la0.y * L2E) * L2E;
    A2[2] = -EXP2(la0.z * L2E) * L2E; A2[3] = -EXP2(la0.w * L2E) * L2E;
    A2[4] = -EXP2(la1.x * L2E) * L2E; A2[5] = -EXP2(la1.y * L2E) * L2E;
    A2[6] = -EXP2(la1.z * L2E) * L2E; A2[7] = -EXP2(la1.w * L2E) * L2E;
  }
  float hs[8];
  {
    const u16* hp = hbuf + (((size_t)b * NCH + c) * 16 + q8) * DN + d;
#pragma unroll
    for (int k = 0; k < 8; k++) hs[k] = h2f(hp[(size_t)k * DN]);
  }
  float cum = 0.f;
  size_t t0 = (size_t)b * TT + (size_t)c * CHL;
  const int sr = w * 4 + (l >> 4);
  const int sc = (l & 15) * 8;
  u16* ylp = yl + t0 * 2048 + d;

#define P2STAGE(wnd, pb) { size_t i0_ = t0 + (size_t)(wnd) * SW;                          \
    gload_lds16(yl   + (i0_ + sr) * 2048 + d0 + sc, (char*)yls[pb] + w * 1024);           \
    gload_lds16(xz   + (i0_ + sr) * 4096 + 2048 + d0 + sc, (char*)z_s[pb] + w * 1024);    \
    gload_lds16(dt_g + (i0_ + sr) * 4096 + d0 + sc, (char*)dts[pb] + w * 1024);           \
    if (w == 0) gload_lds16(xbc + (i0_ + (l >> 2)) * XBCS + 80 + (l & 3) * 4,             \
                            (char*)c_s[pb]); }

  P2STAGE(0, 0);
  for (int wnd = 0; wnd < CHL / SW; wnd++) {
    int pb = wnd & 1;
    __syncthreads();
    if (wnd + 1 < CHL / SW) P2STAGE(wnd + 1, pb ^ 1);
#pragma unroll 4
    for (int tt = 0; tt < SW; tt++) {
      float dtv = h2f(dts[pb][tt][dl]);
      cum += dtv;
      float4 C0 = *(const float4*)&c_s[pb][tt][q8];
      float4 C1 = *(const float4*)&c_s[pb][tt][q8 + 4];
      float yv = C0.x * (EXP2(cum * A2[0]) * hs[0]) + C0.y * (EXP2(cum * A2[1]) * hs[1])
               + C0.z * (EXP2(cum * A2[2]) * hs[2]) + C0.w * (EXP2(cum * A2[3]) * hs[3])
               + C1.x * (EXP2(cum * A2[4]) * hs[4]) + C1.y * (EXP2(cum * A2[5]) * hs[5])
               + C1.z * (EXP2(cum * A2[6]) * hs[6]) + C1.w * (EXP2(cum * A2[7]) * hs[7]);
      if (q == 0) yv += h2f(yls[pb][tt][dl]);
      yv += __shfl_xor(yv, 1, 64);
      float zv = bf2f(z_s[pb][tt][dl]);
      float sig = __builtin_amdgcn_rcpf(1.f + EXP2(-zv * L2E));
      if (q == 0) *ylp = f2bf(yv * zv * sig);
      ylp += 2048;
    }
  }
#undef P2STAGE
}

extern "C" void kernel_launch(void* const* d_in, const int* in_sizes, int n_in,
                              void* d_out, int out_size, void* d_ws, size_t ws_size,
                              hipStream_t stream) {
  const float* x       = (const float*)d_in[0];
  const float* W_in    = (const float*)d_in[1];
  const float* conv_w  = (const float*)d_in[2];
  const float* conv_b  = (const float*)d_in[3];
  const float* W_x     = (const float*)d_in[4];
  const float* W_dt    = (const float*)d_in[5];
  const float* b_dt    = (const float*)d_in[6];
  const float* log_A   = (const float*)d_in[7];
  const float* D_param = (const float*)d_in[8];
  const float* W_out   = (const float*)d_in[9];
  const float* ln_w    = (const float*)d_in[10];
  const float* ln_b    = (const float*)d_in[11];
  float* out = (float*)d_out;

  size_t need = (size_t)MROWS * 4096 * 2 + (size_t)MROWS * DN * 2 + (size_t)MROWS * 96 * 4;
  if (ws_size < need) return;
  u16*   xz  = (u16*)d_ws;                        // 16384 x 4096 bf16 (x_inner | z)
  u16*   u   = xz + (size_t)MROWS * 4096;         // 16384 x 2048 bf16 (u -> y_local -> y)
  u16*   W_out_b = (u16*)(u + (size_t)MROWS * DN);// 4MiB, gemm2 staging

  // d_out (64MiB) staging: all dead before gemm2 fully overwrites d_out
  u16*   xn_b    = (u16*)d_out;                                  // [0,32)MiB, dead after gemm1
  float* xbc_p   = (float*)d_out;                                // [0,32)MiB: 4 K-split partials
  float* xbc     = (float*)d_out;                                // [0,8)MiB final (over part0)
  u16*   hbuf    = (u16*)((char*)d_out + (32u << 20));           // [32,48)MiB f16 (after merge)
  u16*   W_in_b  = (u16*)((char*)d_out + (40u << 20));           // [40,48)MiB, dead after gemm1
  float* Sbuf    = (float*)((char*)d_out + (48u << 20));         // [48,50)MiB
  u16*   W_x_b   = (u16*)((char*)d_out + (50u << 20));           // [50,50.5)MiB
  u16*   W_dt_b  = (u16*)((char*)d_out + (50u << 20) + (512u << 10)); // [50.5,50.75)
  u16*   dl_b    = (u16*)((char*)d_out + (51u << 20));           // [51,53)MiB

  // one-time opt-in for 128KB dynamic LDS; fall back to 128-tile GEMM if unavailable
  static int use256 = -1;
  if (use256 < 0) {
    hipError_t e0 = hipFuncSetAttribute(reinterpret_cast<const void*>(&gemm256<0>),
        hipFuncAttributeMaxDynamicSharedMemorySize, 131072);
    hipError_t e2 = hipFuncSetAttribute(reinterpret_cast<const void*>(&gemm256<2>),
        hipFuncAttributeMaxDynamicSharedMemorySize, 131072);
    use256 = (e0 == hipSuccess && e2 == hipSuccess) ? 1 : 0;
  }

  cvt_weights_kernel<<<6432, 256, 0, stream>>>(
      W_in, W_in_b, W_x, W_x_b, W_dt, W_dt_b, W_out, W_out_b);
  ln_kernel<<<MROWS, 256, 0, stream>>>(x, ln_w, ln_b, xn_b);
  if (use256) {
    gemm256<0><<<dim3(MROWS / 256, 4096 / 256), 512, 131072, stream>>>(
        xn_b, DM, W_in_b, DM, xz, 4096, nullptr, DM);
  } else {
    gemm_mfma_nt<0><<<dim3(MROWS / 128, 4096 / 128), 256, 0, stream>>>(
        xn_b, DM, W_in_b, DM, xz, 4096, nullptr, DM, nullptr, nullptr);
  }
  conv_silu_kernel<<<MROWS, 256, 0, stream>>>(xz, conv_w, conv_b, u);
  // xbc = u @ W_x.T via 4-way K-split (512 blocks = 2/CU) + merge (also emits dl bf16)
  gemm_mfma_nt<4><<<dim3(MROWS / 128, 4), 256, 0, stream>>>(
      u, DN, W_x_b, DN, xbc_p, XBCS, nullptr, DN, nullptr, nullptr);
  xbc_merge<<<(MROWS * 128 / 4) / 256, 256, 0, stream>>>(xbc_p, xbc, dl_b);
  // dt = min(softplus(dl @ W_dt.T + b_dt)+1e-3, 0.1) -> f16 into dead x_inner cols of xz
  gemm_mfma_nt<3><<<dim3(MROWS / 128, DN / 128), 256, 0, stream>>>(
      dl_b, 64, W_dt_b, 64, xz, 4096, nullptr, 64, b_dt, nullptr);
  scan_part1<<<dim3(DN / 128, NCH, 4), 256, 0, stream>>>(
      u, xz, xbc, log_A, D_param, hbuf, Sbuf);
  scan_combine<<<4 * DN * 16 / 256, 256, 0, stream>>>(log_A, Sbuf, hbuf);
  scan_part2<<<dim3(DN / 128, NCH, 4), 256, 0, stream>>>(
      u, xz, xbc, xz, log_A, hbuf);
  if (use256) {
    gemm256<2><<<dim3(MROWS / 256, 1024 / 256), 512, 131072, stream>>>(
        u, DN, W_out_b, DN, out, DM, x, DN);
  } else {
    gemm_mfma_nt<2><<<dim3(MROWS / 128, 1024 / 128), 256, 0, stream>>>(
        u, DN, W_out_b, DN, out, DM, x, DN, nullptr, nullptr);
  }
}